// Round 7
// baseline (565.474 us; speedup 1.0000x reference)
//
#include <hip/hip_runtime.h>
#include <hip/hip_bf16.h>

typedef unsigned short u16;
typedef __attribute__((ext_vector_type(8))) short s16x8;
typedef __attribute__((ext_vector_type(4))) float f32x4;

__device__ __forceinline__ float b2f(u16 v){
  unsigned u = ((unsigned)v) << 16; float f; __builtin_memcpy(&f, &u, 4); return f;
}
__device__ __forceinline__ float bits2f(unsigned u){
  float f; __builtin_memcpy(&f, &u, 4); return f;
}
__device__ __forceinline__ u16 f2b(float f){
  unsigned u; __builtin_memcpy(&u, &f, 4);
  unsigned r = (u + 0x7FFFu + ((u >> 16) & 1u)) >> 16; return (u16)r;
}
// 8 consecutive f32 -> 8 bf16 (RNE)
__device__ __forceinline__ s16x8 cvt8(const float* __restrict__ p){
  f32x4 a = *(const f32x4*)p;
  f32x4 b = *(const f32x4*)(p + 4);
  s16x8 r;
  r[0]=(short)f2b(a[0]); r[1]=(short)f2b(a[1]); r[2]=(short)f2b(a[2]); r[3]=(short)f2b(a[3]);
  r[4]=(short)f2b(b[0]); r[5]=(short)f2b(b[1]); r[6]=(short)f2b(b[2]); r[7]=(short)f2b(b[3]);
  return r;
}
// scaled variant (for log2e-folded GRU weights)
__device__ __forceinline__ s16x8 cvt8s(const float* __restrict__ p, float s){
  f32x4 a = *(const f32x4*)p;
  f32x4 b = *(const f32x4*)(p + 4);
  s16x8 r;
  r[0]=(short)f2b(a[0]*s); r[1]=(short)f2b(a[1]*s); r[2]=(short)f2b(a[2]*s); r[3]=(short)f2b(a[3]*s);
  r[4]=(short)f2b(b[0]*s); r[5]=(short)f2b(b[1]*s); r[6]=(short)f2b(b[2]*s); r[7]=(short)f2b(b[3]*s);
  return r;
}
#define LOG2E  1.4426950408889634f
#define LOG2E2 2.8853900817779268f
// pre-activations arrive scaled by log2e (sigm) / 2*log2e (tanh)
__device__ __forceinline__ float sigm2(float x){        // = 1/(1+e^-a), x = log2e*a
  float e = __builtin_amdgcn_exp2f(-x);
  return __builtin_amdgcn_rcpf(1.f + e);
}
__device__ __forceinline__ float tanh2(float y){        // = tanh(a), y = 2*log2e*a
  float e = __builtin_amdgcn_exp2f(y);
  return 1.f - 2.f * __builtin_amdgcn_rcpf(e + 1.f);
}
// non-scaled versions for the small kernels
__device__ __forceinline__ float sigm(float x){
  float e = __builtin_amdgcn_exp2f(-x * LOG2E);
  return __builtin_amdgcn_rcpf(1.f + e);
}
__device__ __forceinline__ float tanh_(float x){
  float e = __builtin_amdgcn_exp2f(x * LOG2E2);
  return 1.f - 2.f * __builtin_amdgcn_rcpf(e + 1.f);
}
__device__ __forceinline__ f32x4 mfma16(s16x8 a, s16x8 b, f32x4 c){
  return __builtin_amdgcn_mfma_f32_16x16x32_bf16(a, b, c, 0, 0, 0);
}

// ---------------- constant-one outputs (word_w, sent_w: softmax over size-1 axis) ----
__global__ void k_ones(float* __restrict__ out){
  int i = blockIdx.x * 512 + threadIdx.x;
  if (i < 8256) out[i] = 1.0f;
}

// ---------------- gi = log2e-scaled (emb[doc] @ Wi^T + bi (+bh for r,z)) -------------
// grid = 2 dirs * 64 mtiles(=sentences) * 6 ntiles ; block 512
// gi layout (bf16): [d][word][sent][ gt*256 + whc*32 + l15*2 + jt ]  (jt-pairs in u32)
__global__ __launch_bounds__(512, 2) void k_gi(const int* __restrict__ doc, const float* __restrict__ emb,
                                               const float* __restrict__ wWi, const float* __restrict__ wbi,
                                               const float* __restrict__ wbh, u16* __restrict__ gi){
  __shared__ u16 sA[128 * 64];
  __shared__ u16 sB[128 * 64];
  int bid = blockIdx.x;
  int d = bid / 384; int rem = bid % 384;
  int mt = rem / 6, nt = rem % 6;
  int mbase = mt * 128, nbase = nt * 128;
  int t = threadIdx.x;
  int w = t >> 6, l = t & 63, l15 = l & 15, l4 = l >> 4;
  int wm = w >> 2, wn = w & 3; // 2 x 4 wave grid
  int r0 = t >> 3, c0 = t & 7;
  int tok0 = doc[mbase + r0];
  int tok1 = doc[mbase + 64 + r0];
  const float* Wb = wWi + d * 196608 + nbase * 256;
  f32x4 acc[4][2];
  #pragma unroll
  for (int a = 0; a < 4; ++a){ acc[a][0] = {0.f,0.f,0.f,0.f}; acc[a][1] = {0.f,0.f,0.f,0.f}; }
  for (int ki = 0; ki < 4; ++ki){
    int k0 = ki * 64;
    s16x8 a0 = cvt8(&emb[tok0 * 256 + k0 + c0 * 8]);
    s16x8 a1 = cvt8(&emb[tok1 * 256 + k0 + c0 * 8]);
    s16x8 b0 = cvt8(&Wb[r0 * 256 + k0 + c0 * 8]);
    s16x8 b1 = cvt8(&Wb[(64 + r0) * 256 + k0 + c0 * 8]);
    __syncthreads();
    int sw = c0 ^ (r0 & 7);
    *(s16x8*)&sA[(r0 * 8 + sw) * 8] = a0;
    *(s16x8*)&sA[((64 + r0) * 8 + sw) * 8] = a1;
    *(s16x8*)&sB[(r0 * 8 + sw) * 8] = b0;
    *(s16x8*)&sB[((64 + r0) * 8 + sw) * 8] = b1;
    __syncthreads();
    #pragma unroll
    for (int kt = 0; kt < 2; ++kt){
      int ch = kt * 4 + l4;
      s16x8 bfr[2];
      #pragma unroll
      for (int n2 = 0; n2 < 2; ++n2){
        int rr = wn * 32 + n2 * 16 + l15;
        bfr[n2] = *(const s16x8*)&sB[(rr * 8 + (ch ^ (rr & 7))) * 8];
      }
      #pragma unroll
      for (int m2 = 0; m2 < 4; ++m2){
        int rr = wm * 64 + m2 * 16 + l15;
        s16x8 af = *(const s16x8*)&sA[(rr * 8 + (ch ^ (rr & 7))) * 8];
        acc[m2][0] = mfma16(af, bfr[0], acc[m2][0]);
        acc[m2][1] = mfma16(af, bfr[1], acc[m2][1]);
      }
    }
  }
  int cgb = nbase + wn * 32;            // one gt per (nt,wn)
  int gt  = cgb >> 8;
  int whc = (cgb & 255) >> 5;
  float sg = (gt < 2) ? LOG2E : LOG2E2;
  int cg0 = cgb + l15, cg1 = cgb + 16 + l15;
  float bi0 = wbi[d * 768 + cg0] + ((gt < 2) ? wbh[d * 768 + cg0] : 0.f);
  float bi1 = wbi[d * 768 + cg1] + ((gt < 2) ? wbh[d * 768 + cg1] : 0.f);
  #pragma unroll
  for (int m2 = 0; m2 < 4; ++m2){
    #pragma unroll
    for (int i = 0; i < 4; ++i){
      int ml = wm * 64 + m2 * 16 + l4 * 4 + i;   // word index
      int base2 = ((d * 128 + ml) * 64 + mt) * 768 + gt * 256 + whc * 32;
      unsigned lo = f2b(sg * (acc[m2][0][i] + bi0));
      unsigned hi = f2b(sg * (acc[m2][1][i] + bi1));
      *(unsigned*)&gi[base2 + l15 * 2] = lo | (hi << 16);
    }
  }
}

// ---------------- word GRU recurrence: 128 steps, per-block = (dir, 16 sentences) ----
// grid = 8 (d = bid&1, g = bid>>1), block 512 (8 waves, wave w owns 32 hidden cols)
// ALL 48 weight fragments in registers (192 VGPR). LDS = h double-buffer only (16 KiB).
// Per-wave per-step LDS reads: 8 (h/af only). Budget audit ~250/256 at 2 waves/SIMD.
__global__ __launch_bounds__(512, 2) void k_rec(const float* __restrict__ wWh, const float* __restrict__ wbh,
                                                const u16* __restrict__ gi, u16* __restrict__ wenc){
  __shared__ u16 sH0[4096];    // h buffers [16][256] bf16, XOR-swizzled (8 KiB each)
  __shared__ u16 sH1[4096];
  int bid = blockIdx.x; int d = bid & 1, g = bid >> 1;
  int t = threadIdx.x, w = t >> 6, l = t & 63, l15 = l & 15, l4 = l >> 4;
  int jb = w * 32;
  const float* Wh = wWh + d * 196608;
  // r,z gates (scaled log2e), both jt halves: 32 frags = 128 regs
  s16x8 bR[2][2][8];
  #pragma unroll
  for (int gt = 0; gt < 2; ++gt)
    #pragma unroll
    for (int jt = 0; jt < 2; ++jt)
      #pragma unroll
      for (int kt = 0; kt < 8; ++kt){
        int n = gt * 256 + jb + jt * 16 + l15;
        bR[gt][jt][kt] = cvt8s(&Wh[n * 256 + kt * 32 + l4 * 8], LOG2E);
      }
  // n gate, both jt halves (scaled 2log2e): 16 frags = 64 regs
  s16x8 bN0[8], bN1[8];
  #pragma unroll
  for (int kt = 0; kt < 8; ++kt){
    int n0 = 512 + jb + l15;
    int n1 = 512 + jb + 16 + l15;
    bN0[kt] = cvt8s(&Wh[n0 * 256 + kt * 32 + l4 * 8], LOG2E2);
    bN1[kt] = cvt8s(&Wh[n1 * 256 + kt * 32 + l4 * 8], LOG2E2);
  }
  s16x8 z8 = {0,0,0,0,0,0,0,0};
  *(s16x8*)&sH0[t * 8] = z8;
  float hloc[2][4] = {{0.f,0.f,0.f,0.f},{0.f,0.f,0.f,0.f}};
  float bhn[2];
  #pragma unroll
  for (int jt = 0; jt < 2; ++jt)
    bhn[jt] = wbh[d * 768 + 512 + jb + jt * 16 + l15] * LOG2E2;  // pre-scaled

  // gi layout: [d][word][sent][768'] with jt-paired u32 at gt*256 + jb + l15*2
  const u16* gb = gi + d * 6291456 + (g * 16 + l4 * 4) * 768 + jb + l15 * 2;
  u16* wbase = wenc + ((g * 16 + l4 * 4) * 128) * 512 + d * 256 + jb + l15;

  // prefetch step 0's gate values (12 u32 per thread)
  unsigned g32[3][4];
  #pragma unroll
  for (int gt = 0; gt < 3; ++gt)
    #pragma unroll
    for (int i = 0; i < 4; ++i)
      g32[gt][i] = *(const unsigned*)&gb[gt * 256 + i * 768];
  __syncthreads();

  auto body = [&](int step, const u16* shc, u16* shn){
    f32x4 acc[3][2];
    #pragma unroll
    for (int a = 0; a < 3; ++a){ acc[a][0] = {0.f,0.f,0.f,0.f}; acc[a][1] = {0.f,0.f,0.f,0.f}; }
    #pragma unroll
    for (int kt = 0; kt < 8; ++kt){
      int ch = kt * 4 + l4;
      s16x8 af = *(const s16x8*)&shc[l15 * 256 + (ch ^ (l15 & 7)) * 8];
      acc[0][0] = mfma16(af, bR[0][0][kt], acc[0][0]);
      acc[0][1] = mfma16(af, bR[0][1][kt], acc[0][1]);
      acc[1][0] = mfma16(af, bR[1][0][kt], acc[1][0]);
      acc[1][1] = mfma16(af, bR[1][1][kt], acc[1][1]);
      acc[2][0] = mfma16(af, bN0[kt], acc[2][0]);
      acc[2][1] = mfma16(af, bN1[kt], acc[2][1]);
    }
    u16 hb[2][4];
    #pragma unroll
    for (int jt = 0; jt < 2; ++jt){
      #pragma unroll
      for (int i = 0; i < 4; ++i){
        unsigned v0 = g32[0][i], v1 = g32[1][i], v2 = g32[2][i];
        float ir, iz, inn;
        if (jt == 0){ ir = bits2f(v0 << 16); iz = bits2f(v1 << 16); inn = bits2f(v2 << 16); }
        else        { ir = bits2f(v0 & 0xffff0000u); iz = bits2f(v1 & 0xffff0000u); inn = bits2f(v2 & 0xffff0000u); }
        float r = sigm2(ir + acc[0][jt][i]);
        float z = sigm2(iz + acc[1][jt][i]);
        float nn = tanh2(inn + r * (acc[2][jt][i] + bhn[jt]));
        float h = nn + z * (hloc[jt][i] - nn);
        hloc[jt][i] = h;
      }
      // pack pairs with v_cvt_pk_bf16_f32 (RNE)
      __hip_bfloat162 p01 = __float22bfloat162_rn(float2{hloc[jt][0], hloc[jt][1]});
      __hip_bfloat162 p23 = __float22bfloat162_rn(float2{hloc[jt][2], hloc[jt][3]});
      unsigned b01, b23;
      __builtin_memcpy(&b01, &p01, 4); __builtin_memcpy(&b23, &p23, 4);
      hb[jt][0] = (u16)b01; hb[jt][1] = (u16)(b01 >> 16);
      hb[jt][2] = (u16)b23; hb[jt][3] = (u16)(b23 >> 16);
    }
    // prefetch next step's gate values; stay in flight across the raw barrier.
    // Final iteration reads past gi (lands in wenc region; values unused).
    {
      const u16* gp = gb + (step + 1) * 49152;
      #pragma unroll
      for (int gt = 0; gt < 3; ++gt)
        #pragma unroll
        for (int i = 0; i < 4; ++i)
          g32[gt][i] = *(const unsigned*)&gp[gt * 256 + i * 768];
    }
    #pragma unroll
    for (int jt = 0; jt < 2; ++jt){
      #pragma unroll
      for (int i = 0; i < 4; ++i){
        int s = l4 * 4 + i, c = jb + jt * 16 + l15;
        shn[s * 256 + ((c >> 3) ^ (s & 7)) * 8 + (c & 7)] = hb[jt][i];
        wbase[(i * 128 + step) * 512 + jt * 16] = hb[jt][i];  // fire-and-forget
      }
    }
    // drain only LDS (lgkm), NOT vmem; then raw barrier.
    asm volatile("s_waitcnt lgkmcnt(0)" ::: "memory");
    __builtin_amdgcn_s_barrier();
    __builtin_amdgcn_sched_barrier(0);
  };

  #pragma unroll 1
  for (int it = 0; it < 64; ++it){
    body(2 * it,     sH0, sH1);
    body(2 * it + 1, sH1, sH0);
  }
}

// ---------------- u_word = tanh(wordenc @ waW^T + wab); sent_summ = sum over words ---
// grid = 64 sentences * 4 ntiles ; block 512
__global__ __launch_bounds__(512, 2) void k_uword(const u16* __restrict__ wenc, const float* __restrict__ waW,
                                                  const float* __restrict__ wab, u16* __restrict__ ssum){
  __shared__ u16 sA[128 * 64], sB[128 * 64];
  __shared__ float red[128];
  int bid = blockIdx.x; int s = bid >> 2, nt = bid & 3; int nbase = nt * 128;
  int t = threadIdx.x, w = t >> 6, l = t & 63, l15 = l & 15, l4 = l >> 4;
  int wm = w >> 2, wn = w & 3;
  int r0 = t >> 3, c0 = t & 7;
  const u16* Arow = wenc + s * 65536;
  const float* Brow = waW + nbase * 512;
  if (t < 128) red[t] = 0.f;
  f32x4 acc[4][2];
  #pragma unroll
  for (int a = 0; a < 4; ++a){ acc[a][0] = {0.f,0.f,0.f,0.f}; acc[a][1] = {0.f,0.f,0.f,0.f}; }
  for (int ki = 0; ki < 8; ++ki){
    int k0 = ki * 64;
    s16x8 a0 = *(const s16x8*)&Arow[r0 * 512 + k0 + c0 * 8];
    s16x8 a1 = *(const s16x8*)&Arow[(64 + r0) * 512 + k0 + c0 * 8];
    s16x8 b0 = cvt8(&Brow[r0 * 512 + k0 + c0 * 8]);
    s16x8 b1 = cvt8(&Brow[(64 + r0) * 512 + k0 + c0 * 8]);
    __syncthreads();
    int sw = c0 ^ (r0 & 7);
    *(s16x8*)&sA[(r0 * 8 + sw) * 8] = a0;
    *(s16x8*)&sA[((64 + r0) * 8 + sw) * 8] = a1;
    *(s16x8*)&sB[(r0 * 8 + sw) * 8] = b0;
    *(s16x8*)&sB[((64 + r0) * 8 + sw) * 8] = b1;
    __syncthreads();
    #pragma unroll
    for (int kt = 0; kt < 2; ++kt){
      int ch = kt * 4 + l4;
      s16x8 bfr[2];
      #pragma unroll
      for (int n2 = 0; n2 < 2; ++n2){
        int rr = wn * 32 + n2 * 16 + l15;
        bfr[n2] = *(const s16x8*)&sB[(rr * 8 + (ch ^ (rr & 7))) * 8];
      }
      #pragma unroll
      for (int m2 = 0; m2 < 4; ++m2){
        int rr = wm * 64 + m2 * 16 + l15;
        s16x8 af = *(const s16x8*)&sA[(rr * 8 + (ch ^ (rr & 7))) * 8];
        acc[m2][0] = mfma16(af, bfr[0], acc[m2][0]);
        acc[m2][1] = mfma16(af, bfr[1], acc[m2][1]);
      }
    }
  }
  float bi0 = wab[nbase + wn * 32 + l15];
  float bi1 = wab[nbase + wn * 32 + 16 + l15];
  float p0 = 0.f, p1 = 0.f;
  #pragma unroll
  for (int m2 = 0; m2 < 4; ++m2){
    #pragma unroll
    for (int i = 0; i < 4; ++i){
      p0 += tanh_(acc[m2][0][i] + bi0);
      p1 += tanh_(acc[m2][1][i] + bi1);
    }
  }
  p0 += __shfl_xor(p0, 16); p0 += __shfl_xor(p0, 32);
  p1 += __shfl_xor(p1, 16); p1 += __shfl_xor(p1, 32);
  if (l4 == 0){
    atomicAdd(&red[wn * 32 + l15], p0);
    atomicAdd(&red[wn * 32 + 16 + l15], p1);
  }
  __syncthreads();
  if (t < 128) ssum[s * 512 + nbase + t] = f2b(red[t]);
}

// ---------------- sentence GRU (zero state): sentenc ---------------------------------
// grid = 2 dirs * 8 jblocks(64) ; block 512 (waves: 4M x 2J)
__global__ __launch_bounds__(512, 2) void k_sent(const u16* __restrict__ ssum, const float* __restrict__ sWi,
                                                 const float* __restrict__ sbi, const float* __restrict__ sbh,
                                                 u16* __restrict__ senc){
  __shared__ u16 sA[64 * 512]; // 64 KiB, swizzled
  int bid = blockIdx.x; int d = bid >> 3, jb8 = bid & 7; int jbase = jb8 * 64;
  int t = threadIdx.x, w = t >> 6, l = t & 63, l15 = l & 15, l4 = l >> 4;
  int wm = w >> 1, wj = w & 1;
  #pragma unroll
  for (int j = 0; j < 8; ++j){
    int q = j * 512 + t, r = q >> 6, c = q & 63;
    s16x8 v = *(const s16x8*)&ssum[r * 512 + c * 8];
    *(s16x8*)&sA[(r * 64 + (c ^ (r & 7))) * 8] = v;
  }
  __syncthreads();
  const float* Wd = sWi + d * 786432;
  f32x4 acc[3][2];
  #pragma unroll
  for (int a = 0; a < 3; ++a){ acc[a][0] = {0.f,0.f,0.f,0.f}; acc[a][1] = {0.f,0.f,0.f,0.f}; }
  int ra = wm * 16 + l15;
  #pragma unroll 4
  for (int kt = 0; kt < 16; ++kt){
    int ch = kt * 4 + l4;
    s16x8 af = *(const s16x8*)&sA[(ra * 64 + (ch ^ (ra & 7))) * 8];
    #pragma unroll
    for (int gt = 0; gt < 3; ++gt){
      #pragma unroll
      for (int jt = 0; jt < 2; ++jt){
        int n = gt * 512 + jbase + wj * 32 + jt * 16 + l15;
        s16x8 bf = cvt8(&Wd[n * 512 + kt * 32 + l4 * 8]);
        acc[gt][jt] = mfma16(af, bf, acc[gt][jt]);
      }
    }
  }
  float biv[3][2], bhv[3][2];
  #pragma unroll
  for (int gt = 0; gt < 3; ++gt){
    #pragma unroll
    for (int jt = 0; jt < 2; ++jt){
      int n = gt * 512 + jbase + wj * 32 + jt * 16 + l15;
      biv[gt][jt] = sbi[d * 1536 + n];
      bhv[gt][jt] = sbh[d * 1536 + n];
    }
  }
  #pragma unroll
  for (int jt = 0; jt < 2; ++jt){
    #pragma unroll
    for (int i = 0; i < 4; ++i){
      float r_ = sigm(acc[0][jt][i] + biv[0][jt] + bhv[0][jt]);
      float z_ = sigm(acc[1][jt][i] + biv[1][jt] + bhv[1][jt]);
      float n_ = tanh_(acc[2][jt][i] + biv[2][jt] + r_ * bhv[2][jt]);
      float sh = (1.f - z_) * n_;
      int srow = wm * 16 + l4 * 4 + i;
      senc[srow * 1024 + d * 512 + jbase + wj * 32 + jt * 16 + l15] = f2b(sh);
    }
  }
}

// ---------------- u_sent = tanh(sentenc @ saW^T + sab); doc = sum over sentences -----
// grid = 8 ntiles ; block 512 (waves 2M x 4N)
__global__ __launch_bounds__(512, 2) void k_usent(const u16* __restrict__ senc, const float* __restrict__ saW,
                                                  const float* __restrict__ sab, float* __restrict__ docv){
  __shared__ u16 sA[64 * 1024]; // 128 KiB, swizzled
  __shared__ float red[128];
  int bid = blockIdx.x; int nbase = bid * 128;
  int t = threadIdx.x, w = t >> 6, l = t & 63, l15 = l & 15, l4 = l >> 4;
  int wm = w >> 2, wn = w & 3;
  if (t < 128) red[t] = 0.f;
  #pragma unroll
  for (int j = 0; j < 16; ++j){
    int q = j * 512 + t, r = q >> 7, c = q & 127;
    s16x8 v = *(const s16x8*)&senc[r * 1024 + c * 8];
    *(s16x8*)&sA[(r * 128 + (c ^ (r & 7))) * 8] = v;
  }
  __syncthreads();
  f32x4 acc[2][2];
  #pragma unroll
  for (int a = 0; a < 2; ++a){ acc[a][0] = {0.f,0.f,0.f,0.f}; acc[a][1] = {0.f,0.f,0.f,0.f}; }
  #pragma unroll 4
  for (int kt = 0; kt < 32; ++kt){
    int ch = kt * 4 + l4;
    s16x8 af[2];
    #pragma unroll
    for (int mt = 0; mt < 2; ++mt){
      int r = wm * 32 + mt * 16 + l15;
      af[mt] = *(const s16x8*)&sA[(r * 128 + (ch ^ (r & 7))) * 8];
    }
    #pragma unroll
    for (int nt = 0; nt < 2; ++nt){
      int n = nbase + wn * 32 + nt * 16 + l15;
      s16x8 bf = cvt8(&saW[n * 1024 + kt * 32 + l4 * 8]);
      acc[0][nt] = mfma16(af[0], bf, acc[0][nt]);
      acc[1][nt] = mfma16(af[1], bf, acc[1][nt]);
    }
  }
  float b0 = sab[nbase + wn * 32 + l15];
  float b1 = sab[nbase + wn * 32 + 16 + l15];
  float p0 = 0.f, p1 = 0.f;
  #pragma unroll
  for (int mt = 0; mt < 2; ++mt){
    #pragma unroll
    for (int i = 0; i < 4; ++i){
      p0 += tanh_(acc[mt][0][i] + b0);
      p1 += tanh_(acc[mt][1][i] + b1);
    }
  }
  p0 += __shfl_xor(p0, 16); p0 += __shfl_xor(p0, 32);
  p1 += __shfl_xor(p1, 16); p1 += __shfl_xor(p1, 32);
  if (l4 == 0){
    atomicAdd(&red[wn * 32 + l15], p0);
    atomicAdd(&red[wn * 32 + 16 + l15], p1);
  }
  __syncthreads();
  if (t < 128) docv[nbase + t] = red[t];
}

// ---------------- logits + log_softmax ----------------------------------------------
__global__ __launch_bounds__(256) void k_final(const float* __restrict__ docv, const float* __restrict__ doW,
                                               const float* __restrict__ dob, float* __restrict__ out){
  __shared__ float lg[16];
  int w = threadIdx.x >> 6, l = threadIdx.x & 63;
  for (int c = w; c < 13; c += 4){
    float p = 0.f;
    for (int j = 0; j < 16; ++j){
      int k = j * 64 + l;
      p += docv[k] * doW[c * 1024 + k];
    }
    for (int o = 32; o >= 1; o >>= 1) p += __shfl_xor(p, o);
    if (l == 0) lg[c] = p + dob[c];
  }
  __syncthreads();
  if (threadIdx.x == 0){
    float m = lg[0];
    for (int c = 1; c < 13; ++c) m = fmaxf(m, lg[c]);
    float s = 0.f;
    for (int c = 0; c < 13; ++c) s += __expf(lg[c] - m);
    float ls = logf(s);
    for (int c = 0; c < 13; ++c) out[8256 + c] = lg[c] - m - ls;
  }
}

extern "C" void kernel_launch(void* const* d_in, const int* in_sizes, int n_in,
                              void* d_out, int out_size, void* d_ws, size_t ws_size,
                              hipStream_t stream) {
  (void)in_sizes; (void)n_in; (void)out_size; (void)ws_size;
  const int*   doc = (const int*)d_in[0];
  const float* emb = (const float*)d_in[1];
  const float* wWi = (const float*)d_in[2];
  const float* wWh = (const float*)d_in[3];
  const float* wbi = (const float*)d_in[4];
  const float* wbh = (const float*)d_in[5];
  const float* sWi = (const float*)d_in[6];
  // d_in[7] = s_Wh unused (sentence GRU sees zero state)
  const float* sbi = (const float*)d_in[8];
  const float* sbh = (const float*)d_in[9];
  const float* waW = (const float*)d_in[10];
  const float* wab = (const float*)d_in[11];
  // d_in[12] = uw_W unused (softmax over size-1 axis)
  const float* saW = (const float*)d_in[13];
  const float* sab = (const float*)d_in[14];
  // d_in[15] = us_W unused
  const float* doW = (const float*)d_in[16];
  const float* dob = (const float*)d_in[17];
  float* out = (float*)d_out;
  char* ws = (char*)d_ws;
  u16* gi    = (u16*)(ws);                    // 2*128*64*768 bf16 = 25,165,824 B
  u16* wenc  = (u16*)(ws + 25165824);         // 64*128*512 bf16  =  8,388,608 B
  u16* ssumv = (u16*)(ws + 33554432);         // 64*512 bf16      =     65,536 B
  u16* sencv = (u16*)(ws + 33619968);         // 64*1024 bf16     =    131,072 B
  float* docv = (float*)(ws + 33751040);      // 1024 f32         =      4,096 B

  k_ones  <<<17, 512, 0, stream>>>(out);
  k_gi    <<<768, 512, 0, stream>>>(doc, emb, wWi, wbi, wbh, gi);
  k_rec   <<<8, 512, 0, stream>>>(wWh, wbh, gi, wenc);
  k_uword <<<256, 512, 0, stream>>>(wenc, waW, wab, ssumv);
  k_sent  <<<16, 512, 0, stream>>>(ssumv, sWi, sbi, sbh, sencv);
  k_usent <<<8, 512, 0, stream>>>(sencv, saW, sab, docv);
  k_final <<<1, 256, 0, stream>>>(docv, doW, dob, out);
}

// Round 8
// 488.958 us; speedup vs baseline: 1.1565x; 1.1565x over previous
//
#include <hip/hip_runtime.h>
#include <hip/hip_bf16.h>

typedef unsigned short u16;
typedef __attribute__((ext_vector_type(8))) short s16x8;
typedef __attribute__((ext_vector_type(4))) float f32x4;

__device__ __forceinline__ float b2f(u16 v){
  unsigned u = ((unsigned)v) << 16; float f; __builtin_memcpy(&f, &u, 4); return f;
}
__device__ __forceinline__ float bits2f(unsigned u){
  float f; __builtin_memcpy(&f, &u, 4); return f;
}
__device__ __forceinline__ u16 f2b(float f){
  unsigned u; __builtin_memcpy(&u, &f, 4);
  unsigned r = (u + 0x7FFFu + ((u >> 16) & 1u)) >> 16; return (u16)r;
}
// 8 consecutive f32 -> 8 bf16 (RNE)
__device__ __forceinline__ s16x8 cvt8(const float* __restrict__ p){
  f32x4 a = *(const f32x4*)p;
  f32x4 b = *(const f32x4*)(p + 4);
  s16x8 r;
  r[0]=(short)f2b(a[0]); r[1]=(short)f2b(a[1]); r[2]=(short)f2b(a[2]); r[3]=(short)f2b(a[3]);
  r[4]=(short)f2b(b[0]); r[5]=(short)f2b(b[1]); r[6]=(short)f2b(b[2]); r[7]=(short)f2b(b[3]);
  return r;
}
// scaled variant (for log2e-folded GRU weights)
__device__ __forceinline__ s16x8 cvt8s(const float* __restrict__ p, float s){
  f32x4 a = *(const f32x4*)p;
  f32x4 b = *(const f32x4*)(p + 4);
  s16x8 r;
  r[0]=(short)f2b(a[0]*s); r[1]=(short)f2b(a[1]*s); r[2]=(short)f2b(a[2]*s); r[3]=(short)f2b(a[3]*s);
  r[4]=(short)f2b(b[0]*s); r[5]=(short)f2b(b[1]*s); r[6]=(short)f2b(b[2]*s); r[7]=(short)f2b(b[3]*s);
  return r;
}
#define LOG2E  1.4426950408889634f
#define LOG2E2 2.8853900817779268f
// pre-activations arrive scaled by log2e (sigm) / 2*log2e (tanh)
__device__ __forceinline__ float sigm2(float x){        // = 1/(1+e^-a), x = log2e*a
  float e = __builtin_amdgcn_exp2f(-x);
  return __builtin_amdgcn_rcpf(1.f + e);
}
__device__ __forceinline__ float tanh2(float y){        // = tanh(a), y = 2*log2e*a
  float e = __builtin_amdgcn_exp2f(y);
  return 1.f - 2.f * __builtin_amdgcn_rcpf(e + 1.f);
}
// non-scaled versions for the small kernels
__device__ __forceinline__ float sigm(float x){
  float e = __builtin_amdgcn_exp2f(-x * LOG2E);
  return __builtin_amdgcn_rcpf(1.f + e);
}
__device__ __forceinline__ float tanh_(float x){
  float e = __builtin_amdgcn_exp2f(x * LOG2E2);
  return 1.f - 2.f * __builtin_amdgcn_rcpf(e + 1.f);
}
__device__ __forceinline__ f32x4 mfma16(s16x8 a, s16x8 b, f32x4 c){
  return __builtin_amdgcn_mfma_f32_16x16x32_bf16(a, b, c, 0, 0, 0);
}

// ---------------- constant-one outputs (word_w, sent_w: softmax over size-1 axis) ----
__global__ void k_ones(float* __restrict__ out){
  int i = blockIdx.x * 512 + threadIdx.x;
  if (i < 8256) out[i] = 1.0f;
}

// ---------------- gi = log2e-scaled (emb[doc] @ Wi^T + bi (+bh for r,z)) -------------
// grid = 2 dirs * 64 mtiles(=sentences) * 6 ntiles ; block 512
// gi layout (bf16): [d][word][sent][ gt*256 + whc*32 + l15*2 + jt ]  (jt-pairs in u32)
__global__ __launch_bounds__(512, 2) void k_gi(const int* __restrict__ doc, const float* __restrict__ emb,
                                               const float* __restrict__ wWi, const float* __restrict__ wbi,
                                               const float* __restrict__ wbh, u16* __restrict__ gi){
  __shared__ u16 sA[128 * 64];
  __shared__ u16 sB[128 * 64];
  int bid = blockIdx.x;
  int d = bid / 384; int rem = bid % 384;
  int mt = rem / 6, nt = rem % 6;
  int mbase = mt * 128, nbase = nt * 128;
  int t = threadIdx.x;
  int w = t >> 6, l = t & 63, l15 = l & 15, l4 = l >> 4;
  int wm = w >> 2, wn = w & 3; // 2 x 4 wave grid
  int r0 = t >> 3, c0 = t & 7;
  int tok0 = doc[mbase + r0];
  int tok1 = doc[mbase + 64 + r0];
  const float* Wb = wWi + d * 196608 + nbase * 256;
  f32x4 acc[4][2];
  #pragma unroll
  for (int a = 0; a < 4; ++a){ acc[a][0] = {0.f,0.f,0.f,0.f}; acc[a][1] = {0.f,0.f,0.f,0.f}; }
  for (int ki = 0; ki < 4; ++ki){
    int k0 = ki * 64;
    s16x8 a0 = cvt8(&emb[tok0 * 256 + k0 + c0 * 8]);
    s16x8 a1 = cvt8(&emb[tok1 * 256 + k0 + c0 * 8]);
    s16x8 b0 = cvt8(&Wb[r0 * 256 + k0 + c0 * 8]);
    s16x8 b1 = cvt8(&Wb[(64 + r0) * 256 + k0 + c0 * 8]);
    __syncthreads();
    int sw = c0 ^ (r0 & 7);
    *(s16x8*)&sA[(r0 * 8 + sw) * 8] = a0;
    *(s16x8*)&sA[((64 + r0) * 8 + sw) * 8] = a1;
    *(s16x8*)&sB[(r0 * 8 + sw) * 8] = b0;
    *(s16x8*)&sB[((64 + r0) * 8 + sw) * 8] = b1;
    __syncthreads();
    #pragma unroll
    for (int kt = 0; kt < 2; ++kt){
      int ch = kt * 4 + l4;
      s16x8 bfr[2];
      #pragma unroll
      for (int n2 = 0; n2 < 2; ++n2){
        int rr = wn * 32 + n2 * 16 + l15;
        bfr[n2] = *(const s16x8*)&sB[(rr * 8 + (ch ^ (rr & 7))) * 8];
      }
      #pragma unroll
      for (int m2 = 0; m2 < 4; ++m2){
        int rr = wm * 64 + m2 * 16 + l15;
        s16x8 af = *(const s16x8*)&sA[(rr * 8 + (ch ^ (rr & 7))) * 8];
        acc[m2][0] = mfma16(af, bfr[0], acc[m2][0]);
        acc[m2][1] = mfma16(af, bfr[1], acc[m2][1]);
      }
    }
  }
  int cgb = nbase + wn * 32;            // one gt per (nt,wn)
  int gt  = cgb >> 8;
  int whc = (cgb & 255) >> 5;
  float sg = (gt < 2) ? LOG2E : LOG2E2;
  int cg0 = cgb + l15, cg1 = cgb + 16 + l15;
  float bi0 = wbi[d * 768 + cg0] + ((gt < 2) ? wbh[d * 768 + cg0] : 0.f);
  float bi1 = wbi[d * 768 + cg1] + ((gt < 2) ? wbh[d * 768 + cg1] : 0.f);
  #pragma unroll
  for (int m2 = 0; m2 < 4; ++m2){
    #pragma unroll
    for (int i = 0; i < 4; ++i){
      int ml = wm * 64 + m2 * 16 + l4 * 4 + i;   // word index
      int base2 = ((d * 128 + ml) * 64 + mt) * 768 + gt * 256 + whc * 32;
      unsigned lo = f2b(sg * (acc[m2][0][i] + bi0));
      unsigned hi = f2b(sg * (acc[m2][1][i] + bi1));
      *(unsigned*)&gi[base2 + l15 * 2] = lo | (hi << 16);
    }
  }
}

// ---------------- word GRU recurrence: 128 steps, per-block = (dir, 16 sentences) ----
// grid = 8 (d = bid&1, g = bid>>1), block 512 (8 waves, wave w owns 32 hidden cols)
// R6 weight split (proven no-spill): r,z both halves + n jt0 in regs (160); n jt1 in LDS.
// NEW: 2-deep rotating prefetch of the af/bn1 LDS reads (hides ~120cy ds_read latency).
__global__ __launch_bounds__(512, 2) void k_rec(const float* __restrict__ wWh, const float* __restrict__ wbh,
                                                const u16* __restrict__ gi, u16* __restrict__ wenc){
  __shared__ u16 sBn1[32768];  // n-gate jt1 frags: [w][kt][lane*8] (64 KiB)
  __shared__ u16 sH0[4096];    // h buffers [16][256] bf16, XOR-swizzled (8 KiB each)
  __shared__ u16 sH1[4096];
  int bid = blockIdx.x; int d = bid & 1, g = bid >> 1;
  int t = threadIdx.x, w = t >> 6, l = t & 63, l15 = l & 15, l4 = l >> 4;
  int jb = w * 32;
  const float* Wh = wWh + d * 196608;
  // r,z gates (scaled log2e), both jt halves: 32 frags = 128 regs
  s16x8 bR[2][2][8];
  #pragma unroll
  for (int gt = 0; gt < 2; ++gt)
    #pragma unroll
    for (int jt = 0; jt < 2; ++jt)
      #pragma unroll
      for (int kt = 0; kt < 8; ++kt){
        int n = gt * 256 + jb + jt * 16 + l15;
        bR[gt][jt][kt] = cvt8s(&Wh[n * 256 + kt * 32 + l4 * 8], LOG2E);
      }
  // n gate jt0 (scaled 2log2e): 8 frags = 32 regs
  s16x8 bN0[8];
  #pragma unroll
  for (int kt = 0; kt < 8; ++kt){
    int n = 512 + jb + l15;
    bN0[kt] = cvt8s(&Wh[n * 256 + kt * 32 + l4 * 8], LOG2E2);
  }
  // n gate jt1 to LDS (linear per-lane layout: conflict-free)
  #pragma unroll
  for (int kt = 0; kt < 8; ++kt){
    int n = 512 + jb + 16 + l15;
    s16x8 v = cvt8s(&Wh[n * 256 + kt * 32 + l4 * 8], LOG2E2);
    *(s16x8*)&sBn1[((w * 8 + kt) * 64 + l) * 8] = v;
  }
  s16x8 z8 = {0,0,0,0,0,0,0,0};
  *(s16x8*)&sH0[t * 8] = z8;
  float hloc[2][4] = {{0.f,0.f,0.f,0.f},{0.f,0.f,0.f,0.f}};
  float bhn[2];
  #pragma unroll
  for (int jt = 0; jt < 2; ++jt)
    bhn[jt] = wbh[d * 768 + 512 + jb + jt * 16 + l15] * LOG2E2;  // pre-scaled

  // gi layout: [d][word][sent][768'] with jt-paired u32 at gt*256 + jb + l15*2
  const u16* gb = gi + d * 6291456 + (g * 16 + l4 * 4) * 768 + jb + l15 * 2;
  u16* wbase = wenc + ((g * 16 + l4 * 4) * 128) * 512 + d * 256 + jb + l15;
  const u16* bnbase = &sBn1[(w * 8 * 64 + l) * 8];   // + kt*512 elems
  int afxor = l15 & 7;
  int afrow = l15 * 256;

  // prefetch step 0's gate values (12 u32 per thread)
  unsigned g32[3][4];
  #pragma unroll
  for (int gt = 0; gt < 3; ++gt)
    #pragma unroll
    for (int i = 0; i < 4; ++i)
      g32[gt][i] = *(const unsigned*)&gb[gt * 256 + i * 768];
  __syncthreads();

  auto body = [&](int step, const u16* shc, u16* shn){
    f32x4 acc[3][2];
    #pragma unroll
    for (int a = 0; a < 3; ++a){ acc[a][0] = {0.f,0.f,0.f,0.f}; acc[a][1] = {0.f,0.f,0.f,0.f}; }
    // 2-deep rotating prefetch of af (h) and bn1 (n-gate jt1) LDS reads.
    s16x8 afb[2], bnb[2];
    afb[0] = *(const s16x8*)&shc[afrow + (((0 * 4 + l4) ^ afxor)) * 8];
    bnb[0] = *(const s16x8*)&bnbase[0 * 512];
    afb[1] = *(const s16x8*)&shc[afrow + (((1 * 4 + l4) ^ afxor)) * 8];
    bnb[1] = *(const s16x8*)&bnbase[1 * 512];
    #pragma unroll
    for (int kt = 0; kt < 8; ++kt){
      s16x8 af = afb[kt & 1];
      s16x8 bn1 = bnb[kt & 1];
      if (kt < 6){
        afb[kt & 1] = *(const s16x8*)&shc[afrow + ((((kt + 2) * 4 + l4) ^ afxor)) * 8];
        bnb[kt & 1] = *(const s16x8*)&bnbase[(kt + 2) * 512];
      }
      acc[0][0] = mfma16(af, bR[0][0][kt], acc[0][0]);
      acc[0][1] = mfma16(af, bR[0][1][kt], acc[0][1]);
      acc[1][0] = mfma16(af, bR[1][0][kt], acc[1][0]);
      acc[1][1] = mfma16(af, bR[1][1][kt], acc[1][1]);
      acc[2][0] = mfma16(af, bN0[kt], acc[2][0]);
      acc[2][1] = mfma16(af, bn1, acc[2][1]);
    }
    u16 hb[2][4];
    #pragma unroll
    for (int jt = 0; jt < 2; ++jt){
      #pragma unroll
      for (int i = 0; i < 4; ++i){
        unsigned v0 = g32[0][i], v1 = g32[1][i], v2 = g32[2][i];
        float ir, iz, inn;
        if (jt == 0){ ir = bits2f(v0 << 16); iz = bits2f(v1 << 16); inn = bits2f(v2 << 16); }
        else        { ir = bits2f(v0 & 0xffff0000u); iz = bits2f(v1 & 0xffff0000u); inn = bits2f(v2 & 0xffff0000u); }
        float r = sigm2(ir + acc[0][jt][i]);
        float z = sigm2(iz + acc[1][jt][i]);
        float nn = tanh2(inn + r * (acc[2][jt][i] + bhn[jt]));
        float h = nn + z * (hloc[jt][i] - nn);
        hloc[jt][i] = h;
      }
      // pack pairs with v_cvt_pk_bf16_f32 (RNE)
      __hip_bfloat162 p01 = __float22bfloat162_rn(float2{hloc[jt][0], hloc[jt][1]});
      __hip_bfloat162 p23 = __float22bfloat162_rn(float2{hloc[jt][2], hloc[jt][3]});
      unsigned b01, b23;
      __builtin_memcpy(&b01, &p01, 4); __builtin_memcpy(&b23, &p23, 4);
      hb[jt][0] = (u16)b01; hb[jt][1] = (u16)(b01 >> 16);
      hb[jt][2] = (u16)b23; hb[jt][3] = (u16)(b23 >> 16);
    }
    // prefetch next step's gate values; stay in flight across the raw barrier.
    // Final iteration reads past gi (lands in wenc region; values unused).
    {
      const u16* gp = gb + (step + 1) * 49152;
      #pragma unroll
      for (int gt = 0; gt < 3; ++gt)
        #pragma unroll
        for (int i = 0; i < 4; ++i)
          g32[gt][i] = *(const unsigned*)&gp[gt * 256 + i * 768];
    }
    #pragma unroll
    for (int jt = 0; jt < 2; ++jt){
      #pragma unroll
      for (int i = 0; i < 4; ++i){
        int s = l4 * 4 + i, c = jb + jt * 16 + l15;
        shn[s * 256 + ((c >> 3) ^ (s & 7)) * 8 + (c & 7)] = hb[jt][i];
        wbase[(i * 128 + step) * 512 + jt * 16] = hb[jt][i];  // fire-and-forget
      }
    }
    // drain only LDS (lgkm), NOT vmem; then raw barrier.
    asm volatile("s_waitcnt lgkmcnt(0)" ::: "memory");
    __builtin_amdgcn_s_barrier();
    __builtin_amdgcn_sched_barrier(0);
  };

  #pragma unroll 1
  for (int it = 0; it < 64; ++it){
    body(2 * it,     sH0, sH1);
    body(2 * it + 1, sH1, sH0);
  }
}

// ---------------- u_word = tanh(wordenc @ waW^T + wab); sent_summ = sum over words ---
// grid = 64 sentences * 4 ntiles ; block 512
__global__ __launch_bounds__(512, 2) void k_uword(const u16* __restrict__ wenc, const float* __restrict__ waW,
                                                  const float* __restrict__ wab, u16* __restrict__ ssum){
  __shared__ u16 sA[128 * 64], sB[128 * 64];
  __shared__ float red[128];
  int bid = blockIdx.x; int s = bid >> 2, nt = bid & 3; int nbase = nt * 128;
  int t = threadIdx.x, w = t >> 6, l = t & 63, l15 = l & 15, l4 = l >> 4;
  int wm = w >> 2, wn = w & 3;
  int r0 = t >> 3, c0 = t & 7;
  const u16* Arow = wenc + s * 65536;
  const float* Brow = waW + nbase * 512;
  if (t < 128) red[t] = 0.f;
  f32x4 acc[4][2];
  #pragma unroll
  for (int a = 0; a < 4; ++a){ acc[a][0] = {0.f,0.f,0.f,0.f}; acc[a][1] = {0.f,0.f,0.f,0.f}; }
  for (int ki = 0; ki < 8; ++ki){
    int k0 = ki * 64;
    s16x8 a0 = *(const s16x8*)&Arow[r0 * 512 + k0 + c0 * 8];
    s16x8 a1 = *(const s16x8*)&Arow[(64 + r0) * 512 + k0 + c0 * 8];
    s16x8 b0 = cvt8(&Brow[r0 * 512 + k0 + c0 * 8]);
    s16x8 b1 = cvt8(&Brow[(64 + r0) * 512 + k0 + c0 * 8]);
    __syncthreads();
    int sw = c0 ^ (r0 & 7);
    *(s16x8*)&sA[(r0 * 8 + sw) * 8] = a0;
    *(s16x8*)&sA[((64 + r0) * 8 + sw) * 8] = a1;
    *(s16x8*)&sB[(r0 * 8 + sw) * 8] = b0;
    *(s16x8*)&sB[((64 + r0) * 8 + sw) * 8] = b1;
    __syncthreads();
    #pragma unroll
    for (int kt = 0; kt < 2; ++kt){
      int ch = kt * 4 + l4;
      s16x8 bfr[2];
      #pragma unroll
      for (int n2 = 0; n2 < 2; ++n2){
        int rr = wn * 32 + n2 * 16 + l15;
        bfr[n2] = *(const s16x8*)&sB[(rr * 8 + (ch ^ (rr & 7))) * 8];
      }
      #pragma unroll
      for (int m2 = 0; m2 < 4; ++m2){
        int rr = wm * 64 + m2 * 16 + l15;
        s16x8 af = *(const s16x8*)&sA[(rr * 8 + (ch ^ (rr & 7))) * 8];
        acc[m2][0] = mfma16(af, bfr[0], acc[m2][0]);
        acc[m2][1] = mfma16(af, bfr[1], acc[m2][1]);
      }
    }
  }
  float bi0 = wab[nbase + wn * 32 + l15];
  float bi1 = wab[nbase + wn * 32 + 16 + l15];
  float p0 = 0.f, p1 = 0.f;
  #pragma unroll
  for (int m2 = 0; m2 < 4; ++m2){
    #pragma unroll
    for (int i = 0; i < 4; ++i){
      p0 += tanh_(acc[m2][0][i] + bi0);
      p1 += tanh_(acc[m2][1][i] + bi1);
    }
  }
  p0 += __shfl_xor(p0, 16); p0 += __shfl_xor(p0, 32);
  p1 += __shfl_xor(p1, 16); p1 += __shfl_xor(p1, 32);
  if (l4 == 0){
    atomicAdd(&red[wn * 32 + l15], p0);
    atomicAdd(&red[wn * 32 + 16 + l15], p1);
  }
  __syncthreads();
  if (t < 128) ssum[s * 512 + nbase + t] = f2b(red[t]);
}

// ---------------- sentence GRU (zero state): sentenc ---------------------------------
// grid = 2 dirs * 8 jblocks(64) ; block 512 (waves: 4M x 2J)
__global__ __launch_bounds__(512, 2) void k_sent(const u16* __restrict__ ssum, const float* __restrict__ sWi,
                                                 const float* __restrict__ sbi, const float* __restrict__ sbh,
                                                 u16* __restrict__ senc){
  __shared__ u16 sA[64 * 512]; // 64 KiB, swizzled
  int bid = blockIdx.x; int d = bid >> 3, jb8 = bid & 7; int jbase = jb8 * 64;
  int t = threadIdx.x, w = t >> 6, l = t & 63, l15 = l & 15, l4 = l >> 4;
  int wm = w >> 1, wj = w & 1;
  #pragma unroll
  for (int j = 0; j < 8; ++j){
    int q = j * 512 + t, r = q >> 6, c = q & 63;
    s16x8 v = *(const s16x8*)&ssum[r * 512 + c * 8];
    *(s16x8*)&sA[(r * 64 + (c ^ (r & 7))) * 8] = v;
  }
  __syncthreads();
  const float* Wd = sWi + d * 786432;
  f32x4 acc[3][2];
  #pragma unroll
  for (int a = 0; a < 3; ++a){ acc[a][0] = {0.f,0.f,0.f,0.f}; acc[a][1] = {0.f,0.f,0.f,0.f}; }
  int ra = wm * 16 + l15;
  #pragma unroll 4
  for (int kt = 0; kt < 16; ++kt){
    int ch = kt * 4 + l4;
    s16x8 af = *(const s16x8*)&sA[(ra * 64 + (ch ^ (ra & 7))) * 8];
    #pragma unroll
    for (int gt = 0; gt < 3; ++gt){
      #pragma unroll
      for (int jt = 0; jt < 2; ++jt){
        int n = gt * 512 + jbase + wj * 32 + jt * 16 + l15;
        s16x8 bf = cvt8(&Wd[n * 512 + kt * 32 + l4 * 8]);
        acc[gt][jt] = mfma16(af, bf, acc[gt][jt]);
      }
    }
  }
  float biv[3][2], bhv[3][2];
  #pragma unroll
  for (int gt = 0; gt < 3; ++gt){
    #pragma unroll
    for (int jt = 0; jt < 2; ++jt){
      int n = gt * 512 + jbase + wj * 32 + jt * 16 + l15;
      biv[gt][jt] = sbi[d * 1536 + n];
      bhv[gt][jt] = sbh[d * 1536 + n];
    }
  }
  #pragma unroll
  for (int jt = 0; jt < 2; ++jt){
    #pragma unroll
    for (int i = 0; i < 4; ++i){
      float r_ = sigm(acc[0][jt][i] + biv[0][jt] + bhv[0][jt]);
      float z_ = sigm(acc[1][jt][i] + biv[1][jt] + bhv[1][jt]);
      float n_ = tanh_(acc[2][jt][i] + biv[2][jt] + r_ * bhv[2][jt]);
      float sh = (1.f - z_) * n_;
      int srow = wm * 16 + l4 * 4 + i;
      senc[srow * 1024 + d * 512 + jbase + wj * 32 + jt * 16 + l15] = f2b(sh);
    }
  }
}

// ---------------- u_sent = tanh(sentenc @ saW^T + sab); doc = sum over sentences -----
// grid = 8 ntiles ; block 512 (waves 2M x 4N)
__global__ __launch_bounds__(512, 2) void k_usent(const u16* __restrict__ senc, const float* __restrict__ saW,
                                                  const float* __restrict__ sab, float* __restrict__ docv){
  __shared__ u16 sA[64 * 1024]; // 128 KiB, swizzled
  __shared__ float red[128];
  int bid = blockIdx.x; int nbase = bid * 128;
  int t = threadIdx.x, w = t >> 6, l = t & 63, l15 = l & 15, l4 = l >> 4;
  int wm = w >> 2, wn = w & 3;
  if (t < 128) red[t] = 0.f;
  #pragma unroll
  for (int j = 0; j < 16; ++j){
    int q = j * 512 + t, r = q >> 7, c = q & 127;
    s16x8 v = *(const s16x8*)&senc[r * 1024 + c * 8];
    *(s16x8*)&sA[(r * 128 + (c ^ (r & 7))) * 8] = v;
  }
  __syncthreads();
  f32x4 acc[2][2];
  #pragma unroll
  for (int a = 0; a < 2; ++a){ acc[a][0] = {0.f,0.f,0.f,0.f}; acc[a][1] = {0.f,0.f,0.f,0.f}; }
  #pragma unroll 4
  for (int kt = 0; kt < 32; ++kt){
    int ch = kt * 4 + l4;
    s16x8 af[2];
    #pragma unroll
    for (int mt = 0; mt < 2; ++mt){
      int r = wm * 32 + mt * 16 + l15;
      af[mt] = *(const s16x8*)&sA[(r * 128 + (ch ^ (r & 7))) * 8];
    }
    #pragma unroll
    for (int nt = 0; nt < 2; ++nt){
      int n = nbase + wn * 32 + nt * 16 + l15;
      s16x8 bf = cvt8(&saW[n * 1024 + kt * 32 + l4 * 8]);
      acc[0][nt] = mfma16(af[0], bf, acc[0][nt]);
      acc[1][nt] = mfma16(af[1], bf, acc[1][nt]);
    }
  }
  float b0 = sab[nbase + wn * 32 + l15];
  float b1 = sab[nbase + wn * 32 + 16 + l15];
  float p0 = 0.f, p1 = 0.f;
  #pragma unroll
  for (int mt = 0; mt < 2; ++mt){
    #pragma unroll
    for (int i = 0; i < 4; ++i){
      p0 += tanh_(acc[mt][0][i] + b0);
      p1 += tanh_(acc[mt][1][i] + b1);
    }
  }
  p0 += __shfl_xor(p0, 16); p0 += __shfl_xor(p0, 32);
  p1 += __shfl_xor(p1, 16); p1 += __shfl_xor(p1, 32);
  if (l4 == 0){
    atomicAdd(&red[wn * 32 + l15], p0);
    atomicAdd(&red[wn * 32 + 16 + l15], p1);
  }
  __syncthreads();
  if (t < 128) docv[nbase + t] = red[t];
}

// ---------------- logits + log_softmax ----------------------------------------------
__global__ __launch_bounds__(256) void k_final(const float* __restrict__ docv, const float* __restrict__ doW,
                                               const float* __restrict__ dob, float* __restrict__ out){
  __shared__ float lg[16];
  int w = threadIdx.x >> 6, l = threadIdx.x & 63;
  for (int c = w; c < 13; c += 4){
    float p = 0.f;
    for (int j = 0; j < 16; ++j){
      int k = j * 64 + l;
      p += docv[k] * doW[c * 1024 + k];
    }
    for (int o = 32; o >= 1; o >>= 1) p += __shfl_xor(p, o);
    if (l == 0) lg[c] = p + dob[c];
  }
  __syncthreads();
  if (threadIdx.x == 0){
    float m = lg[0];
    for (int c = 1; c < 13; ++c) m = fmaxf(m, lg[c]);
    float s = 0.f;
    for (int c = 0; c < 13; ++c) s += __expf(lg[c] - m);
    float ls = logf(s);
    for (int c = 0; c < 13; ++c) out[8256 + c] = lg[c] - m - ls;
  }
}

extern "C" void kernel_launch(void* const* d_in, const int* in_sizes, int n_in,
                              void* d_out, int out_size, void* d_ws, size_t ws_size,
                              hipStream_t stream) {
  (void)in_sizes; (void)n_in; (void)out_size; (void)ws_size;
  const int*   doc = (const int*)d_in[0];
  const float* emb = (const float*)d_in[1];
  const float* wWi = (const float*)d_in[2];
  const float* wWh = (const float*)d_in[3];
  const float* wbi = (const float*)d_in[4];
  const float* wbh = (const float*)d_in[5];
  const float* sWi = (const float*)d_in[6];
  // d_in[7] = s_Wh unused (sentence GRU sees zero state)
  const float* sbi = (const float*)d_in[8];
  const float* sbh = (const float*)d_in[9];
  const float* waW = (const float*)d_in[10];
  const float* wab = (const float*)d_in[11];
  // d_in[12] = uw_W unused (softmax over size-1 axis)
  const float* saW = (const float*)d_in[13];
  const float* sab = (const float*)d_in[14];
  // d_in[15] = us_W unused
  const float* doW = (const float*)d_in[16];
  const float* dob = (const float*)d_in[17];
  float* out = (float*)d_out;
  char* ws = (char*)d_ws;
  u16* gi    = (u16*)(ws);                    // 2*128*64*768 bf16 = 25,165,824 B
  u16* wenc  = (u16*)(ws + 25165824);         // 64*128*512 bf16  =  8,388,608 B
  u16* ssumv = (u16*)(ws + 33554432);         // 64*512 bf16      =     65,536 B
  u16* sencv = (u16*)(ws + 33619968);         // 64*1024 bf16     =    131,072 B
  float* docv = (float*)(ws + 33751040);      // 1024 f32         =      4,096 B

  k_ones  <<<17, 512, 0, stream>>>(out);
  k_gi    <<<768, 512, 0, stream>>>(doc, emb, wWi, wbi, wbh, gi);
  k_rec   <<<8, 512, 0, stream>>>(wWh, wbh, gi, wenc);
  k_uword <<<256, 512, 0, stream>>>(wenc, waW, wab, ssumv);
  k_sent  <<<16, 512, 0, stream>>>(ssumv, sWi, sbi, sbh, sencv);
  k_usent <<<8, 512, 0, stream>>>(sencv, saW, sab, docv);
  k_final <<<1, 256, 0, stream>>>(docv, doW, dob, out);
}

// Round 9
// 453.421 us; speedup vs baseline: 1.2471x; 1.0784x over previous
//
#include <hip/hip_runtime.h>
#include <hip/hip_bf16.h>

typedef unsigned short u16;
typedef __attribute__((ext_vector_type(8))) short s16x8;
typedef __attribute__((ext_vector_type(4))) float f32x4;
typedef __attribute__((ext_vector_type(4))) unsigned u32x4;

__device__ __forceinline__ float b2f(u16 v){
  unsigned u = ((unsigned)v) << 16; float f; __builtin_memcpy(&f, &u, 4); return f;
}
__device__ __forceinline__ float bits2f(unsigned u){
  float f; __builtin_memcpy(&f, &u, 4); return f;
}
__device__ __forceinline__ u16 f2b(float f){
  unsigned u; __builtin_memcpy(&u, &f, 4);
  unsigned r = (u + 0x7FFFu + ((u >> 16) & 1u)) >> 16; return (u16)r;
}
// pack 2 f32 -> u32 of 2 bf16 (v_cvt_pk_bf16_f32, RNE); x in low half
__device__ __forceinline__ unsigned pk2(float x, float y){
  __hip_bfloat162 q = __float22bfloat162_rn(float2{x, y});
  unsigned r; __builtin_memcpy(&r, &q, 4); return r;
}
// 8 consecutive f32 -> 8 bf16 (RNE) via 4x cvt_pk
__device__ __forceinline__ s16x8 cvt8(const float* __restrict__ p){
  f32x4 a = *(const f32x4*)p;
  f32x4 b = *(const f32x4*)(p + 4);
  u32x4 u; u[0]=pk2(a[0],a[1]); u[1]=pk2(a[2],a[3]); u[2]=pk2(b[0],b[1]); u[3]=pk2(b[2],b[3]);
  s16x8 r; __builtin_memcpy(&r, &u, 16); return r;
}
// scaled variant (for log2e-folded GRU weights)
__device__ __forceinline__ s16x8 cvt8s(const float* __restrict__ p, float s){
  f32x4 a = *(const f32x4*)p;
  f32x4 b = *(const f32x4*)(p + 4);
  u32x4 u; u[0]=pk2(a[0]*s,a[1]*s); u[1]=pk2(a[2]*s,a[3]*s); u[2]=pk2(b[0]*s,b[1]*s); u[3]=pk2(b[2]*s,b[3]*s);
  s16x8 r; __builtin_memcpy(&r, &u, 16); return r;
}
#define LOG2E  1.4426950408889634f
#define LOG2E2 2.8853900817779268f
// pre-activations arrive scaled by log2e (sigm) / 2*log2e (tanh)
__device__ __forceinline__ float sigm2(float x){        // = 1/(1+e^-a), x = log2e*a
  float e = __builtin_amdgcn_exp2f(-x);
  return __builtin_amdgcn_rcpf(1.f + e);
}
__device__ __forceinline__ float tanh2(float y){        // = tanh(a), y = 2*log2e*a
  float e = __builtin_amdgcn_exp2f(y);
  return 1.f - 2.f * __builtin_amdgcn_rcpf(e + 1.f);
}
// non-scaled versions for the small kernels
__device__ __forceinline__ float sigm(float x){
  float e = __builtin_amdgcn_exp2f(-x * LOG2E);
  return __builtin_amdgcn_rcpf(1.f + e);
}
__device__ __forceinline__ float tanh_(float x){
  float e = __builtin_amdgcn_exp2f(x * LOG2E2);
  return 1.f - 2.f * __builtin_amdgcn_rcpf(e + 1.f);
}
__device__ __forceinline__ f32x4 mfma16(s16x8 a, s16x8 b, f32x4 c){
  return __builtin_amdgcn_mfma_f32_16x16x32_bf16(a, b, c, 0, 0, 0);
}

// ---------------- gi = log2e-scaled (emb[doc] @ Wi^T + bi (+bh for r,z)) -------------
// grid = 2 dirs * 64 mtiles(=sentences) * 6 ntiles ; block 512
// gi layout (bf16): [d][word][sent][ gt*256 + whc*32 + l15*2 + jt ]  (jt-pairs in u32)
__global__ __launch_bounds__(512, 2) void k_gi(const int* __restrict__ doc, const float* __restrict__ emb,
                                               const float* __restrict__ wWi, const float* __restrict__ wbi,
                                               const float* __restrict__ wbh, u16* __restrict__ gi){
  __shared__ u16 sA[128 * 64];
  __shared__ u16 sB[128 * 64];
  int bid = blockIdx.x;
  int d = bid / 384; int rem = bid % 384;
  int mt = rem / 6, nt = rem % 6;
  int mbase = mt * 128, nbase = nt * 128;
  int t = threadIdx.x;
  int w = t >> 6, l = t & 63, l15 = l & 15, l4 = l >> 4;
  int wm = w >> 2, wn = w & 3; // 2 x 4 wave grid
  int r0 = t >> 3, c0 = t & 7;
  int tok0 = doc[mbase + r0];
  int tok1 = doc[mbase + 64 + r0];
  const float* Wb = wWi + d * 196608 + nbase * 256;
  f32x4 acc[4][2];
  #pragma unroll
  for (int a = 0; a < 4; ++a){ acc[a][0] = {0.f,0.f,0.f,0.f}; acc[a][1] = {0.f,0.f,0.f,0.f}; }
  for (int ki = 0; ki < 4; ++ki){
    int k0 = ki * 64;
    s16x8 a0 = cvt8(&emb[tok0 * 256 + k0 + c0 * 8]);
    s16x8 a1 = cvt8(&emb[tok1 * 256 + k0 + c0 * 8]);
    s16x8 b0 = cvt8(&Wb[r0 * 256 + k0 + c0 * 8]);
    s16x8 b1 = cvt8(&Wb[(64 + r0) * 256 + k0 + c0 * 8]);
    __syncthreads();
    int sw = c0 ^ (r0 & 7);
    *(s16x8*)&sA[(r0 * 8 + sw) * 8] = a0;
    *(s16x8*)&sA[((64 + r0) * 8 + sw) * 8] = a1;
    *(s16x8*)&sB[(r0 * 8 + sw) * 8] = b0;
    *(s16x8*)&sB[((64 + r0) * 8 + sw) * 8] = b1;
    __syncthreads();
    #pragma unroll
    for (int kt = 0; kt < 2; ++kt){
      int ch = kt * 4 + l4;
      s16x8 bfr[2];
      #pragma unroll
      for (int n2 = 0; n2 < 2; ++n2){
        int rr = wn * 32 + n2 * 16 + l15;
        bfr[n2] = *(const s16x8*)&sB[(rr * 8 + (ch ^ (rr & 7))) * 8];
      }
      #pragma unroll
      for (int m2 = 0; m2 < 4; ++m2){
        int rr = wm * 64 + m2 * 16 + l15;
        s16x8 af = *(const s16x8*)&sA[(rr * 8 + (ch ^ (rr & 7))) * 8];
        acc[m2][0] = mfma16(af, bfr[0], acc[m2][0]);
        acc[m2][1] = mfma16(af, bfr[1], acc[m2][1]);
      }
    }
  }
  int cgb = nbase + wn * 32;            // one gt per (nt,wn)
  int gt  = cgb >> 8;
  int whc = (cgb & 255) >> 5;
  float sg = (gt < 2) ? LOG2E : LOG2E2;
  int cg0 = cgb + l15, cg1 = cgb + 16 + l15;
  float bi0 = wbi[d * 768 + cg0] + ((gt < 2) ? wbh[d * 768 + cg0] : 0.f);
  float bi1 = wbi[d * 768 + cg1] + ((gt < 2) ? wbh[d * 768 + cg1] : 0.f);
  #pragma unroll
  for (int m2 = 0; m2 < 4; ++m2){
    #pragma unroll
    for (int i = 0; i < 4; ++i){
      int ml = wm * 64 + m2 * 16 + l4 * 4 + i;   // word index
      int base2 = ((d * 128 + ml) * 64 + mt) * 768 + gt * 256 + whc * 32;
      *(unsigned*)&gi[base2 + l15 * 2] = pk2(sg * (acc[m2][0][i] + bi0),
                                             sg * (acc[m2][1][i] + bi1));
    }
  }
}

// ---------------- word GRU recurrence: 128 steps, per-block = (dir, 16 sentences) ----
// grid = 8 (d = bid&1, g = bid>>1), block 512 (8 waves, wave w owns 32 hidden cols)
// R6 weight split (best known): r,z both halves + n jt0 in regs (160 VGPR); n jt1 in LDS.
// NEW: 4-distinct bank-swizzle key (s ^ (s>>2))&7 kills the 4-way ds_write conflict.
__global__ __launch_bounds__(512, 2) void k_rec(const float* __restrict__ wWh, const float* __restrict__ wbh,
                                                const u16* __restrict__ gi, u16* __restrict__ wenc){
  __shared__ u16 sBn1[32768];  // n-gate jt1 frags: [w][kt][lane*8] (64 KiB)
  __shared__ u16 sH0[4096];    // h buffers [16][256] bf16, key-swizzled (8 KiB each)
  __shared__ u16 sH1[4096];
  int bid = blockIdx.x; int d = bid & 1, g = bid >> 1;
  int t = threadIdx.x, w = t >> 6, l = t & 63, l15 = l & 15, l4 = l >> 4;
  int jb = w * 32;
  const float* Wh = wWh + d * 196608;
  // r,z gates (scaled log2e), both jt halves: 32 frags = 128 regs
  s16x8 bR[2][2][8];
  #pragma unroll
  for (int gt = 0; gt < 2; ++gt)
    #pragma unroll
    for (int jt = 0; jt < 2; ++jt)
      #pragma unroll
      for (int kt = 0; kt < 8; ++kt){
        int n = gt * 256 + jb + jt * 16 + l15;
        bR[gt][jt][kt] = cvt8s(&Wh[n * 256 + kt * 32 + l4 * 8], LOG2E);
      }
  // n gate jt0 (scaled 2log2e): 8 frags = 32 regs
  s16x8 bN0[8];
  #pragma unroll
  for (int kt = 0; kt < 8; ++kt){
    int n = 512 + jb + l15;
    bN0[kt] = cvt8s(&Wh[n * 256 + kt * 32 + l4 * 8], LOG2E2);
  }
  // n gate jt1 to LDS (linear per-lane layout: conflict-free)
  #pragma unroll
  for (int kt = 0; kt < 8; ++kt){
    int n = 512 + jb + 16 + l15;
    s16x8 v = cvt8s(&Wh[n * 256 + kt * 32 + l4 * 8], LOG2E2);
    *(s16x8*)&sBn1[((w * 8 + kt) * 64 + l) * 8] = v;
  }
  s16x8 z8 = {0,0,0,0,0,0,0,0};
  *(s16x8*)&sH0[t * 8] = z8;
  float hloc[2][4] = {{0.f,0.f,0.f,0.f},{0.f,0.f,0.f,0.f}};
  float bhn[2];
  #pragma unroll
  for (int jt = 0; jt < 2; ++jt)
    bhn[jt] = wbh[d * 768 + 512 + jb + jt * 16 + l15] * LOG2E2;  // pre-scaled

  // swizzle keys: read key for row l15; write keys for rows s = l4*4+i.
  // key(s) = (s ^ (s>>2)) & 7 maps {i,4+i,8+i,12+i} to 4 DISTINCT values -> no
  // 4-way write conflict (old key s&7 collapsed them to 2).
  int rkey = (l15 ^ (l15 >> 2)) & 7;
  int skey[4];
  #pragma unroll
  for (int i = 0; i < 4; ++i){ int s = l4 * 4 + i; skey[i] = (s ^ (s >> 2)) & 7; }

  // gi layout: [d][word][sent][768'] with jt-paired u32 at gt*256 + jb + l15*2
  const u16* gb = gi + d * 6291456 + (g * 16 + l4 * 4) * 768 + jb + l15 * 2;
  u16* wbase = wenc + ((g * 16 + l4 * 4) * 128) * 512 + d * 256 + jb + l15;

  // prefetch step 0's gate values (12 u32 per thread)
  unsigned g32[3][4];
  #pragma unroll
  for (int gt = 0; gt < 3; ++gt)
    #pragma unroll
    for (int i = 0; i < 4; ++i)
      g32[gt][i] = *(const unsigned*)&gb[gt * 256 + i * 768];
  __syncthreads();

  auto body = [&](int step, const u16* shc, u16* shn){
    f32x4 acc[3][2];
    #pragma unroll
    for (int a = 0; a < 3; ++a){ acc[a][0] = {0.f,0.f,0.f,0.f}; acc[a][1] = {0.f,0.f,0.f,0.f}; }
    #pragma unroll
    for (int kt = 0; kt < 8; ++kt){
      int ch = kt * 4 + l4;
      s16x8 af = *(const s16x8*)&shc[l15 * 256 + (ch ^ rkey) * 8];
      acc[0][0] = mfma16(af, bR[0][0][kt], acc[0][0]);
      acc[0][1] = mfma16(af, bR[0][1][kt], acc[0][1]);
      acc[1][0] = mfma16(af, bR[1][0][kt], acc[1][0]);
      acc[1][1] = mfma16(af, bR[1][1][kt], acc[1][1]);
      acc[2][0] = mfma16(af, bN0[kt], acc[2][0]);
      s16x8 bn1 = *(const s16x8*)&sBn1[((w * 8 + kt) * 64 + l) * 8];
      acc[2][1] = mfma16(af, bn1, acc[2][1]);
    }
    u16 hb[2][4];
    #pragma unroll
    for (int jt = 0; jt < 2; ++jt){
      #pragma unroll
      for (int i = 0; i < 4; ++i){
        unsigned v0 = g32[0][i], v1 = g32[1][i], v2 = g32[2][i];
        float ir, iz, inn;
        if (jt == 0){ ir = bits2f(v0 << 16); iz = bits2f(v1 << 16); inn = bits2f(v2 << 16); }
        else        { ir = bits2f(v0 & 0xffff0000u); iz = bits2f(v1 & 0xffff0000u); inn = bits2f(v2 & 0xffff0000u); }
        float r = sigm2(ir + acc[0][jt][i]);
        float z = sigm2(iz + acc[1][jt][i]);
        float nn = tanh2(inn + r * (acc[2][jt][i] + bhn[jt]));
        float h = nn + z * (hloc[jt][i] - nn);
        hloc[jt][i] = h;
      }
      unsigned b01 = pk2(hloc[jt][0], hloc[jt][1]);
      unsigned b23 = pk2(hloc[jt][2], hloc[jt][3]);
      hb[jt][0] = (u16)b01; hb[jt][1] = (u16)(b01 >> 16);
      hb[jt][2] = (u16)b23; hb[jt][3] = (u16)(b23 >> 16);
    }
    // prefetch next step's gate values; stay in flight across the raw barrier.
    // Final iteration reads past gi (lands in wenc region; values unused).
    {
      const u16* gp = gb + (step + 1) * 49152;
      #pragma unroll
      for (int gt = 0; gt < 3; ++gt)
        #pragma unroll
        for (int i = 0; i < 4; ++i)
          g32[gt][i] = *(const unsigned*)&gp[gt * 256 + i * 768];
    }
    #pragma unroll
    for (int jt = 0; jt < 2; ++jt){
      #pragma unroll
      for (int i = 0; i < 4; ++i){
        int s = l4 * 4 + i, c = jb + jt * 16 + l15;
        shn[s * 256 + ((c >> 3) ^ skey[i]) * 8 + (c & 7)] = hb[jt][i];
        wbase[(i * 128 + step) * 512 + jt * 16] = hb[jt][i];  // fire-and-forget
      }
    }
    // drain only LDS (lgkm), NOT vmem; then raw barrier.
    asm volatile("s_waitcnt lgkmcnt(0)" ::: "memory");
    __builtin_amdgcn_s_barrier();
    __builtin_amdgcn_sched_barrier(0);
  };

  #pragma unroll 1
  for (int it = 0; it < 64; ++it){
    body(2 * it,     sH0, sH1);
    body(2 * it + 1, sH1, sH0);
  }
}

// ---------------- u_word = tanh(wordenc @ waW^T + wab); sent_summ = sum over words ---
// grid = 64 sentences * 4 ntiles ; block 512.  Also writes word_w ones (k_ones folded).
__global__ __launch_bounds__(512, 2) void k_uword(const u16* __restrict__ wenc, const float* __restrict__ waW,
                                                  const float* __restrict__ wab, u16* __restrict__ ssum,
                                                  float* __restrict__ outw){
  __shared__ u16 sA[128 * 64], sB[128 * 64];
  __shared__ float red[128];
  int bid = blockIdx.x; int s = bid >> 2, nt = bid & 3; int nbase = nt * 128;
  int t = threadIdx.x, w = t >> 6, l = t & 63, l15 = l & 15, l4 = l >> 4;
  int wm = w >> 2, wn = w & 3;
  int r0 = t >> 3, c0 = t & 7;
  const u16* Arow = wenc + s * 65536;
  const float* Brow = waW + nbase * 512;
  if (t < 128) red[t] = 0.f;
  if (t < 32) outw[s * 128 + nt * 32 + t] = 1.0f;   // word_w ones
  f32x4 acc[4][2];
  #pragma unroll
  for (int a = 0; a < 4; ++a){ acc[a][0] = {0.f,0.f,0.f,0.f}; acc[a][1] = {0.f,0.f,0.f,0.f}; }
  for (int ki = 0; ki < 8; ++ki){
    int k0 = ki * 64;
    s16x8 a0 = *(const s16x8*)&Arow[r0 * 512 + k0 + c0 * 8];
    s16x8 a1 = *(const s16x8*)&Arow[(64 + r0) * 512 + k0 + c0 * 8];
    s16x8 b0 = cvt8(&Brow[r0 * 512 + k0 + c0 * 8]);
    s16x8 b1 = cvt8(&Brow[(64 + r0) * 512 + k0 + c0 * 8]);
    __syncthreads();
    int sw = c0 ^ (r0 & 7);
    *(s16x8*)&sA[(r0 * 8 + sw) * 8] = a0;
    *(s16x8*)&sA[((64 + r0) * 8 + sw) * 8] = a1;
    *(s16x8*)&sB[(r0 * 8 + sw) * 8] = b0;
    *(s16x8*)&sB[((64 + r0) * 8 + sw) * 8] = b1;
    __syncthreads();
    #pragma unroll
    for (int kt = 0; kt < 2; ++kt){
      int ch = kt * 4 + l4;
      s16x8 bfr[2];
      #pragma unroll
      for (int n2 = 0; n2 < 2; ++n2){
        int rr = wn * 32 + n2 * 16 + l15;
        bfr[n2] = *(const s16x8*)&sB[(rr * 8 + (ch ^ (rr & 7))) * 8];
      }
      #pragma unroll
      for (int m2 = 0; m2 < 4; ++m2){
        int rr = wm * 64 + m2 * 16 + l15;
        s16x8 af = *(const s16x8*)&sA[(rr * 8 + (ch ^ (rr & 7))) * 8];
        acc[m2][0] = mfma16(af, bfr[0], acc[m2][0]);
        acc[m2][1] = mfma16(af, bfr[1], acc[m2][1]);
      }
    }
  }
  float bi0 = wab[nbase + wn * 32 + l15];
  float bi1 = wab[nbase + wn * 32 + 16 + l15];
  float p0 = 0.f, p1 = 0.f;
  #pragma unroll
  for (int m2 = 0; m2 < 4; ++m2){
    #pragma unroll
    for (int i = 0; i < 4; ++i){
      p0 += tanh_(acc[m2][0][i] + bi0);
      p1 += tanh_(acc[m2][1][i] + bi1);
    }
  }
  p0 += __shfl_xor(p0, 16); p0 += __shfl_xor(p0, 32);
  p1 += __shfl_xor(p1, 16); p1 += __shfl_xor(p1, 32);
  if (l4 == 0){
    atomicAdd(&red[wn * 32 + l15], p0);
    atomicAdd(&red[wn * 32 + 16 + l15], p1);
  }
  __syncthreads();
  if (t < 128) ssum[s * 512 + nbase + t] = f2b(red[t]);
}

// ---------------- sentence GRU (zero state): sentenc ---------------------------------
// grid = 2 dirs * 8 jblocks(64) ; block 512 (waves: 4M x 2J)
__global__ __launch_bounds__(512, 2) void k_sent(const u16* __restrict__ ssum, const float* __restrict__ sWi,
                                                 const float* __restrict__ sbi, const float* __restrict__ sbh,
                                                 u16* __restrict__ senc){
  __shared__ u16 sA[64 * 512]; // 64 KiB, swizzled
  int bid = blockIdx.x; int d = bid >> 3, jb8 = bid & 7; int jbase = jb8 * 64;
  int t = threadIdx.x, w = t >> 6, l = t & 63, l15 = l & 15, l4 = l >> 4;
  int wm = w >> 1, wj = w & 1;
  #pragma unroll
  for (int j = 0; j < 8; ++j){
    int q = j * 512 + t, r = q >> 6, c = q & 63;
    s16x8 v = *(const s16x8*)&ssum[r * 512 + c * 8];
    *(s16x8*)&sA[(r * 64 + (c ^ (r & 7))) * 8] = v;
  }
  __syncthreads();
  const float* Wd = sWi + d * 786432;
  f32x4 acc[3][2];
  #pragma unroll
  for (int a = 0; a < 3; ++a){ acc[a][0] = {0.f,0.f,0.f,0.f}; acc[a][1] = {0.f,0.f,0.f,0.f}; }
  int ra = wm * 16 + l15;
  #pragma unroll 4
  for (int kt = 0; kt < 16; ++kt){
    int ch = kt * 4 + l4;
    s16x8 af = *(const s16x8*)&sA[(ra * 64 + (ch ^ (ra & 7))) * 8];
    #pragma unroll
    for (int gt = 0; gt < 3; ++gt){
      #pragma unroll
      for (int jt = 0; jt < 2; ++jt){
        int n = gt * 512 + jbase + wj * 32 + jt * 16 + l15;
        s16x8 bf = cvt8(&Wd[n * 512 + kt * 32 + l4 * 8]);
        acc[gt][jt] = mfma16(af, bf, acc[gt][jt]);
      }
    }
  }
  float biv[3][2], bhv[3][2];
  #pragma unroll
  for (int gt = 0; gt < 3; ++gt){
    #pragma unroll
    for (int jt = 0; jt < 2; ++jt){
      int n = gt * 512 + jbase + wj * 32 + jt * 16 + l15;
      biv[gt][jt] = sbi[d * 1536 + n];
      bhv[gt][jt] = sbh[d * 1536 + n];
    }
  }
  #pragma unroll
  for (int jt = 0; jt < 2; ++jt){
    #pragma unroll
    for (int i = 0; i < 4; ++i){
      float r_ = sigm(acc[0][jt][i] + biv[0][jt] + bhv[0][jt]);
      float z_ = sigm(acc[1][jt][i] + biv[1][jt] + bhv[1][jt]);
      float n_ = tanh_(acc[2][jt][i] + biv[2][jt] + r_ * bhv[2][jt]);
      float sh = (1.f - z_) * n_;
      int srow = wm * 16 + l4 * 4 + i;
      senc[srow * 1024 + d * 512 + jbase + wj * 32 + jt * 16 + l15] = f2b(sh);
    }
  }
}

// ---------------- u_sent = tanh(sentenc @ saW^T + sab); doc = sum over sentences -----
// grid = 8 ntiles ; block 512 (waves 2M x 4N).  Also writes sent_w ones.
__global__ __launch_bounds__(512, 2) void k_usent(const u16* __restrict__ senc, const float* __restrict__ saW,
                                                  const float* __restrict__ sab, float* __restrict__ docv,
                                                  float* __restrict__ outw){
  __shared__ u16 sA[64 * 1024]; // 128 KiB, swizzled
  __shared__ float red[128];
  int bid = blockIdx.x; int nbase = bid * 128;
  int t = threadIdx.x, w = t >> 6, l = t & 63, l15 = l & 15, l4 = l >> 4;
  int wm = w >> 2, wn = w & 3;
  if (t < 128) red[t] = 0.f;
  if (t < 8) outw[8192 + bid * 8 + t] = 1.0f;   // sent_w ones
  #pragma unroll
  for (int j = 0; j < 16; ++j){
    int q = j * 512 + t, r = q >> 7, c = q & 127;
    s16x8 v = *(const s16x8*)&senc[r * 1024 + c * 8];
    *(s16x8*)&sA[(r * 128 + (c ^ (r & 7))) * 8] = v;
  }
  __syncthreads();
  f32x4 acc[2][2];
  #pragma unroll
  for (int a = 0; a < 2; ++a){ acc[a][0] = {0.f,0.f,0.f,0.f}; acc[a][1] = {0.f,0.f,0.f,0.f}; }
  #pragma unroll 4
  for (int kt = 0; kt < 32; ++kt){
    int ch = kt * 4 + l4;
    s16x8 af[2];
    #pragma unroll
    for (int mt = 0; mt < 2; ++mt){
      int r = wm * 32 + mt * 16 + l15;
      af[mt] = *(const s16x8*)&sA[(r * 128 + (ch ^ (r & 7))) * 8];
    }
    #pragma unroll
    for (int nt = 0; nt < 2; ++nt){
      int n = nbase + wn * 32 + nt * 16 + l15;
      s16x8 bf = cvt8(&saW[n * 1024 + kt * 32 + l4 * 8]);
      acc[0][nt] = mfma16(af[0], bf, acc[0][nt]);
      acc[1][nt] = mfma16(af[1], bf, acc[1][nt]);
    }
  }
  float b0 = sab[nbase + wn * 32 + l15];
  float b1 = sab[nbase + wn * 32 + 16 + l15];
  float p0 = 0.f, p1 = 0.f;
  #pragma unroll
  for (int mt = 0; mt < 2; ++mt){
    #pragma unroll
    for (int i = 0; i < 4; ++i){
      p0 += tanh_(acc[mt][0][i] + b0);
      p1 += tanh_(acc[mt][1][i] + b1);
    }
  }
  p0 += __shfl_xor(p0, 16); p0 += __shfl_xor(p0, 32);
  p1 += __shfl_xor(p1, 16); p1 += __shfl_xor(p1, 32);
  if (l4 == 0){
    atomicAdd(&red[wn * 32 + l15], p0);
    atomicAdd(&red[wn * 32 + 16 + l15], p1);
  }
  __syncthreads();
  if (t < 128) docv[nbase + t] = red[t];
}

// ---------------- logits + log_softmax ----------------------------------------------
__global__ __launch_bounds__(256) void k_final(const float* __restrict__ docv, const float* __restrict__ doW,
                                               const float* __restrict__ dob, float* __restrict__ out){
  __shared__ float lg[16];
  int w = threadIdx.x >> 6, l = threadIdx.x & 63;
  for (int c = w; c < 13; c += 4){
    float p = 0.f;
    for (int j = 0; j < 16; ++j){
      int k = j * 64 + l;
      p += docv[k] * doW[c * 1024 + k];
    }
    for (int o = 32; o >= 1; o >>= 1) p += __shfl_xor(p, o);
    if (l == 0) lg[c] = p + dob[c];
  }
  __syncthreads();
  if (threadIdx.x == 0){
    float m = lg[0];
    for (int c = 1; c < 13; ++c) m = fmaxf(m, lg[c]);
    float s = 0.f;
    for (int c = 0; c < 13; ++c) s += __expf(lg[c] - m);
    float ls = logf(s);
    for (int c = 0; c < 13; ++c) out[8256 + c] = lg[c] - m - ls;
  }
}

extern "C" void kernel_launch(void* const* d_in, const int* in_sizes, int n_in,
                              void* d_out, int out_size, void* d_ws, size_t ws_size,
                              hipStream_t stream) {
  (void)in_sizes; (void)n_in; (void)out_size; (void)ws_size;
  const int*   doc = (const int*)d_in[0];
  const float* emb = (const float*)d_in[1];
  const float* wWi = (const float*)d_in[2];
  const float* wWh = (const float*)d_in[3];
  const float* wbi = (const float*)d_in[4];
  const float* wbh = (const float*)d_in[5];
  const float* sWi = (const float*)d_in[6];
  // d_in[7] = s_Wh unused (sentence GRU sees zero state)
  const float* sbi = (const float*)d_in[8];
  const float* sbh = (const float*)d_in[9];
  const float* waW = (const float*)d_in[10];
  const float* wab = (const float*)d_in[11];
  // d_in[12] = uw_W unused (softmax over size-1 axis)
  const float* saW = (const float*)d_in[13];
  const float* sab = (const float*)d_in[14];
  // d_in[15] = us_W unused
  const float* doW = (const float*)d_in[16];
  const float* dob = (const float*)d_in[17];
  float* out = (float*)d_out;
  char* ws = (char*)d_ws;
  u16* gi    = (u16*)(ws);                    // 2*128*64*768 bf16 = 25,165,824 B
  u16* wenc  = (u16*)(ws + 25165824);         // 64*128*512 bf16  =  8,388,608 B
  u16* ssumv = (u16*)(ws + 33554432);         // 64*512 bf16      =     65,536 B
  u16* sencv = (u16*)(ws + 33619968);         // 64*1024 bf16     =    131,072 B
  float* docv = (float*)(ws + 33751040);      // 1024 f32         =      4,096 B

  k_gi    <<<768, 512, 0, stream>>>(doc, emb, wWi, wbi, wbh, gi);
  k_rec   <<<8, 512, 0, stream>>>(wWh, wbh, gi, wenc);
  k_uword <<<256, 512, 0, stream>>>(wenc, waW, wab, ssumv, out);
  k_sent  <<<16, 512, 0, stream>>>(ssumv, sWi, sbi, sbh, sencv);
  k_usent <<<8, 512, 0, stream>>>(sencv, saW, sab, docv, out);
  k_final <<<1, 256, 0, stream>>>(docv, doW, dob, out);
}

// Round 10
// 407.765 us; speedup vs baseline: 1.3868x; 1.1120x over previous
//
#include <hip/hip_runtime.h>
#include <hip/hip_bf16.h>

typedef unsigned short u16;
typedef __attribute__((ext_vector_type(8))) short s16x8;
typedef __attribute__((ext_vector_type(4))) float f32x4;
typedef __attribute__((ext_vector_type(4))) unsigned u32x4;

__device__ __forceinline__ float b2f(u16 v){
  unsigned u = ((unsigned)v) << 16; float f; __builtin_memcpy(&f, &u, 4); return f;
}
__device__ __forceinline__ float bits2f(unsigned u){
  float f; __builtin_memcpy(&f, &u, 4); return f;
}
__device__ __forceinline__ u16 f2b(float f){
  unsigned u; __builtin_memcpy(&u, &f, 4);
  unsigned r = (u + 0x7FFFu + ((u >> 16) & 1u)) >> 16; return (u16)r;
}
// pack 2 f32 -> u32 of 2 bf16 (v_cvt_pk_bf16_f32, RNE); x in low half
__device__ __forceinline__ unsigned pk2(float x, float y){
  __hip_bfloat162 q = __float22bfloat162_rn(float2{x, y});
  unsigned r; __builtin_memcpy(&r, &q, 4); return r;
}
// 8 consecutive f32 -> 8 bf16 (RNE) via 4x cvt_pk
__device__ __forceinline__ s16x8 cvt8(const float* __restrict__ p){
  f32x4 a = *(const f32x4*)p;
  f32x4 b = *(const f32x4*)(p + 4);
  u32x4 u; u[0]=pk2(a[0],a[1]); u[1]=pk2(a[2],a[3]); u[2]=pk2(b[0],b[1]); u[3]=pk2(b[2],b[3]);
  s16x8 r; __builtin_memcpy(&r, &u, 16); return r;
}
// scaled variant (for log2e-folded GRU weights)
__device__ __forceinline__ s16x8 cvt8s(const float* __restrict__ p, float s){
  f32x4 a = *(const f32x4*)p;
  f32x4 b = *(const f32x4*)(p + 4);
  u32x4 u; u[0]=pk2(a[0]*s,a[1]*s); u[1]=pk2(a[2]*s,a[3]*s); u[2]=pk2(b[0]*s,b[1]*s); u[3]=pk2(b[2]*s,b[3]*s);
  s16x8 r; __builtin_memcpy(&r, &u, 16); return r;
}
#define LOG2E  1.4426950408889634f
#define LOG2E2 2.8853900817779268f
// pre-activations arrive scaled by log2e (sigm) / 2*log2e (tanh)
__device__ __forceinline__ float sigm2(float x){        // = 1/(1+e^-a), x = log2e*a
  float e = __builtin_amdgcn_exp2f(-x);
  return __builtin_amdgcn_rcpf(1.f + e);
}
__device__ __forceinline__ float tanh2(float y){        // = tanh(a), y = 2*log2e*a
  float e = __builtin_amdgcn_exp2f(y);
  return 1.f - 2.f * __builtin_amdgcn_rcpf(e + 1.f);
}
// non-scaled versions for the small kernels
__device__ __forceinline__ float sigm(float x){
  float e = __builtin_amdgcn_exp2f(-x * LOG2E);
  return __builtin_amdgcn_rcpf(1.f + e);
}
__device__ __forceinline__ float tanh_(float x){
  float e = __builtin_amdgcn_exp2f(x * LOG2E2);
  return 1.f - 2.f * __builtin_amdgcn_rcpf(e + 1.f);
}
__device__ __forceinline__ f32x4 mfma16(s16x8 a, s16x8 b, f32x4 c){
  return __builtin_amdgcn_mfma_f32_16x16x32_bf16(a, b, c, 0, 0, 0);
}

// ---------------- gi = log2e-scaled (emb[doc] @ Wi^T + bi (+bh for r,z)) -------------
// grid = 2 dirs * 64 mtiles(=sentences) * 6 ntiles ; block 512
// gi layout (bf16): [d][word][sent][ gt*256 + whc*32 + l15*2 + jt ]  (jt-pairs in u32)
__global__ __launch_bounds__(512, 2) void k_gi(const int* __restrict__ doc, const float* __restrict__ emb,
                                               const float* __restrict__ wWi, const float* __restrict__ wbi,
                                               const float* __restrict__ wbh, u16* __restrict__ gi){
  __shared__ u16 sA[128 * 64];
  __shared__ u16 sB[128 * 64];
  int bid = blockIdx.x;
  int d = bid / 384; int rem = bid % 384;
  int mt = rem / 6, nt = rem % 6;
  int mbase = mt * 128, nbase = nt * 128;
  int t = threadIdx.x;
  int w = t >> 6, l = t & 63, l15 = l & 15, l4 = l >> 4;
  int wm = w >> 2, wn = w & 3; // 2 x 4 wave grid
  int r0 = t >> 3, c0 = t & 7;
  int tok0 = doc[mbase + r0];
  int tok1 = doc[mbase + 64 + r0];
  const float* Wb = wWi + d * 196608 + nbase * 256;
  f32x4 acc[4][2];
  #pragma unroll
  for (int a = 0; a < 4; ++a){ acc[a][0] = {0.f,0.f,0.f,0.f}; acc[a][1] = {0.f,0.f,0.f,0.f}; }
  for (int ki = 0; ki < 4; ++ki){
    int k0 = ki * 64;
    s16x8 a0 = cvt8(&emb[tok0 * 256 + k0 + c0 * 8]);
    s16x8 a1 = cvt8(&emb[tok1 * 256 + k0 + c0 * 8]);
    s16x8 b0 = cvt8(&Wb[r0 * 256 + k0 + c0 * 8]);
    s16x8 b1 = cvt8(&Wb[(64 + r0) * 256 + k0 + c0 * 8]);
    __syncthreads();
    int sw = c0 ^ (r0 & 7);
    *(s16x8*)&sA[(r0 * 8 + sw) * 8] = a0;
    *(s16x8*)&sA[((64 + r0) * 8 + sw) * 8] = a1;
    *(s16x8*)&sB[(r0 * 8 + sw) * 8] = b0;
    *(s16x8*)&sB[((64 + r0) * 8 + sw) * 8] = b1;
    __syncthreads();
    #pragma unroll
    for (int kt = 0; kt < 2; ++kt){
      int ch = kt * 4 + l4;
      s16x8 bfr[2];
      #pragma unroll
      for (int n2 = 0; n2 < 2; ++n2){
        int rr = wn * 32 + n2 * 16 + l15;
        bfr[n2] = *(const s16x8*)&sB[(rr * 8 + (ch ^ (rr & 7))) * 8];
      }
      #pragma unroll
      for (int m2 = 0; m2 < 4; ++m2){
        int rr = wm * 64 + m2 * 16 + l15;
        s16x8 af = *(const s16x8*)&sA[(rr * 8 + (ch ^ (rr & 7))) * 8];
        acc[m2][0] = mfma16(af, bfr[0], acc[m2][0]);
        acc[m2][1] = mfma16(af, bfr[1], acc[m2][1]);
      }
    }
  }
  int cgb = nbase + wn * 32;            // one gt per (nt,wn)
  int gt  = cgb >> 8;
  int whc = (cgb & 255) >> 5;
  float sg = (gt < 2) ? LOG2E : LOG2E2;
  int cg0 = cgb + l15, cg1 = cgb + 16 + l15;
  float bi0 = wbi[d * 768 + cg0] + ((gt < 2) ? wbh[d * 768 + cg0] : 0.f);
  float bi1 = wbi[d * 768 + cg1] + ((gt < 2) ? wbh[d * 768 + cg1] : 0.f);
  #pragma unroll
  for (int m2 = 0; m2 < 4; ++m2){
    #pragma unroll
    for (int i = 0; i < 4; ++i){
      int ml = wm * 64 + m2 * 16 + l4 * 4 + i;   // word index
      int base2 = ((d * 128 + ml) * 64 + mt) * 768 + gt * 256 + whc * 32;
      *(unsigned*)&gi[base2 + l15 * 2] = pk2(sg * (acc[m2][0][i] + bi0),
                                             sg * (acc[m2][1][i] + bi1));
    }
  }
}

// ---------------- word GRU recurrence: 128 steps, per-block = (dir, 16 sentences) ----
// grid = 8 (d = bid&1, g = bid>>1), block 512 (8 waves, wave w owns 32 hidden cols)
// Weight split (best known): r,z both halves + n jt0 in regs (160 VGPR); n jt1 in LDS.
// NEW vs R9: (1) sH row stride 264 elems (528B) -> af-read bank conflicts ~0
//            (2) gate pre-activations folded into MFMA C-input (acc init != 0)
__global__ __launch_bounds__(512, 2) void k_rec(const float* __restrict__ wWh, const float* __restrict__ wbh,
                                                const u16* __restrict__ gi, u16* __restrict__ wenc){
  __shared__ u16 sBn1[32768];  // n-gate jt1 frags: [w][kt][lane*8] (64 KiB)
  __shared__ u16 sH0[4224];    // h buffers [16][264] bf16 (stride-padded), key-swizzled
  __shared__ u16 sH1[4224];
  int bid = blockIdx.x; int d = bid & 1, g = bid >> 1;
  int t = threadIdx.x, w = t >> 6, l = t & 63, l15 = l & 15, l4 = l >> 4;
  int jb = w * 32;
  const float* Wh = wWh + d * 196608;
  // r,z gates (scaled log2e), both jt halves: 32 frags = 128 regs
  s16x8 bR[2][2][8];
  #pragma unroll
  for (int gt = 0; gt < 2; ++gt)
    #pragma unroll
    for (int jt = 0; jt < 2; ++jt)
      #pragma unroll
      for (int kt = 0; kt < 8; ++kt){
        int n = gt * 256 + jb + jt * 16 + l15;
        bR[gt][jt][kt] = cvt8s(&Wh[n * 256 + kt * 32 + l4 * 8], LOG2E);
      }
  // n gate jt0 (scaled 2log2e): 8 frags = 32 regs
  s16x8 bN0[8];
  #pragma unroll
  for (int kt = 0; kt < 8; ++kt){
    int n = 512 + jb + l15;
    bN0[kt] = cvt8s(&Wh[n * 256 + kt * 32 + l4 * 8], LOG2E2);
  }
  // n gate jt1 to LDS (linear per-lane layout: BW-floor reads)
  #pragma unroll
  for (int kt = 0; kt < 8; ++kt){
    int n = 512 + jb + 16 + l15;
    s16x8 v = cvt8s(&Wh[n * 256 + kt * 32 + l4 * 8], LOG2E2);
    *(s16x8*)&sBn1[((w * 8 + kt) * 64 + l) * 8] = v;
  }
  // zero-init h buffer 0: rows 0..15, elems 0..255 of each 264-elem row
  {
    int zr = t >> 5, zc = (t & 31) * 8;
    s16x8 z8 = {0,0,0,0,0,0,0,0};
    *(s16x8*)&sH0[zr * 264 + zc] = z8;
  }
  float hloc[2][4] = {{0.f,0.f,0.f,0.f},{0.f,0.f,0.f,0.f}};
  float bhn[2];
  #pragma unroll
  for (int jt = 0; jt < 2; ++jt)
    bhn[jt] = wbh[d * 768 + 512 + jb + jt * 16 + l15] * LOG2E2;  // pre-scaled

  // swizzle keys: phys_chunk = logical_chunk ^ key(row), key(s) = (s ^ (s>>2)) & 7
  int rkey = (l15 ^ (l15 >> 2)) & 7;
  int skey[4];
  #pragma unroll
  for (int i = 0; i < 4; ++i){ int s = l4 * 4 + i; skey[i] = (s ^ (s >> 2)) & 7; }

  // gi layout: [d][word][sent][768'] with jt-paired u32 at gt*256 + jb + l15*2
  const u16* gb = gi + d * 6291456 + (g * 16 + l4 * 4) * 768 + jb + l15 * 2;
  u16* wbase = wenc + ((g * 16 + l4 * 4) * 128) * 512 + d * 256 + jb + l15;

  // prefetch step 0's gate values (12 u32 per thread)
  unsigned g32[3][4];
  #pragma unroll
  for (int gt = 0; gt < 3; ++gt)
    #pragma unroll
    for (int i = 0; i < 4; ++i)
      g32[gt][i] = *(const unsigned*)&gb[gt * 256 + i * 768];
  __syncthreads();

  auto body = [&](int step, const u16* shc, u16* shn){
    // acc init = gate pre-activations (MFMA C-in): acc0=ir, acc1=iz, acc2=bhn
    f32x4 acc[3][2];
    #pragma unroll
    for (int i = 0; i < 4; ++i){
      acc[0][0][i] = bits2f(g32[0][i] << 16);
      acc[0][1][i] = bits2f(g32[0][i] & 0xffff0000u);
      acc[1][0][i] = bits2f(g32[1][i] << 16);
      acc[1][1][i] = bits2f(g32[1][i] & 0xffff0000u);
      acc[2][0][i] = bhn[0];
      acc[2][1][i] = bhn[1];
    }
    #pragma unroll
    for (int kt = 0; kt < 8; ++kt){
      int ch = kt * 4 + l4;
      s16x8 af = *(const s16x8*)&shc[l15 * 264 + (ch ^ rkey) * 8];
      acc[0][0] = mfma16(af, bR[0][0][kt], acc[0][0]);
      acc[0][1] = mfma16(af, bR[0][1][kt], acc[0][1]);
      acc[1][0] = mfma16(af, bR[1][0][kt], acc[1][0]);
      acc[1][1] = mfma16(af, bR[1][1][kt], acc[1][1]);
      acc[2][0] = mfma16(af, bN0[kt], acc[2][0]);
      s16x8 bn1 = *(const s16x8*)&sBn1[((w * 8 + kt) * 64 + l) * 8];
      acc[2][1] = mfma16(af, bn1, acc[2][1]);
    }
    u16 hb[2][4];
    #pragma unroll
    for (int jt = 0; jt < 2; ++jt){
      #pragma unroll
      for (int i = 0; i < 4; ++i){
        unsigned v2 = g32[2][i];
        float inn = (jt == 0) ? bits2f(v2 << 16) : bits2f(v2 & 0xffff0000u);
        float r = sigm2(acc[0][jt][i]);
        float z = sigm2(acc[1][jt][i]);
        float nn = tanh2(inn + r * acc[2][jt][i]);
        float h = nn + z * (hloc[jt][i] - nn);
        hloc[jt][i] = h;
      }
      unsigned b01 = pk2(hloc[jt][0], hloc[jt][1]);
      unsigned b23 = pk2(hloc[jt][2], hloc[jt][3]);
      hb[jt][0] = (u16)b01; hb[jt][1] = (u16)(b01 >> 16);
      hb[jt][2] = (u16)b23; hb[jt][3] = (u16)(b23 >> 16);
    }
    // prefetch next step's gate values; stay in flight across the raw barrier.
    // Final iteration reads past gi (lands in wenc region; values unused).
    {
      const u16* gp = gb + (step + 1) * 49152;
      #pragma unroll
      for (int gt = 0; gt < 3; ++gt)
        #pragma unroll
        for (int i = 0; i < 4; ++i)
          g32[gt][i] = *(const unsigned*)&gp[gt * 256 + i * 768];
    }
    #pragma unroll
    for (int jt = 0; jt < 2; ++jt){
      #pragma unroll
      for (int i = 0; i < 4; ++i){
        int s = l4 * 4 + i, c = jb + jt * 16 + l15;
        shn[s * 264 + ((c >> 3) ^ skey[i]) * 8 + (c & 7)] = hb[jt][i];
        wbase[(i * 128 + step) * 512 + jt * 16] = hb[jt][i];  // fire-and-forget
      }
    }
    // drain only LDS (lgkm), NOT vmem; then raw barrier.
    asm volatile("s_waitcnt lgkmcnt(0)" ::: "memory");
    __builtin_amdgcn_s_barrier();
    __builtin_amdgcn_sched_barrier(0);
  };

  #pragma unroll 1
  for (int it = 0; it < 64; ++it){
    body(2 * it,     sH0, sH1);
    body(2 * it + 1, sH1, sH0);
  }
}

// ---------------- u_word = tanh(wordenc @ waW^T + wab); sent_summ = sum over words ---
// grid = 64 sentences * 4 ntiles ; block 512.  Also writes word_w ones.
__global__ __launch_bounds__(512, 2) void k_uword(const u16* __restrict__ wenc, const float* __restrict__ waW,
                                                  const float* __restrict__ wab, u16* __restrict__ ssum,
                                                  float* __restrict__ outw){
  __shared__ u16 sA[128 * 64], sB[128 * 64];
  __shared__ float red[128];
  int bid = blockIdx.x; int s = bid >> 2, nt = bid & 3; int nbase = nt * 128;
  int t = threadIdx.x, w = t >> 6, l = t & 63, l15 = l & 15, l4 = l >> 4;
  int wm = w >> 2, wn = w & 3;
  int r0 = t >> 3, c0 = t & 7;
  const u16* Arow = wenc + s * 65536;
  const float* Brow = waW + nbase * 512;
  if (t < 128) red[t] = 0.f;
  if (t < 32) outw[s * 128 + nt * 32 + t] = 1.0f;   // word_w ones
  f32x4 acc[4][2];
  #pragma unroll
  for (int a = 0; a < 4; ++a){ acc[a][0] = {0.f,0.f,0.f,0.f}; acc[a][1] = {0.f,0.f,0.f,0.f}; }
  for (int ki = 0; ki < 8; ++ki){
    int k0 = ki * 64;
    s16x8 a0 = *(const s16x8*)&Arow[r0 * 512 + k0 + c0 * 8];
    s16x8 a1 = *(const s16x8*)&Arow[(64 + r0) * 512 + k0 + c0 * 8];
    s16x8 b0 = cvt8(&Brow[r0 * 512 + k0 + c0 * 8]);
    s16x8 b1 = cvt8(&Brow[(64 + r0) * 512 + k0 + c0 * 8]);
    __syncthreads();
    int sw = c0 ^ (r0 & 7);
    *(s16x8*)&sA[(r0 * 8 + sw) * 8] = a0;
    *(s16x8*)&sA[((64 + r0) * 8 + sw) * 8] = a1;
    *(s16x8*)&sB[(r0 * 8 + sw) * 8] = b0;
    *(s16x8*)&sB[((64 + r0) * 8 + sw) * 8] = b1;
    __syncthreads();
    #pragma unroll
    for (int kt = 0; kt < 2; ++kt){
      int ch = kt * 4 + l4;
      s16x8 bfr[2];
      #pragma unroll
      for (int n2 = 0; n2 < 2; ++n2){
        int rr = wn * 32 + n2 * 16 + l15;
        bfr[n2] = *(const s16x8*)&sB[(rr * 8 + (ch ^ (rr & 7))) * 8];
      }
      #pragma unroll
      for (int m2 = 0; m2 < 4; ++m2){
        int rr = wm * 64 + m2 * 16 + l15;
        s16x8 af = *(const s16x8*)&sA[(rr * 8 + (ch ^ (rr & 7))) * 8];
        acc[m2][0] = mfma16(af, bfr[0], acc[m2][0]);
        acc[m2][1] = mfma16(af, bfr[1], acc[m2][1]);
      }
    }
  }
  float bi0 = wab[nbase + wn * 32 + l15];
  float bi1 = wab[nbase + wn * 32 + 16 + l15];
  float p0 = 0.f, p1 = 0.f;
  #pragma unroll
  for (int m2 = 0; m2 < 4; ++m2){
    #pragma unroll
    for (int i = 0; i < 4; ++i){
      p0 += tanh_(acc[m2][0][i] + bi0);
      p1 += tanh_(acc[m2][1][i] + bi1);
    }
  }
  p0 += __shfl_xor(p0, 16); p0 += __shfl_xor(p0, 32);
  p1 += __shfl_xor(p1, 16); p1 += __shfl_xor(p1, 32);
  if (l4 == 0){
    atomicAdd(&red[wn * 32 + l15], p0);
    atomicAdd(&red[wn * 32 + 16 + l15], p1);
  }
  __syncthreads();
  if (t < 128) ssum[s * 512 + nbase + t] = f2b(red[t]);
}

// ---------------- sentence GRU (zero state): sentenc ---------------------------------
// grid = 2 dirs * 8 jblocks(64) ; block 512 (waves: 4M x 2J)
__global__ __launch_bounds__(512, 2) void k_sent(const u16* __restrict__ ssum, const float* __restrict__ sWi,
                                                 const float* __restrict__ sbi, const float* __restrict__ sbh,
                                                 u16* __restrict__ senc){
  __shared__ u16 sA[64 * 512]; // 64 KiB, swizzled
  int bid = blockIdx.x; int d = bid >> 3, jb8 = bid & 7; int jbase = jb8 * 64;
  int t = threadIdx.x, w = t >> 6, l = t & 63, l15 = l & 15, l4 = l >> 4;
  int wm = w >> 1, wj = w & 1;
  #pragma unroll
  for (int j = 0; j < 8; ++j){
    int q = j * 512 + t, r = q >> 6, c = q & 63;
    s16x8 v = *(const s16x8*)&ssum[r * 512 + c * 8];
    *(s16x8*)&sA[(r * 64 + (c ^ (r & 7))) * 8] = v;
  }
  __syncthreads();
  const float* Wd = sWi + d * 786432;
  f32x4 acc[3][2];
  #pragma unroll
  for (int a = 0; a < 3; ++a){ acc[a][0] = {0.f,0.f,0.f,0.f}; acc[a][1] = {0.f,0.f,0.f,0.f}; }
  int ra = wm * 16 + l15;
  #pragma unroll 4
  for (int kt = 0; kt < 16; ++kt){
    int ch = kt * 4 + l4;
    s16x8 af = *(const s16x8*)&sA[(ra * 64 + (ch ^ (ra & 7))) * 8];
    #pragma unroll
    for (int gt = 0; gt < 3; ++gt){
      #pragma unroll
      for (int jt = 0; jt < 2; ++jt){
        int n = gt * 512 + jbase + wj * 32 + jt * 16 + l15;
        s16x8 bf = cvt8(&Wd[n * 512 + kt * 32 + l4 * 8]);
        acc[gt][jt] = mfma16(af, bf, acc[gt][jt]);
      }
    }
  }
  float biv[3][2], bhv[3][2];
  #pragma unroll
  for (int gt = 0; gt < 3; ++gt){
    #pragma unroll
    for (int jt = 0; jt < 2; ++jt){
      int n = gt * 512 + jbase + wj * 32 + jt * 16 + l15;
      biv[gt][jt] = sbi[d * 1536 + n];
      bhv[gt][jt] = sbh[d * 1536 + n];
    }
  }
  #pragma unroll
  for (int jt = 0; jt < 2; ++jt){
    #pragma unroll
    for (int i = 0; i < 4; ++i){
      float r_ = sigm(acc[0][jt][i] + biv[0][jt] + bhv[0][jt]);
      float z_ = sigm(acc[1][jt][i] + biv[1][jt] + bhv[1][jt]);
      float n_ = tanh_(acc[2][jt][i] + biv[2][jt] + r_ * bhv[2][jt]);
      float sh = (1.f - z_) * n_;
      int srow = wm * 16 + l4 * 4 + i;
      senc[srow * 1024 + d * 512 + jbase + wj * 32 + jt * 16 + l15] = f2b(sh);
    }
  }
}

// ---------------- u_sent = tanh(sentenc @ saW^T + sab); doc = sum over sentences -----
// grid = 8 ntiles ; block 512 (waves 2M x 4N).  Also writes sent_w ones.
__global__ __launch_bounds__(512, 2) void k_usent(const u16* __restrict__ senc, const float* __restrict__ saW,
                                                  const float* __restrict__ sab, float* __restrict__ docv,
                                                  float* __restrict__ outw){
  __shared__ u16 sA[64 * 1024]; // 128 KiB, swizzled
  __shared__ float red[128];
  int bid = blockIdx.x; int nbase = bid * 128;
  int t = threadIdx.x, w = t >> 6, l = t & 63, l15 = l & 15, l4 = l >> 4;
  int wm = w >> 2, wn = w & 3;
  if (t < 128) red[t] = 0.f;
  if (t < 8) outw[8192 + bid * 8 + t] = 1.0f;   // sent_w ones
  #pragma unroll
  for (int j = 0; j < 16; ++j){
    int q = j * 512 + t, r = q >> 7, c = q & 127;
    s16x8 v = *(const s16x8*)&senc[r * 1024 + c * 8];
    *(s16x8*)&sA[(r * 128 + (c ^ (r & 7))) * 8] = v;
  }
  __syncthreads();
  f32x4 acc[2][2];
  #pragma unroll
  for (int a = 0; a < 2; ++a){ acc[a][0] = {0.f,0.f,0.f,0.f}; acc[a][1] = {0.f,0.f,0.f,0.f}; }
  #pragma unroll 4
  for (int kt = 0; kt < 32; ++kt){
    int ch = kt * 4 + l4;
    s16x8 af[2];
    #pragma unroll
    for (int mt = 0; mt < 2; ++mt){
      int r = wm * 32 + mt * 16 + l15;
      af[mt] = *(const s16x8*)&sA[(r * 128 + (ch ^ (r & 7))) * 8];
    }
    #pragma unroll
    for (int nt = 0; nt < 2; ++nt){
      int n = nbase + wn * 32 + nt * 16 + l15;
      s16x8 bf = cvt8(&saW[n * 1024 + kt * 32 + l4 * 8]);
      acc[0][nt] = mfma16(af[0], bf, acc[0][nt]);
      acc[1][nt] = mfma16(af[1], bf, acc[1][nt]);
    }
  }
  float b0 = sab[nbase + wn * 32 + l15];
  float b1 = sab[nbase + wn * 32 + 16 + l15];
  float p0 = 0.f, p1 = 0.f;
  #pragma unroll
  for (int mt = 0; mt < 2; ++mt){
    #pragma unroll
    for (int i = 0; i < 4; ++i){
      p0 += tanh_(acc[mt][0][i] + b0);
      p1 += tanh_(acc[mt][1][i] + b1);
    }
  }
  p0 += __shfl_xor(p0, 16); p0 += __shfl_xor(p0, 32);
  p1 += __shfl_xor(p1, 16); p1 += __shfl_xor(p1, 32);
  if (l4 == 0){
    atomicAdd(&red[wn * 32 + l15], p0);
    atomicAdd(&red[wn * 32 + 16 + l15], p1);
  }
  __syncthreads();
  if (t < 128) docv[nbase + t] = red[t];
}

// ---------------- logits + log_softmax ----------------------------------------------
__global__ __launch_bounds__(256) void k_final(const float* __restrict__ docv, const float* __restrict__ doW,
                                               const float* __restrict__ dob, float* __restrict__ out){
  __shared__ float lg[16];
  int w = threadIdx.x >> 6, l = threadIdx.x & 63;
  for (int c = w; c < 13; c += 4){
    float p = 0.f;
    for (int j = 0; j < 16; ++j){
      int k = j * 64 + l;
      p += docv[k] * doW[c * 1024 + k];
    }
    for (int o = 32; o >= 1; o >>= 1) p += __shfl_xor(p, o);
    if (l == 0) lg[c] = p + dob[c];
  }
  __syncthreads();
  if (threadIdx.x == 0){
    float m = lg[0];
    for (int c = 1; c < 13; ++c) m = fmaxf(m, lg[c]);
    float s = 0.f;
    for (int c = 0; c < 13; ++c) s += __expf(lg[c] - m);
    float ls = logf(s);
    for (int c = 0; c < 13; ++c) out[8256 + c] = lg[c] - m - ls;
  }
}

extern "C" void kernel_launch(void* const* d_in, const int* in_sizes, int n_in,
                              void* d_out, int out_size, void* d_ws, size_t ws_size,
                              hipStream_t stream) {
  (void)in_sizes; (void)n_in; (void)out_size; (void)ws_size;
  const int*   doc = (const int*)d_in[0];
  const float* emb = (const float*)d_in[1];
  const float* wWi = (const float*)d_in[2];
  const float* wWh = (const float*)d_in[3];
  const float* wbi = (const float*)d_in[4];
  const float* wbh = (const float*)d_in[5];
  const float* sWi = (const float*)d_in[6];
  // d_in[7] = s_Wh unused (sentence GRU sees zero state)
  const float* sbi = (const float*)d_in[8];
  const float* sbh = (const float*)d_in[9];
  const float* waW = (const float*)d_in[10];
  const float* wab = (const float*)d_in[11];
  // d_in[12] = uw_W unused (softmax over size-1 axis)
  const float* saW = (const float*)d_in[13];
  const float* sab = (const float*)d_in[14];
  // d_in[15] = us_W unused
  const float* doW = (const float*)d_in[16];
  const float* dob = (const float*)d_in[17];
  float* out = (float*)d_out;
  char* ws = (char*)d_ws;
  u16* gi    = (u16*)(ws);                    // 2*128*64*768 bf16 = 25,165,824 B
  u16* wenc  = (u16*)(ws + 25165824);         // 64*128*512 bf16  =  8,388,608 B
  u16* ssumv = (u16*)(ws + 33554432);         // 64*512 bf16      =     65,536 B
  u16* sencv = (u16*)(ws + 33619968);         // 64*1024 bf16     =    131,072 B
  float* docv = (float*)(ws + 33751040);      // 1024 f32         =      4,096 B

  k_gi    <<<768, 512, 0, stream>>>(doc, emb, wWi, wbi, wbh, gi);
  k_rec   <<<8, 512, 0, stream>>>(wWh, wbh, gi, wenc);
  k_uword <<<256, 512, 0, stream>>>(wenc, waW, wab, ssumv, out);
  k_sent  <<<16, 512, 0, stream>>>(ssumv, sWi, sbi, sbh, sencv);
  k_usent <<<8, 512, 0, stream>>>(sencv, saW, sab, docv, out);
  k_final <<<1, 256, 0, stream>>>(docv, doW, dob, out);
}

// Round 11
// 329.051 us; speedup vs baseline: 1.7185x; 1.2392x over previous
//
#include <hip/hip_runtime.h>
#include <hip/hip_bf16.h>

typedef unsigned short u16;
typedef __attribute__((ext_vector_type(8))) short s16x8;
typedef __attribute__((ext_vector_type(4))) float f32x4;
typedef __attribute__((ext_vector_type(4))) unsigned u32x4;

__device__ __forceinline__ float b2f(u16 v){
  unsigned u = ((unsigned)v) << 16; float f; __builtin_memcpy(&f, &u, 4); return f;
}
__device__ __forceinline__ float bits2f(unsigned u){
  float f; __builtin_memcpy(&f, &u, 4); return f;
}
__device__ __forceinline__ u16 f2b(float f){
  unsigned u; __builtin_memcpy(&u, &f, 4);
  unsigned r = (u + 0x7FFFu + ((u >> 16) & 1u)) >> 16; return (u16)r;
}
// pack 2 f32 -> u32 of 2 bf16 (v_cvt_pk_bf16_f32, RNE); x in low half
__device__ __forceinline__ unsigned pk2(float x, float y){
  __hip_bfloat162 q = __float22bfloat162_rn(float2{x, y});
  unsigned r; __builtin_memcpy(&r, &q, 4); return r;
}
// 8 consecutive f32 -> 8 bf16 (RNE) via 4x cvt_pk
__device__ __forceinline__ s16x8 cvt8(const float* __restrict__ p){
  f32x4 a = *(const f32x4*)p;
  f32x4 b = *(const f32x4*)(p + 4);
  u32x4 u; u[0]=pk2(a[0],a[1]); u[1]=pk2(a[2],a[3]); u[2]=pk2(b[0],b[1]); u[3]=pk2(b[2],b[3]);
  s16x8 r; __builtin_memcpy(&r, &u, 16); return r;
}
// scaled variant (for log2e-folded GRU weights)
__device__ __forceinline__ s16x8 cvt8s(const float* __restrict__ p, float s){
  f32x4 a = *(const f32x4*)p;
  f32x4 b = *(const f32x4*)(p + 4);
  u32x4 u; u[0]=pk2(a[0]*s,a[1]*s); u[1]=pk2(a[2]*s,a[3]*s); u[2]=pk2(b[0]*s,b[1]*s); u[3]=pk2(b[2]*s,b[3]*s);
  s16x8 r; __builtin_memcpy(&r, &u, 16); return r;
}
#define LOG2E  1.4426950408889634f
#define LOG2E2 2.8853900817779268f
// pre-activations arrive scaled by log2e (sigm) / 2*log2e (tanh)
__device__ __forceinline__ float sigm2(float x){        // = 1/(1+e^-a), x = log2e*a
  float e = __builtin_amdgcn_exp2f(-x);
  return __builtin_amdgcn_rcpf(1.f + e);
}
__device__ __forceinline__ float tanh2(float y){        // = tanh(a), y = 2*log2e*a
  float e = __builtin_amdgcn_exp2f(y);
  return 1.f - 2.f * __builtin_amdgcn_rcpf(e + 1.f);
}
// non-scaled versions for the small kernels
__device__ __forceinline__ float sigm(float x){
  float e = __builtin_amdgcn_exp2f(-x * LOG2E);
  return __builtin_amdgcn_rcpf(1.f + e);
}
__device__ __forceinline__ float tanh_(float x){
  float e = __builtin_amdgcn_exp2f(x * LOG2E2);
  return 1.f - 2.f * __builtin_amdgcn_rcpf(e + 1.f);
}
__device__ __forceinline__ f32x4 mfma16(s16x8 a, s16x8 b, f32x4 c){
  return __builtin_amdgcn_mfma_f32_16x16x32_bf16(a, b, c, 0, 0, 0);
}

// ---------------- gi = log2e-scaled (emb[doc] @ Wi^T + bi (+bh for r,z)) -------------
// grid = 2 dirs * 64 mtiles(=sentences) * 6 ntiles ; block 512
// gi layout (bf16): [d][word][sent][ gt*256 + whc*32 + l15*2 + jt ]  (jt-pairs in u32)
__global__ __launch_bounds__(512, 2) void k_gi(const int* __restrict__ doc, const float* __restrict__ emb,
                                               const float* __restrict__ wWi, const float* __restrict__ wbi,
                                               const float* __restrict__ wbh, u16* __restrict__ gi){
  __shared__ u16 sA[128 * 64];
  __shared__ u16 sB[128 * 64];
  int bid = blockIdx.x;
  int d = bid / 384; int rem = bid % 384;
  int mt = rem / 6, nt = rem % 6;
  int mbase = mt * 128, nbase = nt * 128;
  int t = threadIdx.x;
  int w = t >> 6, l = t & 63, l15 = l & 15, l4 = l >> 4;
  int wm = w >> 2, wn = w & 3; // 2 x 4 wave grid
  int r0 = t >> 3, c0 = t & 7;
  int tok0 = doc[mbase + r0];
  int tok1 = doc[mbase + 64 + r0];
  const float* Wb = wWi + d * 196608 + nbase * 256;
  f32x4 acc[4][2];
  #pragma unroll
  for (int a = 0; a < 4; ++a){ acc[a][0] = {0.f,0.f,0.f,0.f}; acc[a][1] = {0.f,0.f,0.f,0.f}; }
  for (int ki = 0; ki < 4; ++ki){
    int k0 = ki * 64;
    s16x8 a0 = cvt8(&emb[tok0 * 256 + k0 + c0 * 8]);
    s16x8 a1 = cvt8(&emb[tok1 * 256 + k0 + c0 * 8]);
    s16x8 b0 = cvt8(&Wb[r0 * 256 + k0 + c0 * 8]);
    s16x8 b1 = cvt8(&Wb[(64 + r0) * 256 + k0 + c0 * 8]);
    __syncthreads();
    int sw = c0 ^ (r0 & 7);
    *(s16x8*)&sA[(r0 * 8 + sw) * 8] = a0;
    *(s16x8*)&sA[((64 + r0) * 8 + sw) * 8] = a1;
    *(s16x8*)&sB[(r0 * 8 + sw) * 8] = b0;
    *(s16x8*)&sB[((64 + r0) * 8 + sw) * 8] = b1;
    __syncthreads();
    #pragma unroll
    for (int kt = 0; kt < 2; ++kt){
      int ch = kt * 4 + l4;
      s16x8 bfr[2];
      #pragma unroll
      for (int n2 = 0; n2 < 2; ++n2){
        int rr = wn * 32 + n2 * 16 + l15;
        bfr[n2] = *(const s16x8*)&sB[(rr * 8 + (ch ^ (rr & 7))) * 8];
      }
      #pragma unroll
      for (int m2 = 0; m2 < 4; ++m2){
        int rr = wm * 64 + m2 * 16 + l15;
        s16x8 af = *(const s16x8*)&sA[(rr * 8 + (ch ^ (rr & 7))) * 8];
        acc[m2][0] = mfma16(af, bfr[0], acc[m2][0]);
        acc[m2][1] = mfma16(af, bfr[1], acc[m2][1]);
      }
    }
  }
  int cgb = nbase + wn * 32;            // one gt per (nt,wn)
  int gt  = cgb >> 8;
  int whc = (cgb & 255) >> 5;
  float sg = (gt < 2) ? LOG2E : LOG2E2;
  int cg0 = cgb + l15, cg1 = cgb + 16 + l15;
  float bi0 = wbi[d * 768 + cg0] + ((gt < 2) ? wbh[d * 768 + cg0] : 0.f);
  float bi1 = wbi[d * 768 + cg1] + ((gt < 2) ? wbh[d * 768 + cg1] : 0.f);
  #pragma unroll
  for (int m2 = 0; m2 < 4; ++m2){
    #pragma unroll
    for (int i = 0; i < 4; ++i){
      int ml = wm * 64 + m2 * 16 + l4 * 4 + i;   // word index
      int base2 = ((d * 128 + ml) * 64 + mt) * 768 + gt * 256 + whc * 32;
      *(unsigned*)&gi[base2 + l15 * 2] = pk2(sg * (acc[m2][0][i] + bi0),
                                             sg * (acc[m2][1][i] + bi1));
    }
  }
}

// ---------------- word GRU recurrence: 128 steps, per-block = (dir, 16 sentences) ----
// grid = 8 (d = bid&1, g = bid>>1), block 512 (8 waves, wave w owns 32 hidden cols)
// Weight split: r,z both halves + n jt0 in regs (160 VGPR); n jt1 in LDS.
// NEW vs R10: NO swizzle at all. Stride 264 (132 dw = 4 mod 32) alone makes the
// af read conflict-free (bank = 4*(l15+l4)+j+16kt: exactly 8 reqs/bank) and the
// h write a free 2-way (l15-pairs merge into one dword).  R10's rkey/skey XOR
// BROKE this (slot histogram 4/8/12/16/... -> the 1,048,576 counter).
__global__ __launch_bounds__(512, 2) void k_rec(const float* __restrict__ wWh, const float* __restrict__ wbh,
                                                const u16* __restrict__ gi, u16* __restrict__ wenc){
  __shared__ u16 sBn1[32768];  // n-gate jt1 frags: [w][kt][lane*8] (64 KiB)
  __shared__ u16 sH0[4224];    // h buffers [16][264] bf16 (stride-padded, unswizzled)
  __shared__ u16 sH1[4224];
  int bid = blockIdx.x; int d = bid & 1, g = bid >> 1;
  int t = threadIdx.x, w = t >> 6, l = t & 63, l15 = l & 15, l4 = l >> 4;
  int jb = w * 32;
  const float* Wh = wWh + d * 196608;
  // r,z gates (scaled log2e), both jt halves: 32 frags = 128 regs
  s16x8 bR[2][2][8];
  #pragma unroll
  for (int gt = 0; gt < 2; ++gt)
    #pragma unroll
    for (int jt = 0; jt < 2; ++jt)
      #pragma unroll
      for (int kt = 0; kt < 8; ++kt){
        int n = gt * 256 + jb + jt * 16 + l15;
        bR[gt][jt][kt] = cvt8s(&Wh[n * 256 + kt * 32 + l4 * 8], LOG2E);
      }
  // n gate jt0 (scaled 2log2e): 8 frags = 32 regs
  s16x8 bN0[8];
  #pragma unroll
  for (int kt = 0; kt < 8; ++kt){
    int n = 512 + jb + l15;
    bN0[kt] = cvt8s(&Wh[n * 256 + kt * 32 + l4 * 8], LOG2E2);
  }
  // n gate jt1 to LDS (linear per-lane layout: conflict-free)
  #pragma unroll
  for (int kt = 0; kt < 8; ++kt){
    int n = 512 + jb + 16 + l15;
    s16x8 v = cvt8s(&Wh[n * 256 + kt * 32 + l4 * 8], LOG2E2);
    *(s16x8*)&sBn1[((w * 8 + kt) * 64 + l) * 8] = v;
  }
  // zero-init h buffer 0: rows 0..15, elems 0..255 of each 264-elem row
  {
    int zr = t >> 5, zc = (t & 31) * 8;
    s16x8 z8 = {0,0,0,0,0,0,0,0};
    *(s16x8*)&sH0[zr * 264 + zc] = z8;
  }
  float hloc[2][4] = {{0.f,0.f,0.f,0.f},{0.f,0.f,0.f,0.f}};
  float bhn[2];
  #pragma unroll
  for (int jt = 0; jt < 2; ++jt)
    bhn[jt] = wbh[d * 768 + 512 + jb + jt * 16 + l15] * LOG2E2;  // pre-scaled

  // gi layout: [d][word][sent][768'] with jt-paired u32 at gt*256 + jb + l15*2
  const u16* gb = gi + d * 6291456 + (g * 16 + l4 * 4) * 768 + jb + l15 * 2;
  u16* wbase = wenc + ((g * 16 + l4 * 4) * 128) * 512 + d * 256 + jb + l15;

  // prefetch step 0's gate values (12 u32 per thread)
  unsigned g32[3][4];
  #pragma unroll
  for (int gt = 0; gt < 3; ++gt)
    #pragma unroll
    for (int i = 0; i < 4; ++i)
      g32[gt][i] = *(const unsigned*)&gb[gt * 256 + i * 768];
  __syncthreads();

  auto body = [&](int step, const u16* shc, u16* shn){
    // acc init = gate pre-activations (MFMA C-in): acc0=ir, acc1=iz, acc2=bhn
    f32x4 acc[3][2];
    #pragma unroll
    for (int i = 0; i < 4; ++i){
      acc[0][0][i] = bits2f(g32[0][i] << 16);
      acc[0][1][i] = bits2f(g32[0][i] & 0xffff0000u);
      acc[1][0][i] = bits2f(g32[1][i] << 16);
      acc[1][1][i] = bits2f(g32[1][i] & 0xffff0000u);
      acc[2][0][i] = bhn[0];
      acc[2][1][i] = bhn[1];
    }
    #pragma unroll
    for (int kt = 0; kt < 8; ++kt){
      int ch = kt * 4 + l4;
      s16x8 af = *(const s16x8*)&shc[l15 * 264 + ch * 8];
      acc[0][0] = mfma16(af, bR[0][0][kt], acc[0][0]);
      acc[0][1] = mfma16(af, bR[0][1][kt], acc[0][1]);
      acc[1][0] = mfma16(af, bR[1][0][kt], acc[1][0]);
      acc[1][1] = mfma16(af, bR[1][1][kt], acc[1][1]);
      acc[2][0] = mfma16(af, bN0[kt], acc[2][0]);
      s16x8 bn1 = *(const s16x8*)&sBn1[((w * 8 + kt) * 64 + l) * 8];
      acc[2][1] = mfma16(af, bn1, acc[2][1]);
    }
    u16 hb[2][4];
    #pragma unroll
    for (int jt = 0; jt < 2; ++jt){
      #pragma unroll
      for (int i = 0; i < 4; ++i){
        unsigned v2 = g32[2][i];
        float inn = (jt == 0) ? bits2f(v2 << 16) : bits2f(v2 & 0xffff0000u);
        float r = sigm2(acc[0][jt][i]);
        float z = sigm2(acc[1][jt][i]);
        float nn = tanh2(inn + r * acc[2][jt][i]);
        float h = nn + z * (hloc[jt][i] - nn);
        hloc[jt][i] = h;
      }
      unsigned b01 = pk2(hloc[jt][0], hloc[jt][1]);
      unsigned b23 = pk2(hloc[jt][2], hloc[jt][3]);
      hb[jt][0] = (u16)b01; hb[jt][1] = (u16)(b01 >> 16);
      hb[jt][2] = (u16)b23; hb[jt][3] = (u16)(b23 >> 16);
    }
    // prefetch next step's gate values; stay in flight across the raw barrier.
    // Final iteration reads past gi (lands in wenc region; values unused).
    {
      const u16* gp = gb + (step + 1) * 49152;
      #pragma unroll
      for (int gt = 0; gt < 3; ++gt)
        #pragma unroll
        for (int i = 0; i < 4; ++i)
          g32[gt][i] = *(const unsigned*)&gp[gt * 256 + i * 768];
    }
    #pragma unroll
    for (int jt = 0; jt < 2; ++jt){
      #pragma unroll
      for (int i = 0; i < 4; ++i){
        int s = l4 * 4 + i, c = jb + jt * 16 + l15;
        shn[s * 264 + c] = hb[jt][i];
        wbase[(i * 128 + step) * 512 + jt * 16] = hb[jt][i];  // fire-and-forget
      }
    }
    // drain only LDS (lgkm), NOT vmem; then raw barrier.
    asm volatile("s_waitcnt lgkmcnt(0)" ::: "memory");
    __builtin_amdgcn_s_barrier();
    __builtin_amdgcn_sched_barrier(0);
  };

  #pragma unroll 1
  for (int it = 0; it < 64; ++it){
    body(2 * it,     sH0, sH1);
    body(2 * it + 1, sH1, sH0);
  }
}

// ---------------- u_word = tanh(wordenc @ waW^T + wab); sent_summ = sum over words ---
// grid = 64 sentences * 4 ntiles ; block 512.  Also writes word_w ones.
__global__ __launch_bounds__(512, 2) void k_uword(const u16* __restrict__ wenc, const float* __restrict__ waW,
                                                  const float* __restrict__ wab, u16* __restrict__ ssum,
                                                  float* __restrict__ outw){
  __shared__ u16 sA[128 * 64], sB[128 * 64];
  __shared__ float red[128];
  int bid = blockIdx.x; int s = bid >> 2, nt = bid & 3; int nbase = nt * 128;
  int t = threadIdx.x, w = t >> 6, l = t & 63, l15 = l & 15, l4 = l >> 4;
  int wm = w >> 2, wn = w & 3;
  int r0 = t >> 3, c0 = t & 7;
  const u16* Arow = wenc + s * 65536;
  const float* Brow = waW + nbase * 512;
  if (t < 128) red[t] = 0.f;
  if (t < 32) outw[s * 128 + nt * 32 + t] = 1.0f;   // word_w ones
  f32x4 acc[4][2];
  #pragma unroll
  for (int a = 0; a < 4; ++a){ acc[a][0] = {0.f,0.f,0.f,0.f}; acc[a][1] = {0.f,0.f,0.f,0.f}; }
  for (int ki = 0; ki < 8; ++ki){
    int k0 = ki * 64;
    s16x8 a0 = *(const s16x8*)&Arow[r0 * 512 + k0 + c0 * 8];
    s16x8 a1 = *(const s16x8*)&Arow[(64 + r0) * 512 + k0 + c0 * 8];
    s16x8 b0 = cvt8(&Brow[r0 * 512 + k0 + c0 * 8]);
    s16x8 b1 = cvt8(&Brow[(64 + r0) * 512 + k0 + c0 * 8]);
    __syncthreads();
    int sw = c0 ^ (r0 & 7);
    *(s16x8*)&sA[(r0 * 8 + sw) * 8] = a0;
    *(s16x8*)&sA[((64 + r0) * 8 + sw) * 8] = a1;
    *(s16x8*)&sB[(r0 * 8 + sw) * 8] = b0;
    *(s16x8*)&sB[((64 + r0) * 8 + sw) * 8] = b1;
    __syncthreads();
    #pragma unroll
    for (int kt = 0; kt < 2; ++kt){
      int ch = kt * 4 + l4;
      s16x8 bfr[2];
      #pragma unroll
      for (int n2 = 0; n2 < 2; ++n2){
        int rr = wn * 32 + n2 * 16 + l15;
        bfr[n2] = *(const s16x8*)&sB[(rr * 8 + (ch ^ (rr & 7))) * 8];
      }
      #pragma unroll
      for (int m2 = 0; m2 < 4; ++m2){
        int rr = wm * 64 + m2 * 16 + l15;
        s16x8 af = *(const s16x8*)&sA[(rr * 8 + (ch ^ (rr & 7))) * 8];
        acc[m2][0] = mfma16(af, bfr[0], acc[m2][0]);
        acc[m2][1] = mfma16(af, bfr[1], acc[m2][1]);
      }
    }
  }
  float bi0 = wab[nbase + wn * 32 + l15];
  float bi1 = wab[nbase + wn * 32 + 16 + l15];
  float p0 = 0.f, p1 = 0.f;
  #pragma unroll
  for (int m2 = 0; m2 < 4; ++m2){
    #pragma unroll
    for (int i = 0; i < 4; ++i){
      p0 += tanh_(acc[m2][0][i] + bi0);
      p1 += tanh_(acc[m2][1][i] + bi1);
    }
  }
  p0 += __shfl_xor(p0, 16); p0 += __shfl_xor(p0, 32);
  p1 += __shfl_xor(p1, 16); p1 += __shfl_xor(p1, 32);
  if (l4 == 0){
    atomicAdd(&red[wn * 32 + l15], p0);
    atomicAdd(&red[wn * 32 + 16 + l15], p1);
  }
  __syncthreads();
  if (t < 128) ssum[s * 512 + nbase + t] = f2b(red[t]);
}

// ---------------- sentence GRU (zero state): sentenc ---------------------------------
// grid = 2 dirs * 8 jblocks(64) ; block 512 (waves: 4M x 2J)
__global__ __launch_bounds__(512, 2) void k_sent(const u16* __restrict__ ssum, const float* __restrict__ sWi,
                                                 const float* __restrict__ sbi, const float* __restrict__ sbh,
                                                 u16* __restrict__ senc){
  __shared__ u16 sA[64 * 512]; // 64 KiB, swizzled
  int bid = blockIdx.x; int d = bid >> 3, jb8 = bid & 7; int jbase = jb8 * 64;
  int t = threadIdx.x, w = t >> 6, l = t & 63, l15 = l & 15, l4 = l >> 4;
  int wm = w >> 1, wj = w & 1;
  #pragma unroll
  for (int j = 0; j < 8; ++j){
    int q = j * 512 + t, r = q >> 6, c = q & 63;
    s16x8 v = *(const s16x8*)&ssum[r * 512 + c * 8];
    *(s16x8*)&sA[(r * 64 + (c ^ (r & 7))) * 8] = v;
  }
  __syncthreads();
  const float* Wd = sWi + d * 786432;
  f32x4 acc[3][2];
  #pragma unroll
  for (int a = 0; a < 3; ++a){ acc[a][0] = {0.f,0.f,0.f,0.f}; acc[a][1] = {0.f,0.f,0.f,0.f}; }
  int ra = wm * 16 + l15;
  #pragma unroll 4
  for (int kt = 0; kt < 16; ++kt){
    int ch = kt * 4 + l4;
    s16x8 af = *(const s16x8*)&sA[(ra * 64 + (ch ^ (ra & 7))) * 8];
    #pragma unroll
    for (int gt = 0; gt < 3; ++gt){
      #pragma unroll
      for (int jt = 0; jt < 2; ++jt){
        int n = gt * 512 + jbase + wj * 32 + jt * 16 + l15;
        s16x8 bf = cvt8(&Wd[n * 512 + kt * 32 + l4 * 8]);
        acc[gt][jt] = mfma16(af, bf, acc[gt][jt]);
      }
    }
  }
  float biv[3][2], bhv[3][2];
  #pragma unroll
  for (int gt = 0; gt < 3; ++gt){
    #pragma unroll
    for (int jt = 0; jt < 2; ++jt){
      int n = gt * 512 + jbase + wj * 32 + jt * 16 + l15;
      biv[gt][jt] = sbi[d * 1536 + n];
      bhv[gt][jt] = sbh[d * 1536 + n];
    }
  }
  #pragma unroll
  for (int jt = 0; jt < 2; ++jt){
    #pragma unroll
    for (int i = 0; i < 4; ++i){
      float r_ = sigm(acc[0][jt][i] + biv[0][jt] + bhv[0][jt]);
      float z_ = sigm(acc[1][jt][i] + biv[1][jt] + bhv[1][jt]);
      float n_ = tanh_(acc[2][jt][i] + biv[2][jt] + r_ * bhv[2][jt]);
      float sh = (1.f - z_) * n_;
      int srow = wm * 16 + l4 * 4 + i;
      senc[srow * 1024 + d * 512 + jbase + wj * 32 + jt * 16 + l15] = f2b(sh);
    }
  }
}

// ---------------- u_sent = tanh(sentenc @ saW^T + sab); doc = sum over sentences -----
// grid = 8 ntiles ; block 512 (waves 2M x 4N).  Also writes sent_w ones.
__global__ __launch_bounds__(512, 2) void k_usent(const u16* __restrict__ senc, const float* __restrict__ saW,
                                                  const float* __restrict__ sab, float* __restrict__ docv,
                                                  float* __restrict__ outw){
  __shared__ u16 sA[64 * 1024]; // 128 KiB, swizzled
  __shared__ float red[128];
  int bid = blockIdx.x; int nbase = bid * 128;
  int t = threadIdx.x, w = t >> 6, l = t & 63, l15 = l & 15, l4 = l >> 4;
  int wm = w >> 2, wn = w & 3;
  if (t < 128) red[t] = 0.f;
  if (t < 8) outw[8192 + bid * 8 + t] = 1.0f;   // sent_w ones
  #pragma unroll
  for (int j = 0; j < 16; ++j){
    int q = j * 512 + t, r = q >> 7, c = q & 127;
    s16x8 v = *(const s16x8*)&senc[r * 1024 + c * 8];
    *(s16x8*)&sA[(r * 128 + (c ^ (r & 7))) * 8] = v;
  }
  __syncthreads();
  f32x4 acc[2][2];
  #pragma unroll
  for (int a = 0; a < 2; ++a){ acc[a][0] = {0.f,0.f,0.f,0.f}; acc[a][1] = {0.f,0.f,0.f,0.f}; }
  #pragma unroll 4
  for (int kt = 0; kt < 32; ++kt){
    int ch = kt * 4 + l4;
    s16x8 af[2];
    #pragma unroll
    for (int mt = 0; mt < 2; ++mt){
      int r = wm * 32 + mt * 16 + l15;
      af[mt] = *(const s16x8*)&sA[(r * 128 + (ch ^ (r & 7))) * 8];
    }
    #pragma unroll
    for (int nt = 0; nt < 2; ++nt){
      int n = nbase + wn * 32 + nt * 16 + l15;
      s16x8 bf = cvt8(&saW[n * 1024 + kt * 32 + l4 * 8]);
      acc[0][nt] = mfma16(af[0], bf, acc[0][nt]);
      acc[1][nt] = mfma16(af[1], bf, acc[1][nt]);
    }
  }
  float b0 = sab[nbase + wn * 32 + l15];
  float b1 = sab[nbase + wn * 32 + 16 + l15];
  float p0 = 0.f, p1 = 0.f;
  #pragma unroll
  for (int mt = 0; mt < 2; ++mt){
    #pragma unroll
    for (int i = 0; i < 4; ++i){
      p0 += tanh_(acc[mt][0][i] + b0);
      p1 += tanh_(acc[mt][1][i] + b1);
    }
  }
  p0 += __shfl_xor(p0, 16); p0 += __shfl_xor(p0, 32);
  p1 += __shfl_xor(p1, 16); p1 += __shfl_xor(p1, 32);
  if (l4 == 0){
    atomicAdd(&red[wn * 32 + l15], p0);
    atomicAdd(&red[wn * 32 + 16 + l15], p1);
  }
  __syncthreads();
  if (t < 128) docv[nbase + t] = red[t];
}

// ---------------- logits + log_softmax ----------------------------------------------
__global__ __launch_bounds__(256) void k_final(const float* __restrict__ docv, const float* __restrict__ doW,
                                               const float* __restrict__ dob, float* __restrict__ out){
  __shared__ float lg[16];
  int w = threadIdx.x >> 6, l = threadIdx.x & 63;
  for (int c = w; c < 13; c += 4){
    float p = 0.f;
    for (int j = 0; j < 16; ++j){
      int k = j * 64 + l;
      p += docv[k] * doW[c * 1024 + k];
    }
    for (int o = 32; o >= 1; o >>= 1) p += __shfl_xor(p, o);
    if (l == 0) lg[c] = p + dob[c];
  }
  __syncthreads();
  if (threadIdx.x == 0){
    float m = lg[0];
    for (int c = 1; c < 13; ++c) m = fmaxf(m, lg[c]);
    float s = 0.f;
    for (int c = 0; c < 13; ++c) s += __expf(lg[c] - m);
    float ls = logf(s);
    for (int c = 0; c < 13; ++c) out[8256 + c] = lg[c] - m - ls;
  }
}

extern "C" void kernel_launch(void* const* d_in, const int* in_sizes, int n_in,
                              void* d_out, int out_size, void* d_ws, size_t ws_size,
                              hipStream_t stream) {
  (void)in_sizes; (void)n_in; (void)out_size; (void)ws_size;
  const int*   doc = (const int*)d_in[0];
  const float* emb = (const float*)d_in[1];
  const float* wWi = (const float*)d_in[2];
  const float* wWh = (const float*)d_in[3];
  const float* wbi = (const float*)d_in[4];
  const float* wbh = (const float*)d_in[5];
  const float* sWi = (const float*)d_in[6];
  // d_in[7] = s_Wh unused (sentence GRU sees zero state)
  const float* sbi = (const float*)d_in[8];
  const float* sbh = (const float*)d_in[9];
  const float* waW = (const float*)d_in[10];
  const float* wab = (const float*)d_in[11];
  // d_in[12] = uw_W unused (softmax over size-1 axis)
  const float* saW = (const float*)d_in[13];
  const float* sab = (const float*)d_in[14];
  // d_in[15] = us_W unused
  const float* doW = (const float*)d_in[16];
  const float* dob = (const float*)d_in[17];
  float* out = (float*)d_out;
  char* ws = (char*)d_ws;
  u16* gi    = (u16*)(ws);                    // 2*128*64*768 bf16 = 25,165,824 B
  u16* wenc  = (u16*)(ws + 25165824);         // 64*128*512 bf16  =  8,388,608 B
  u16* ssumv = (u16*)(ws + 33554432);         // 64*512 bf16      =     65,536 B
  u16* sencv = (u16*)(ws + 33619968);         // 64*1024 bf16     =    131,072 B
  float* docv = (float*)(ws + 33751040);      // 1024 f32         =      4,096 B

  k_gi    <<<768, 512, 0, stream>>>(doc, emb, wWi, wbi, wbh, gi);
  k_rec   <<<8, 512, 0, stream>>>(wWh, wbh, gi, wenc);
  k_uword <<<256, 512, 0, stream>>>(wenc, waW, wab, ssumv, out);
  k_sent  <<<16, 512, 0, stream>>>(ssumv, sWi, sbi, sbh, sencv);
  k_usent <<<8, 512, 0, stream>>>(sencv, saW, sab, docv, out);
  k_final <<<1, 256, 0, stream>>>(docv, doW, dob, out);
}

// Round 12
// 326.922 us; speedup vs baseline: 1.7297x; 1.0065x over previous
//
#include <hip/hip_runtime.h>
#include <hip/hip_bf16.h>

typedef unsigned short u16;
typedef __attribute__((ext_vector_type(8))) short s16x8;
typedef __attribute__((ext_vector_type(4))) float f32x4;
typedef __attribute__((ext_vector_type(4))) unsigned u32x4;

__device__ __forceinline__ float b2f(u16 v){
  unsigned u = ((unsigned)v) << 16; float f; __builtin_memcpy(&f, &u, 4); return f;
}
__device__ __forceinline__ float bits2f(unsigned u){
  float f; __builtin_memcpy(&f, &u, 4); return f;
}
__device__ __forceinline__ u16 f2b(float f){
  unsigned u; __builtin_memcpy(&u, &f, 4);
  unsigned r = (u + 0x7FFFu + ((u >> 16) & 1u)) >> 16; return (u16)r;
}
// pack 2 f32 -> u32 of 2 bf16 (v_cvt_pk_bf16_f32, RNE); x in low half
__device__ __forceinline__ unsigned pk2(float x, float y){
  __hip_bfloat162 q = __float22bfloat162_rn(float2{x, y});
  unsigned r; __builtin_memcpy(&r, &q, 4); return r;
}
// 8 consecutive f32 -> 8 bf16 (RNE) via 4x cvt_pk
__device__ __forceinline__ s16x8 cvt8(const float* __restrict__ p){
  f32x4 a = *(const f32x4*)p;
  f32x4 b = *(const f32x4*)(p + 4);
  u32x4 u; u[0]=pk2(a[0],a[1]); u[1]=pk2(a[2],a[3]); u[2]=pk2(b[0],b[1]); u[3]=pk2(b[2],b[3]);
  s16x8 r; __builtin_memcpy(&r, &u, 16); return r;
}
// scaled variant (for log2e-folded GRU weights)
__device__ __forceinline__ s16x8 cvt8s(const float* __restrict__ p, float s){
  f32x4 a = *(const f32x4*)p;
  f32x4 b = *(const f32x4*)(p + 4);
  u32x4 u; u[0]=pk2(a[0]*s,a[1]*s); u[1]=pk2(a[2]*s,a[3]*s); u[2]=pk2(b[0]*s,b[1]*s); u[3]=pk2(b[2]*s,b[3]*s);
  s16x8 r; __builtin_memcpy(&r, &u, 16); return r;
}
#define LOG2E  1.4426950408889634f
#define LOG2E2 2.8853900817779268f
// pre-activations arrive scaled by log2e (sigm) / 2*log2e (tanh)
__device__ __forceinline__ float sigm2(float x){        // = 1/(1+e^-a), x = log2e*a
  float e = __builtin_amdgcn_exp2f(-x);
  return __builtin_amdgcn_rcpf(1.f + e);
}
__device__ __forceinline__ float tanh2(float y){        // = tanh(a), y = 2*log2e*a
  float e = __builtin_amdgcn_exp2f(y);
  return 1.f - 2.f * __builtin_amdgcn_rcpf(e + 1.f);
}
// non-scaled versions for the small kernels
__device__ __forceinline__ float sigm(float x){
  float e = __builtin_amdgcn_exp2f(-x * LOG2E);
  return __builtin_amdgcn_rcpf(1.f + e);
}
__device__ __forceinline__ float tanh_(float x){
  float e = __builtin_amdgcn_exp2f(x * LOG2E2);
  return 1.f - 2.f * __builtin_amdgcn_rcpf(e + 1.f);
}
__device__ __forceinline__ f32x4 mfma16(s16x8 a, s16x8 b, f32x4 c){
  return __builtin_amdgcn_mfma_f32_16x16x32_bf16(a, b, c, 0, 0, 0);
}

// ---------------- gi = log2e-scaled (emb[doc] @ Wi^T + bi (+bh for r,z)) -------------
// NEW: grid = 64 sentences(mt) * 4 quarters(q) ; block 512.
// Full converted A-tile staged ONCE in LDS (stride-264: conflict-free both sides),
// then 3 (d,nt) weight-panels computed against it (A gather+cvt 12x -> 4x).
// gi layout (bf16): [d][word][sent][ gt*256 + whc*32 + l15*2 + jt ]  (jt-pairs in u32)
__global__ __launch_bounds__(512, 2) void k_gi(const int* __restrict__ doc, const float* __restrict__ emb,
                                               const float* __restrict__ wWi, const float* __restrict__ wbi,
                                               const float* __restrict__ wbh, u16* __restrict__ gi){
  __shared__ u16 sA[128 * 264];   // 67.6 KiB: full A tile, stride-264
  __shared__ u16 sB[128 * 64];    // 16 KiB: per-ki B tile (current swizzle)
  int bid = blockIdx.x;
  int mt = bid >> 2, q = bid & 3;
  int mbase = mt * 128;
  int t = threadIdx.x;
  int w = t >> 6, l = t & 63, l15 = l & 15, l4 = l >> 4;
  int wm = w >> 2, wn = w & 3; // 2 x 4 wave grid
  int r0 = t >> 3, c0 = t & 7;
  int tok0 = doc[mbase + r0];
  int tok1 = doc[mbase + 64 + r0];
  // stage full A (emb gather, f32->bf16): rows r0, r0+64; chunks (ki*8+c0)
  // write bank = 4*((r0+c0)&7)+... : 8 distinct-addr reqs/bank -> conflict-free
  #pragma unroll
  for (int ki = 0; ki < 4; ++ki){
    s16x8 a0 = cvt8(&emb[tok0 * 256 + ki * 64 + c0 * 8]);
    s16x8 a1 = cvt8(&emb[tok1 * 256 + ki * 64 + c0 * 8]);
    *(s16x8*)&sA[r0 * 264 + (ki * 8 + c0) * 8] = a0;
    *(s16x8*)&sA[(64 + r0) * 264 + (ki * 8 + c0) * 8] = a1;
  }
  #pragma unroll 1
  for (int p = 0; p < 3; ++p){
    int pi = q * 3 + p;
    int d = pi / 6, nt = pi % 6;
    int nbase = nt * 128;
    const float* Wb = wWi + d * 196608 + nbase * 256;
    f32x4 acc[4][2];
    #pragma unroll
    for (int a = 0; a < 4; ++a){ acc[a][0] = {0.f,0.f,0.f,0.f}; acc[a][1] = {0.f,0.f,0.f,0.f}; }
    for (int ki = 0; ki < 4; ++ki){
      s16x8 b0 = cvt8(&Wb[r0 * 256 + ki * 64 + c0 * 8]);
      s16x8 b1 = cvt8(&Wb[(64 + r0) * 256 + ki * 64 + c0 * 8]);
      __syncthreads();   // also guards sA staging on first iteration
      int sw = c0 ^ (r0 & 7);
      *(s16x8*)&sB[(r0 * 8 + sw) * 8] = b0;
      *(s16x8*)&sB[((64 + r0) * 8 + sw) * 8] = b1;
      __syncthreads();
      #pragma unroll
      for (int kt = 0; kt < 2; ++kt){
        int ch = kt * 4 + l4;
        s16x8 bfr[2];
        #pragma unroll
        for (int n2 = 0; n2 < 2; ++n2){
          int rr = wn * 32 + n2 * 16 + l15;
          bfr[n2] = *(const s16x8*)&sB[(rr * 8 + (ch ^ (rr & 7))) * 8];
        }
        #pragma unroll
        for (int m2 = 0; m2 < 4; ++m2){
          int rr = wm * 64 + m2 * 16 + l15;
          // af read bank = 4*(rr+chunk)+j : 8 distinct-addr reqs/bank -> conflict-free
          s16x8 af = *(const s16x8*)&sA[rr * 264 + (ki * 8 + ch) * 8];
          acc[m2][0] = mfma16(af, bfr[0], acc[m2][0]);
          acc[m2][1] = mfma16(af, bfr[1], acc[m2][1]);
        }
      }
    }
    int cgb = nbase + wn * 32;            // one gt per (nt,wn)
    int gt  = cgb >> 8;
    int whc = (cgb & 255) >> 5;
    float sg = (gt < 2) ? LOG2E : LOG2E2;
    int cg0 = cgb + l15, cg1 = cgb + 16 + l15;
    float bi0 = wbi[d * 768 + cg0] + ((gt < 2) ? wbh[d * 768 + cg0] : 0.f);
    float bi1 = wbi[d * 768 + cg1] + ((gt < 2) ? wbh[d * 768 + cg1] : 0.f);
    #pragma unroll
    for (int m2 = 0; m2 < 4; ++m2){
      #pragma unroll
      for (int i = 0; i < 4; ++i){
        int ml = wm * 64 + m2 * 16 + l4 * 4 + i;   // word index
        int base2 = ((d * 128 + ml) * 64 + mt) * 768 + gt * 256 + whc * 32;
        *(unsigned*)&gi[base2 + l15 * 2] = pk2(sg * (acc[m2][0][i] + bi0),
                                               sg * (acc[m2][1][i] + bi1));
      }
    }
  }
}

// ---------------- word GRU recurrence: 128 steps, per-block = (dir, 16 sentences) ----
// grid = 8 (d = bid&1, g = bid>>1), block 512 (8 waves, wave w owns 32 hidden cols)
// Weight split: r,z both halves + n jt0 in regs (160 VGPR); n jt1 in LDS.
// Stride-264 padded h buffers, NO swizzle (conflict-free, R11-proven best: 211us).
__global__ __launch_bounds__(512, 2) void k_rec(const float* __restrict__ wWh, const float* __restrict__ wbh,
                                                const u16* __restrict__ gi, u16* __restrict__ wenc){
  __shared__ u16 sBn1[32768];  // n-gate jt1 frags: [w][kt][lane*8] (64 KiB)
  __shared__ u16 sH0[4224];    // h buffers [16][264] bf16 (stride-padded, unswizzled)
  __shared__ u16 sH1[4224];
  int bid = blockIdx.x; int d = bid & 1, g = bid >> 1;
  int t = threadIdx.x, w = t >> 6, l = t & 63, l15 = l & 15, l4 = l >> 4;
  int jb = w * 32;
  const float* Wh = wWh + d * 196608;
  // r,z gates (scaled log2e), both jt halves: 32 frags = 128 regs
  s16x8 bR[2][2][8];
  #pragma unroll
  for (int gt = 0; gt < 2; ++gt)
    #pragma unroll
    for (int jt = 0; jt < 2; ++jt)
      #pragma unroll
      for (int kt = 0; kt < 8; ++kt){
        int n = gt * 256 + jb + jt * 16 + l15;
        bR[gt][jt][kt] = cvt8s(&Wh[n * 256 + kt * 32 + l4 * 8], LOG2E);
      }
  // n gate jt0 (scaled 2log2e): 8 frags = 32 regs
  s16x8 bN0[8];
  #pragma unroll
  for (int kt = 0; kt < 8; ++kt){
    int n = 512 + jb + l15;
    bN0[kt] = cvt8s(&Wh[n * 256 + kt * 32 + l4 * 8], LOG2E2);
  }
  // n gate jt1 to LDS (linear per-lane layout: conflict-free)
  #pragma unroll
  for (int kt = 0; kt < 8; ++kt){
    int n = 512 + jb + 16 + l15;
    s16x8 v = cvt8s(&Wh[n * 256 + kt * 32 + l4 * 8], LOG2E2);
    *(s16x8*)&sBn1[((w * 8 + kt) * 64 + l) * 8] = v;
  }
  // zero-init h buffer 0: rows 0..15, elems 0..255 of each 264-elem row
  {
    int zr = t >> 5, zc = (t & 31) * 8;
    s16x8 z8 = {0,0,0,0,0,0,0,0};
    *(s16x8*)&sH0[zr * 264 + zc] = z8;
  }
  float hloc[2][4] = {{0.f,0.f,0.f,0.f},{0.f,0.f,0.f,0.f}};
  float bhn[2];
  #pragma unroll
  for (int jt = 0; jt < 2; ++jt)
    bhn[jt] = wbh[d * 768 + 512 + jb + jt * 16 + l15] * LOG2E2;  // pre-scaled

  // gi layout: [d][word][sent][768'] with jt-paired u32 at gt*256 + jb + l15*2
  const u16* gb = gi + d * 6291456 + (g * 16 + l4 * 4) * 768 + jb + l15 * 2;
  u16* wbase = wenc + ((g * 16 + l4 * 4) * 128) * 512 + d * 256 + jb + l15;

  // prefetch step 0's gate values (12 u32 per thread)
  unsigned g32[3][4];
  #pragma unroll
  for (int gt = 0; gt < 3; ++gt)
    #pragma unroll
    for (int i = 0; i < 4; ++i)
      g32[gt][i] = *(const unsigned*)&gb[gt * 256 + i * 768];
  __syncthreads();

  auto body = [&](int step, const u16* shc, u16* shn){
    // acc init = gate pre-activations (MFMA C-in): acc0=ir, acc1=iz, acc2=bhn
    f32x4 acc[3][2];
    #pragma unroll
    for (int i = 0; i < 4; ++i){
      acc[0][0][i] = bits2f(g32[0][i] << 16);
      acc[0][1][i] = bits2f(g32[0][i] & 0xffff0000u);
      acc[1][0][i] = bits2f(g32[1][i] << 16);
      acc[1][1][i] = bits2f(g32[1][i] & 0xffff0000u);
      acc[2][0][i] = bhn[0];
      acc[2][1][i] = bhn[1];
    }
    #pragma unroll
    for (int kt = 0; kt < 8; ++kt){
      int ch = kt * 4 + l4;
      s16x8 af = *(const s16x8*)&shc[l15 * 264 + ch * 8];
      acc[0][0] = mfma16(af, bR[0][0][kt], acc[0][0]);
      acc[0][1] = mfma16(af, bR[0][1][kt], acc[0][1]);
      acc[1][0] = mfma16(af, bR[1][0][kt], acc[1][0]);
      acc[1][1] = mfma16(af, bR[1][1][kt], acc[1][1]);
      acc[2][0] = mfma16(af, bN0[kt], acc[2][0]);
      s16x8 bn1 = *(const s16x8*)&sBn1[((w * 8 + kt) * 64 + l) * 8];
      acc[2][1] = mfma16(af, bn1, acc[2][1]);
    }
    u16 hb[2][4];
    #pragma unroll
    for (int jt = 0; jt < 2; ++jt){
      #pragma unroll
      for (int i = 0; i < 4; ++i){
        unsigned v2 = g32[2][i];
        float inn = (jt == 0) ? bits2f(v2 << 16) : bits2f(v2 & 0xffff0000u);
        float r = sigm2(acc[0][jt][i]);
        float z = sigm2(acc[1][jt][i]);
        float nn = tanh2(inn + r * acc[2][jt][i]);
        float h = nn + z * (hloc[jt][i] - nn);
        hloc[jt][i] = h;
      }
      unsigned b01 = pk2(hloc[jt][0], hloc[jt][1]);
      unsigned b23 = pk2(hloc[jt][2], hloc[jt][3]);
      hb[jt][0] = (u16)b01; hb[jt][1] = (u16)(b01 >> 16);
      hb[jt][2] = (u16)b23; hb[jt][3] = (u16)(b23 >> 16);
    }
    // prefetch next step's gate values; stay in flight across the raw barrier.
    // Final iteration reads past gi (lands in wenc region; values unused).
    {
      const u16* gp = gb + (step + 1) * 49152;
      #pragma unroll
      for (int gt = 0; gt < 3; ++gt)
        #pragma unroll
        for (int i = 0; i < 4; ++i)
          g32[gt][i] = *(const unsigned*)&gp[gt * 256 + i * 768];
    }
    #pragma unroll
    for (int jt = 0; jt < 2; ++jt){
      #pragma unroll
      for (int i = 0; i < 4; ++i){
        int s = l4 * 4 + i, c = jb + jt * 16 + l15;
        shn[s * 264 + c] = hb[jt][i];
        wbase[(i * 128 + step) * 512 + jt * 16] = hb[jt][i];  // fire-and-forget
      }
    }
    // drain only LDS (lgkm), NOT vmem; then raw barrier.
    asm volatile("s_waitcnt lgkmcnt(0)" ::: "memory");
    __builtin_amdgcn_s_barrier();
    __builtin_amdgcn_sched_barrier(0);
  };

  #pragma unroll 1
  for (int it = 0; it < 64; ++it){
    body(2 * it,     sH0, sH1);
    body(2 * it + 1, sH1, sH0);
  }
}

// ---------------- u_word = tanh(wordenc @ waW^T + wab); sent_summ = sum over words ---
// grid = 64 sentences * 4 ntiles ; block 512.  Also writes word_w ones.
__global__ __launch_bounds__(512, 2) void k_uword(const u16* __restrict__ wenc, const float* __restrict__ waW,
                                                  const float* __restrict__ wab, u16* __restrict__ ssum,
                                                  float* __restrict__ outw){
  __shared__ u16 sA[128 * 64], sB[128 * 64];
  __shared__ float red[128];
  int bid = blockIdx.x; int s = bid >> 2, nt = bid & 3; int nbase = nt * 128;
  int t = threadIdx.x, w = t >> 6, l = t & 63, l15 = l & 15, l4 = l >> 4;
  int wm = w >> 2, wn = w & 3;
  int r0 = t >> 3, c0 = t & 7;
  const u16* Arow = wenc + s * 65536;
  const float* Brow = waW + nbase * 512;
  if (t < 128) red[t] = 0.f;
  if (t < 32) outw[s * 128 + nt * 32 + t] = 1.0f;   // word_w ones
  f32x4 acc[4][2];
  #pragma unroll
  for (int a = 0; a < 4; ++a){ acc[a][0] = {0.f,0.f,0.f,0.f}; acc[a][1] = {0.f,0.f,0.f,0.f}; }
  for (int ki = 0; ki < 8; ++ki){
    int k0 = ki * 64;
    s16x8 a0 = *(const s16x8*)&Arow[r0 * 512 + k0 + c0 * 8];
    s16x8 a1 = *(const s16x8*)&Arow[(64 + r0) * 512 + k0 + c0 * 8];
    s16x8 b0 = cvt8(&Brow[r0 * 512 + k0 + c0 * 8]);
    s16x8 b1 = cvt8(&Brow[(64 + r0) * 512 + k0 + c0 * 8]);
    __syncthreads();
    int sw = c0 ^ (r0 & 7);
    *(s16x8*)&sA[(r0 * 8 + sw) * 8] = a0;
    *(s16x8*)&sA[((64 + r0) * 8 + sw) * 8] = a1;
    *(s16x8*)&sB[(r0 * 8 + sw) * 8] = b0;
    *(s16x8*)&sB[((64 + r0) * 8 + sw) * 8] = b1;
    __syncthreads();
    #pragma unroll
    for (int kt = 0; kt < 2; ++kt){
      int ch = kt * 4 + l4;
      s16x8 bfr[2];
      #pragma unroll
      for (int n2 = 0; n2 < 2; ++n2){
        int rr = wn * 32 + n2 * 16 + l15;
        bfr[n2] = *(const s16x8*)&sB[(rr * 8 + (ch ^ (rr & 7))) * 8];
      }
      #pragma unroll
      for (int m2 = 0; m2 < 4; ++m2){
        int rr = wm * 64 + m2 * 16 + l15;
        s16x8 af = *(const s16x8*)&sA[(rr * 8 + (ch ^ (rr & 7))) * 8];
        acc[m2][0] = mfma16(af, bfr[0], acc[m2][0]);
        acc[m2][1] = mfma16(af, bfr[1], acc[m2][1]);
      }
    }
  }
  float bi0 = wab[nbase + wn * 32 + l15];
  float bi1 = wab[nbase + wn * 32 + 16 + l15];
  float p0 = 0.f, p1 = 0.f;
  #pragma unroll
  for (int m2 = 0; m2 < 4; ++m2){
    #pragma unroll
    for (int i = 0; i < 4; ++i){
      p0 += tanh_(acc[m2][0][i] + bi0);
      p1 += tanh_(acc[m2][1][i] + bi1);
    }
  }
  p0 += __shfl_xor(p0, 16); p0 += __shfl_xor(p0, 32);
  p1 += __shfl_xor(p1, 16); p1 += __shfl_xor(p1, 32);
  if (l4 == 0){
    atomicAdd(&red[wn * 32 + l15], p0);
    atomicAdd(&red[wn * 32 + 16 + l15], p1);
  }
  __syncthreads();
  if (t < 128) ssum[s * 512 + nbase + t] = f2b(red[t]);
}

// ---------------- sentence GRU (zero state): sentenc ---------------------------------
// grid = 2 dirs * 8 jblocks(64) ; block 512 (waves: 4M x 2J)
__global__ __launch_bounds__(512, 2) void k_sent(const u16* __restrict__ ssum, const float* __restrict__ sWi,
                                                 const float* __restrict__ sbi, const float* __restrict__ sbh,
                                                 u16* __restrict__ senc){
  __shared__ u16 sA[64 * 512]; // 64 KiB, swizzled
  int bid = blockIdx.x; int d = bid >> 3, jb8 = bid & 7; int jbase = jb8 * 64;
  int t = threadIdx.x, w = t >> 6, l = t & 63, l15 = l & 15, l4 = l >> 4;
  int wm = w >> 1, wj = w & 1;
  #pragma unroll
  for (int j = 0; j < 8; ++j){
    int q = j * 512 + t, r = q >> 6, c = q & 63;
    s16x8 v = *(const s16x8*)&ssum[r * 512 + c * 8];
    *(s16x8*)&sA[(r * 64 + (c ^ (r & 7))) * 8] = v;
  }
  __syncthreads();
  const float* Wd = sWi + d * 786432;
  f32x4 acc[3][2];
  #pragma unroll
  for (int a = 0; a < 3; ++a){ acc[a][0] = {0.f,0.f,0.f,0.f}; acc[a][1] = {0.f,0.f,0.f,0.f}; }
  int ra = wm * 16 + l15;
  #pragma unroll 4
  for (int kt = 0; kt < 16; ++kt){
    int ch = kt * 4 + l4;
    s16x8 af = *(const s16x8*)&sA[(ra * 64 + (ch ^ (ra & 7))) * 8];
    #pragma unroll
    for (int gt = 0; gt < 3; ++gt){
      #pragma unroll
      for (int jt = 0; jt < 2; ++jt){
        int n = gt * 512 + jbase + wj * 32 + jt * 16 + l15;
        s16x8 bf = cvt8(&Wd[n * 512 + kt * 32 + l4 * 8]);
        acc[gt][jt] = mfma16(af, bf, acc[gt][jt]);
      }
    }
  }
  float biv[3][2], bhv[3][2];
  #pragma unroll
  for (int gt = 0; gt < 3; ++gt){
    #pragma unroll
    for (int jt = 0; jt < 2; ++jt){
      int n = gt * 512 + jbase + wj * 32 + jt * 16 + l15;
      biv[gt][jt] = sbi[d * 1536 + n];
      bhv[gt][jt] = sbh[d * 1536 + n];
    }
  }
  #pragma unroll
  for (int jt = 0; jt < 2; ++jt){
    #pragma unroll
    for (int i = 0; i < 4; ++i){
      float r_ = sigm(acc[0][jt][i] + biv[0][jt] + bhv[0][jt]);
      float z_ = sigm(acc[1][jt][i] + biv[1][jt] + bhv[1][jt]);
      float n_ = tanh_(acc[2][jt][i] + biv[2][jt] + r_ * bhv[2][jt]);
      float sh = (1.f - z_) * n_;
      int srow = wm * 16 + l4 * 4 + i;
      senc[srow * 1024 + d * 512 + jbase + wj * 32 + jt * 16 + l15] = f2b(sh);
    }
  }
}

// ---------------- u_sent = tanh(sentenc @ saW^T + sab); doc = sum over sentences -----
// grid = 8 ntiles ; block 512 (waves 2M x 4N).  Also writes sent_w ones.
__global__ __launch_bounds__(512, 2) void k_usent(const u16* __restrict__ senc, const float* __restrict__ saW,
                                                  const float* __restrict__ sab, float* __restrict__ docv,
                                                  float* __restrict__ outw){
  __shared__ u16 sA[64 * 1024]; // 128 KiB, swizzled
  __shared__ float red[128];
  int bid = blockIdx.x; int nbase = bid * 128;
  int t = threadIdx.x, w = t >> 6, l = t & 63, l15 = l & 15, l4 = l >> 4;
  int wm = w >> 2, wn = w & 3;
  if (t < 128) red[t] = 0.f;
  if (t < 8) outw[8192 + bid * 8 + t] = 1.0f;   // sent_w ones
  #pragma unroll
  for (int j = 0; j < 16; ++j){
    int q = j * 512 + t, r = q >> 7, c = q & 127;
    s16x8 v = *(const s16x8*)&senc[r * 1024 + c * 8];
    *(s16x8*)&sA[(r * 128 + (c ^ (r & 7))) * 8] = v;
  }
  __syncthreads();
  f32x4 acc[2][2];
  #pragma unroll
  for (int a = 0; a < 2; ++a){ acc[a][0] = {0.f,0.f,0.f,0.f}; acc[a][1] = {0.f,0.f,0.f,0.f}; }
  #pragma unroll 4
  for (int kt = 0; kt < 32; ++kt){
    int ch = kt * 4 + l4;
    s16x8 af[2];
    #pragma unroll
    for (int mt = 0; mt < 2; ++mt){
      int r = wm * 32 + mt * 16 + l15;
      af[mt] = *(const s16x8*)&sA[(r * 128 + (ch ^ (r & 7))) * 8];
    }
    #pragma unroll
    for (int nt = 0; nt < 2; ++nt){
      int n = nbase + wn * 32 + nt * 16 + l15;
      s16x8 bf = cvt8(&saW[n * 1024 + kt * 32 + l4 * 8]);
      acc[0][nt] = mfma16(af[0], bf, acc[0][nt]);
      acc[1][nt] = mfma16(af[1], bf, acc[1][nt]);
    }
  }
  float b0 = sab[nbase + wn * 32 + l15];
  float b1 = sab[nbase + wn * 32 + 16 + l15];
  float p0 = 0.f, p1 = 0.f;
  #pragma unroll
  for (int mt = 0; mt < 2; ++mt){
    #pragma unroll
    for (int i = 0; i < 4; ++i){
      p0 += tanh_(acc[mt][0][i] + b0);
      p1 += tanh_(acc[mt][1][i] + b1);
    }
  }
  p0 += __shfl_xor(p0, 16); p0 += __shfl_xor(p0, 32);
  p1 += __shfl_xor(p1, 16); p1 += __shfl_xor(p1, 32);
  if (l4 == 0){
    atomicAdd(&red[wn * 32 + l15], p0);
    atomicAdd(&red[wn * 32 + 16 + l15], p1);
  }
  __syncthreads();
  if (t < 128) docv[nbase + t] = red[t];
}

// ---------------- logits + log_softmax ----------------------------------------------
__global__ __launch_bounds__(256) void k_final(const float* __restrict__ docv, const float* __restrict__ doW,
                                               const float* __restrict__ dob, float* __restrict__ out){
  __shared__ float lg[16];
  int w = threadIdx.x >> 6, l = threadIdx.x & 63;
  for (int c = w; c < 13; c += 4){
    float p = 0.f;
    for (int j = 0; j < 16; ++j){
      int k = j * 64 + l;
      p += docv[k] * doW[c * 1024 + k];
    }
    for (int o = 32; o >= 1; o >>= 1) p += __shfl_xor(p, o);
    if (l == 0) lg[c] = p + dob[c];
  }
  __syncthreads();
  if (threadIdx.x == 0){
    float m = lg[0];
    for (int c = 1; c < 13; ++c) m = fmaxf(m, lg[c]);
    float s = 0.f;
    for (int c = 0; c < 13; ++c) s += __expf(lg[c] - m);
    float ls = logf(s);
    for (int c = 0; c < 13; ++c) out[8256 + c] = lg[c] - m - ls;
  }
}

extern "C" void kernel_launch(void* const* d_in, const int* in_sizes, int n_in,
                              void* d_out, int out_size, void* d_ws, size_t ws_size,
                              hipStream_t stream) {
  (void)in_sizes; (void)n_in; (void)out_size; (void)ws_size;
  const int*   doc = (const int*)d_in[0];
  const float* emb = (const float*)d_in[1];
  const float* wWi = (const float*)d_in[2];
  const float* wWh = (const float*)d_in[3];
  const float* wbi = (const float*)d_in[4];
  const float* wbh = (const float*)d_in[5];
  const float* sWi = (const float*)d_in[6];
  // d_in[7] = s_Wh unused (sentence GRU sees zero state)
  const float* sbi = (const float*)d_in[8];
  const float* sbh = (const float*)d_in[9];
  const float* waW = (const float*)d_in[10];
  const float* wab = (const float*)d_in[11];
  // d_in[12] = uw_W unused (softmax over size-1 axis)
  const float* saW = (const float*)d_in[13];
  const float* sab = (const float*)d_in[14];
  // d_in[15] = us_W unused
  const float* doW = (const float*)d_in[16];
  const float* dob = (const float*)d_in[17];
  float* out = (float*)d_out;
  char* ws = (char*)d_ws;
  u16* gi    = (u16*)(ws);                    // 2*128*64*768 bf16 = 25,165,824 B
  u16* wenc  = (u16*)(ws + 25165824);         // 64*128*512 bf16  =  8,388,608 B
  u16* ssumv = (u16*)(ws + 33554432);         // 64*512 bf16      =     65,536 B
  u16* sencv = (u16*)(ws + 33619968);         // 64*1024 bf16     =    131,072 B
  float* docv = (float*)(ws + 33751040);      // 1024 f32         =      4,096 B

  k_gi    <<<256, 512, 0, stream>>>(doc, emb, wWi, wbi, wbh, gi);
  k_rec   <<<8, 512, 0, stream>>>(wWh, wbh, gi, wenc);
  k_uword <<<256, 512, 0, stream>>>(wenc, waW, wab, ssumv, out);
  k_sent  <<<16, 512, 0, stream>>>(ssumv, sWi, sbi, sbh, sencv);
  k_usent <<<8, 512, 0, stream>>>(sencv, saW, sab, docv, out);
  k_final <<<1, 256, 0, stream>>>(docv, doW, dob, out);
}

// Round 13
// 276.094 us; speedup vs baseline: 2.0481x; 1.1841x over previous
//
#include <hip/hip_runtime.h>
#include <hip/hip_bf16.h>

typedef unsigned short u16;
typedef __attribute__((ext_vector_type(8))) short s16x8;
typedef __attribute__((ext_vector_type(4))) float f32x4;
typedef __attribute__((ext_vector_type(4))) unsigned u32x4;

__device__ __forceinline__ float b2f(u16 v){
  unsigned u = ((unsigned)v) << 16; float f; __builtin_memcpy(&f, &u, 4); return f;
}
__device__ __forceinline__ float bits2f(unsigned u){
  float f; __builtin_memcpy(&f, &u, 4); return f;
}
__device__ __forceinline__ u16 f2b(float f){
  unsigned u; __builtin_memcpy(&u, &f, 4);
  unsigned r = (u + 0x7FFFu + ((u >> 16) & 1u)) >> 16; return (u16)r;
}
// pack 2 f32 -> u32 of 2 bf16 (v_cvt_pk_bf16_f32, RNE); x in low half
__device__ __forceinline__ unsigned pk2(float x, float y){
  __hip_bfloat162 q = __float22bfloat162_rn(float2{x, y});
  unsigned r; __builtin_memcpy(&r, &q, 4); return r;
}
// 8 consecutive f32 -> 8 bf16 (RNE) via 4x cvt_pk
__device__ __forceinline__ s16x8 cvt8(const float* __restrict__ p){
  f32x4 a = *(const f32x4*)p;
  f32x4 b = *(const f32x4*)(p + 4);
  u32x4 u; u[0]=pk2(a[0],a[1]); u[1]=pk2(a[2],a[3]); u[2]=pk2(b[0],b[1]); u[3]=pk2(b[2],b[3]);
  s16x8 r; __builtin_memcpy(&r, &u, 16); return r;
}
// scaled variant (for log2e-folded GRU weights)
__device__ __forceinline__ s16x8 cvt8s(const float* __restrict__ p, float s){
  f32x4 a = *(const f32x4*)p;
  f32x4 b = *(const f32x4*)(p + 4);
  u32x4 u; u[0]=pk2(a[0]*s,a[1]*s); u[1]=pk2(a[2]*s,a[3]*s); u[2]=pk2(b[0]*s,b[1]*s); u[3]=pk2(b[2]*s,b[3]*s);
  s16x8 r; __builtin_memcpy(&r, &u, 16); return r;
}
#define LOG2E  1.4426950408889634f
#define LOG2E2 2.8853900817779268f
__device__ __forceinline__ float sigm2(float x){        // = 1/(1+e^-a), x = log2e*a
  float e = __builtin_amdgcn_exp2f(-x);
  return __builtin_amdgcn_rcpf(1.f + e);
}
__device__ __forceinline__ float tanh2(float y){        // = tanh(a), y = 2*log2e*a
  float e = __builtin_amdgcn_exp2f(y);
  return 1.f - 2.f * __builtin_amdgcn_rcpf(e + 1.f);
}
__device__ __forceinline__ float sigm(float x){
  float e = __builtin_amdgcn_exp2f(-x * LOG2E);
  return __builtin_amdgcn_rcpf(1.f + e);
}
__device__ __forceinline__ float tanh_(float x){
  float e = __builtin_amdgcn_exp2f(x * LOG2E2);
  return 1.f - 2.f * __builtin_amdgcn_rcpf(e + 1.f);
}
__device__ __forceinline__ f32x4 mfma16(s16x8 a, s16x8 b, f32x4 c){
  return __builtin_amdgcn_mfma_f32_16x16x32_bf16(a, b, c, 0, 0, 0);
}

// ---------------- gi = log2e-scaled (emb[doc] @ Wi^T + bi (+bh for r,z)) -------------
// grid = 64 sentences(mt) * 4 quarters(q) ; block 512.
__global__ __launch_bounds__(512, 2) void k_gi(const int* __restrict__ doc, const float* __restrict__ emb,
                                               const float* __restrict__ wWi, const float* __restrict__ wbi,
                                               const float* __restrict__ wbh, u16* __restrict__ gi){
  __shared__ u16 sA[128 * 264];   // 67.6 KiB: full A tile, stride-264
  __shared__ u16 sB[128 * 64];    // 16 KiB: per-ki B tile
  int bid = blockIdx.x;
  int mt = bid >> 2, q = bid & 3;
  int mbase = mt * 128;
  int t = threadIdx.x;
  int w = t >> 6, l = t & 63, l15 = l & 15, l4 = l >> 4;
  int wm = w >> 2, wn = w & 3; // 2 x 4 wave grid
  int r0 = t >> 3, c0 = t & 7;
  int tok0 = doc[mbase + r0];
  int tok1 = doc[mbase + 64 + r0];
  #pragma unroll
  for (int ki = 0; ki < 4; ++ki){
    s16x8 a0 = cvt8(&emb[tok0 * 256 + ki * 64 + c0 * 8]);
    s16x8 a1 = cvt8(&emb[tok1 * 256 + ki * 64 + c0 * 8]);
    *(s16x8*)&sA[r0 * 264 + (ki * 8 + c0) * 8] = a0;
    *(s16x8*)&sA[(64 + r0) * 264 + (ki * 8 + c0) * 8] = a1;
  }
  #pragma unroll 1
  for (int p = 0; p < 3; ++p){
    int pi = q * 3 + p;
    int d = pi / 6, nt = pi % 6;
    int nbase = nt * 128;
    const float* Wb = wWi + d * 196608 + nbase * 256;
    f32x4 acc[4][2];
    #pragma unroll
    for (int a = 0; a < 4; ++a){ acc[a][0] = {0.f,0.f,0.f,0.f}; acc[a][1] = {0.f,0.f,0.f,0.f}; }
    for (int ki = 0; ki < 4; ++ki){
      s16x8 b0 = cvt8(&Wb[r0 * 256 + ki * 64 + c0 * 8]);
      s16x8 b1 = cvt8(&Wb[(64 + r0) * 256 + ki * 64 + c0 * 8]);
      __syncthreads();   // also guards sA staging on first iteration
      int sw = c0 ^ (r0 & 7);
      *(s16x8*)&sB[(r0 * 8 + sw) * 8] = b0;
      *(s16x8*)&sB[((64 + r0) * 8 + sw) * 8] = b1;
      __syncthreads();
      #pragma unroll
      for (int kt = 0; kt < 2; ++kt){
        int ch = kt * 4 + l4;
        s16x8 bfr[2];
        #pragma unroll
        for (int n2 = 0; n2 < 2; ++n2){
          int rr = wn * 32 + n2 * 16 + l15;
          bfr[n2] = *(const s16x8*)&sB[(rr * 8 + (ch ^ (rr & 7))) * 8];
        }
        #pragma unroll
        for (int m2 = 0; m2 < 4; ++m2){
          int rr = wm * 64 + m2 * 16 + l15;
          s16x8 af = *(const s16x8*)&sA[rr * 264 + (ki * 8 + ch) * 8];
          acc[m2][0] = mfma16(af, bfr[0], acc[m2][0]);
          acc[m2][1] = mfma16(af, bfr[1], acc[m2][1]);
        }
      }
    }
    int cgb = nbase + wn * 32;            // one gt per (nt,wn)
    int gt  = cgb >> 8;
    int whc = (cgb & 255) >> 5;
    float sg = (gt < 2) ? LOG2E : LOG2E2;
    int cg0 = cgb + l15, cg1 = cgb + 16 + l15;
    float bi0 = wbi[d * 768 + cg0] + ((gt < 2) ? wbh[d * 768 + cg0] : 0.f);
    float bi1 = wbi[d * 768 + cg1] + ((gt < 2) ? wbh[d * 768 + cg1] : 0.f);
    #pragma unroll
    for (int m2 = 0; m2 < 4; ++m2){
      #pragma unroll
      for (int i = 0; i < 4; ++i){
        int ml = wm * 64 + m2 * 16 + l4 * 4 + i;   // word index
        int base2 = ((d * 128 + ml) * 64 + mt) * 768 + gt * 256 + whc * 32;
        *(unsigned*)&gi[base2 + l15 * 2] = pk2(sg * (acc[m2][0][i] + bi0),
                                               sg * (acc[m2][1][i] + bi1));
      }
    }
  }
}

// ---------------- word GRU recurrence (FROZEN best config: 211us) --------------------
__global__ __launch_bounds__(512, 2) void k_rec(const float* __restrict__ wWh, const float* __restrict__ wbh,
                                                const u16* __restrict__ gi, u16* __restrict__ wenc){
  __shared__ u16 sBn1[32768];  // n-gate jt1 frags: [w][kt][lane*8] (64 KiB)
  __shared__ u16 sH0[4224];    // h buffers [16][264] bf16 (stride-padded, unswizzled)
  __shared__ u16 sH1[4224];
  int bid = blockIdx.x; int d = bid & 1, g = bid >> 1;
  int t = threadIdx.x, w = t >> 6, l = t & 63, l15 = l & 15, l4 = l >> 4;
  int jb = w * 32;
  const float* Wh = wWh + d * 196608;
  s16x8 bR[2][2][8];
  #pragma unroll
  for (int gt = 0; gt < 2; ++gt)
    #pragma unroll
    for (int jt = 0; jt < 2; ++jt)
      #pragma unroll
      for (int kt = 0; kt < 8; ++kt){
        int n = gt * 256 + jb + jt * 16 + l15;
        bR[gt][jt][kt] = cvt8s(&Wh[n * 256 + kt * 32 + l4 * 8], LOG2E);
      }
  s16x8 bN0[8];
  #pragma unroll
  for (int kt = 0; kt < 8; ++kt){
    int n = 512 + jb + l15;
    bN0[kt] = cvt8s(&Wh[n * 256 + kt * 32 + l4 * 8], LOG2E2);
  }
  #pragma unroll
  for (int kt = 0; kt < 8; ++kt){
    int n = 512 + jb + 16 + l15;
    s16x8 v = cvt8s(&Wh[n * 256 + kt * 32 + l4 * 8], LOG2E2);
    *(s16x8*)&sBn1[((w * 8 + kt) * 64 + l) * 8] = v;
  }
  {
    int zr = t >> 5, zc = (t & 31) * 8;
    s16x8 z8 = {0,0,0,0,0,0,0,0};
    *(s16x8*)&sH0[zr * 264 + zc] = z8;
  }
  float hloc[2][4] = {{0.f,0.f,0.f,0.f},{0.f,0.f,0.f,0.f}};
  float bhn[2];
  #pragma unroll
  for (int jt = 0; jt < 2; ++jt)
    bhn[jt] = wbh[d * 768 + 512 + jb + jt * 16 + l15] * LOG2E2;

  const u16* gb = gi + d * 6291456 + (g * 16 + l4 * 4) * 768 + jb + l15 * 2;
  u16* wbase = wenc + ((g * 16 + l4 * 4) * 128) * 512 + d * 256 + jb + l15;

  unsigned g32[3][4];
  #pragma unroll
  for (int gt = 0; gt < 3; ++gt)
    #pragma unroll
    for (int i = 0; i < 4; ++i)
      g32[gt][i] = *(const unsigned*)&gb[gt * 256 + i * 768];
  __syncthreads();

  auto body = [&](int step, const u16* shc, u16* shn){
    f32x4 acc[3][2];
    #pragma unroll
    for (int i = 0; i < 4; ++i){
      acc[0][0][i] = bits2f(g32[0][i] << 16);
      acc[0][1][i] = bits2f(g32[0][i] & 0xffff0000u);
      acc[1][0][i] = bits2f(g32[1][i] << 16);
      acc[1][1][i] = bits2f(g32[1][i] & 0xffff0000u);
      acc[2][0][i] = bhn[0];
      acc[2][1][i] = bhn[1];
    }
    #pragma unroll
    for (int kt = 0; kt < 8; ++kt){
      int ch = kt * 4 + l4;
      s16x8 af = *(const s16x8*)&shc[l15 * 264 + ch * 8];
      acc[0][0] = mfma16(af, bR[0][0][kt], acc[0][0]);
      acc[0][1] = mfma16(af, bR[0][1][kt], acc[0][1]);
      acc[1][0] = mfma16(af, bR[1][0][kt], acc[1][0]);
      acc[1][1] = mfma16(af, bR[1][1][kt], acc[1][1]);
      acc[2][0] = mfma16(af, bN0[kt], acc[2][0]);
      s16x8 bn1 = *(const s16x8*)&sBn1[((w * 8 + kt) * 64 + l) * 8];
      acc[2][1] = mfma16(af, bn1, acc[2][1]);
    }
    u16 hb[2][4];
    #pragma unroll
    for (int jt = 0; jt < 2; ++jt){
      #pragma unroll
      for (int i = 0; i < 4; ++i){
        unsigned v2 = g32[2][i];
        float inn = (jt == 0) ? bits2f(v2 << 16) : bits2f(v2 & 0xffff0000u);
        float r = sigm2(acc[0][jt][i]);
        float z = sigm2(acc[1][jt][i]);
        float nn = tanh2(inn + r * acc[2][jt][i]);
        float h = nn + z * (hloc[jt][i] - nn);
        hloc[jt][i] = h;
      }
      unsigned b01 = pk2(hloc[jt][0], hloc[jt][1]);
      unsigned b23 = pk2(hloc[jt][2], hloc[jt][3]);
      hb[jt][0] = (u16)b01; hb[jt][1] = (u16)(b01 >> 16);
      hb[jt][2] = (u16)b23; hb[jt][3] = (u16)(b23 >> 16);
    }
    {
      const u16* gp = gb + (step + 1) * 49152;
      #pragma unroll
      for (int gt = 0; gt < 3; ++gt)
        #pragma unroll
        for (int i = 0; i < 4; ++i)
          g32[gt][i] = *(const unsigned*)&gp[gt * 256 + i * 768];
    }
    #pragma unroll
    for (int jt = 0; jt < 2; ++jt){
      #pragma unroll
      for (int i = 0; i < 4; ++i){
        int s = l4 * 4 + i, c = jb + jt * 16 + l15;
        shn[s * 264 + c] = hb[jt][i];
        wbase[(i * 128 + step) * 512 + jt * 16] = hb[jt][i];
      }
    }
    asm volatile("s_waitcnt lgkmcnt(0)" ::: "memory");
    __builtin_amdgcn_s_barrier();
    __builtin_amdgcn_sched_barrier(0);
  };

  #pragma unroll 1
  for (int it = 0; it < 64; ++it){
    body(2 * it,     sH0, sH1);
    body(2 * it + 1, sH1, sH0);
  }
}

// ---------------- weight pre-convert: waW|sWi|saW|doW -> bf16 into dead gi region ----
__global__ __launch_bounds__(256) void k_cvt(const float* __restrict__ a, const float* __restrict__ b,
                                             const float* __restrict__ c, const float* __restrict__ d2,
                                             u16* __restrict__ o){
  int i = blockIdx.x * 256 + threadIdx.x;
  int n = gridDim.x * 256;
  for (int qd = i; qd < 724224; qd += n){
    int e = qd * 4;
    f32x4 v;
    if (e < 262144)       v = *(const f32x4*)&a[e];
    else if (e < 1835008) v = *(const f32x4*)&b[e - 262144];
    else if (e < 2883584) v = *(const f32x4*)&c[e - 1835008];
    else                  v = *(const f32x4*)&d2[e - 2883584];
    *(unsigned*)&o[e]     = pk2(v[0], v[1]);
    *(unsigned*)&o[e + 2] = pk2(v[2], v[3]);
  }
}

// ---------------- u_word = tanh(wordenc @ waW^T + wab); sent_summ = sum over words ---
// grid = 64 sentences * 4 ntiles ; block 512.  bf16 weights.  Also writes word_w ones.
__global__ __launch_bounds__(512, 2) void k_uword(const u16* __restrict__ wenc, const u16* __restrict__ waWb,
                                                  const float* __restrict__ wab, u16* __restrict__ ssum,
                                                  float* __restrict__ outw){
  __shared__ u16 sA[128 * 64], sB[128 * 64];
  __shared__ float red[128];
  int bid = blockIdx.x; int s = bid >> 2, nt = bid & 3; int nbase = nt * 128;
  int t = threadIdx.x, w = t >> 6, l = t & 63, l15 = l & 15, l4 = l >> 4;
  int wm = w >> 2, wn = w & 3;
  int r0 = t >> 3, c0 = t & 7;
  const u16* Arow = wenc + s * 65536;
  const u16* Brow = waWb + nbase * 512;
  if (t < 128) red[t] = 0.f;
  if (t < 32) outw[s * 128 + nt * 32 + t] = 1.0f;   // word_w ones
  f32x4 acc[4][2];
  #pragma unroll
  for (int a = 0; a < 4; ++a){ acc[a][0] = {0.f,0.f,0.f,0.f}; acc[a][1] = {0.f,0.f,0.f,0.f}; }
  for (int ki = 0; ki < 8; ++ki){
    int k0 = ki * 64;
    s16x8 a0 = *(const s16x8*)&Arow[r0 * 512 + k0 + c0 * 8];
    s16x8 a1 = *(const s16x8*)&Arow[(64 + r0) * 512 + k0 + c0 * 8];
    s16x8 b0 = *(const s16x8*)&Brow[r0 * 512 + k0 + c0 * 8];
    s16x8 b1 = *(const s16x8*)&Brow[(64 + r0) * 512 + k0 + c0 * 8];
    __syncthreads();
    int sw = c0 ^ (r0 & 7);
    *(s16x8*)&sA[(r0 * 8 + sw) * 8] = a0;
    *(s16x8*)&sA[((64 + r0) * 8 + sw) * 8] = a1;
    *(s16x8*)&sB[(r0 * 8 + sw) * 8] = b0;
    *(s16x8*)&sB[((64 + r0) * 8 + sw) * 8] = b1;
    __syncthreads();
    #pragma unroll
    for (int kt = 0; kt < 2; ++kt){
      int ch = kt * 4 + l4;
      s16x8 bfr[2];
      #pragma unroll
      for (int n2 = 0; n2 < 2; ++n2){
        int rr = wn * 32 + n2 * 16 + l15;
        bfr[n2] = *(const s16x8*)&sB[(rr * 8 + (ch ^ (rr & 7))) * 8];
      }
      #pragma unroll
      for (int m2 = 0; m2 < 4; ++m2){
        int rr = wm * 64 + m2 * 16 + l15;
        s16x8 af = *(const s16x8*)&sA[(rr * 8 + (ch ^ (rr & 7))) * 8];
        acc[m2][0] = mfma16(af, bfr[0], acc[m2][0]);
        acc[m2][1] = mfma16(af, bfr[1], acc[m2][1]);
      }
    }
  }
  float bi0 = wab[nbase + wn * 32 + l15];
  float bi1 = wab[nbase + wn * 32 + 16 + l15];
  float p0 = 0.f, p1 = 0.f;
  #pragma unroll
  for (int m2 = 0; m2 < 4; ++m2){
    #pragma unroll
    for (int i = 0; i < 4; ++i){
      p0 += tanh_(acc[m2][0][i] + bi0);
      p1 += tanh_(acc[m2][1][i] + bi1);
    }
  }
  p0 += __shfl_xor(p0, 16); p0 += __shfl_xor(p0, 32);
  p1 += __shfl_xor(p1, 16); p1 += __shfl_xor(p1, 32);
  if (l4 == 0){
    atomicAdd(&red[wn * 32 + l15], p0);
    atomicAdd(&red[wn * 32 + 16 + l15], p1);
  }
  __syncthreads();
  if (t < 128) ssum[s * 512 + nbase + t] = f2b(red[t]);
}

// ---------------- sentence GRU (zero state): sentenc ---------------------------------
// grid = 2 dirs * 16 jblocks(32) ; block 512 (waves: 4M x 2J of 16).  bf16 weights.
__global__ __launch_bounds__(512, 2) void k_sent(const u16* __restrict__ ssum, const u16* __restrict__ sWib,
                                                 const float* __restrict__ sbi, const float* __restrict__ sbh,
                                                 u16* __restrict__ senc){
  __shared__ u16 sA[64 * 512]; // 64 KiB, swizzled
  int bid = blockIdx.x; int d = bid >> 4, jb16 = bid & 15; int jbase = jb16 * 32;
  int t = threadIdx.x, w = t >> 6, l = t & 63, l15 = l & 15, l4 = l >> 4;
  int wm = w >> 1, wj = w & 1;
  #pragma unroll
  for (int j = 0; j < 8; ++j){
    int q = j * 512 + t, r = q >> 6, c = q & 63;
    s16x8 v = *(const s16x8*)&ssum[r * 512 + c * 8];
    *(s16x8*)&sA[(r * 64 + (c ^ (r & 7))) * 8] = v;
  }
  __syncthreads();
  const u16* Wd = sWib + d * 786432;
  f32x4 acc[3];
  #pragma unroll
  for (int a = 0; a < 3; ++a) acc[a] = {0.f,0.f,0.f,0.f};
  int ra = wm * 16 + l15;
  int jcol = jbase + wj * 16 + l15;
  #pragma unroll 4
  for (int kt = 0; kt < 16; ++kt){
    int ch = kt * 4 + l4;
    s16x8 af = *(const s16x8*)&sA[(ra * 64 + (ch ^ (ra & 7))) * 8];
    #pragma unroll
    for (int gt = 0; gt < 3; ++gt){
      int n = gt * 512 + jcol;
      s16x8 bf = *(const s16x8*)&Wd[n * 512 + kt * 32 + l4 * 8];
      acc[gt] = mfma16(af, bf, acc[gt]);
    }
  }
  float biv[3], bhv[3];
  #pragma unroll
  for (int gt = 0; gt < 3; ++gt){
    int n = gt * 512 + jcol;
    biv[gt] = sbi[d * 1536 + n];
    bhv[gt] = sbh[d * 1536 + n];
  }
  #pragma unroll
  for (int i = 0; i < 4; ++i){
    float r_ = sigm(acc[0][i] + biv[0] + bhv[0]);
    float z_ = sigm(acc[1][i] + biv[1] + bhv[1]);
    float n_ = tanh_(acc[2][i] + biv[2] + r_ * bhv[2]);
    float sh = (1.f - z_) * n_;
    int srow = wm * 16 + l4 * 4 + i;
    senc[srow * 1024 + d * 512 + jcol] = f2b(sh);
  }
}

// ---------------- u_sent = tanh(sentenc @ saW^T + sab); doc = sum over sentences -----
// grid = 16 ntiles(64) ; block 512 (waves 2M x 4N of 16).  bf16 weights + sent_w ones.
__global__ __launch_bounds__(512, 2) void k_usent(const u16* __restrict__ senc, const u16* __restrict__ saWb,
                                                  const float* __restrict__ sab, float* __restrict__ docv,
                                                  float* __restrict__ outw){
  __shared__ u16 sA[64 * 1024]; // 128 KiB, swizzled
  __shared__ float red[64];
  int bid = blockIdx.x; int nbase = bid * 64;
  int t = threadIdx.x, w = t >> 6, l = t & 63, l15 = l & 15, l4 = l >> 4;
  int wm = w >> 2, wn = w & 3;
  if (t < 64) red[t] = 0.f;
  if (t < 4) outw[8192 + bid * 4 + t] = 1.0f;   // sent_w ones
  #pragma unroll
  for (int j = 0; j < 16; ++j){
    int q = j * 512 + t, r = q >> 7, c = q & 127;
    s16x8 v = *(const s16x8*)&senc[r * 1024 + c * 8];
    *(s16x8*)&sA[(r * 128 + (c ^ (r & 7))) * 8] = v;
  }
  __syncthreads();
  f32x4 acc[2];
  acc[0] = {0.f,0.f,0.f,0.f}; acc[1] = {0.f,0.f,0.f,0.f};
  int ncol = nbase + wn * 16 + l15;
  #pragma unroll 4
  for (int kt = 0; kt < 32; ++kt){
    int ch = kt * 4 + l4;
    s16x8 af[2];
    #pragma unroll
    for (int mt = 0; mt < 2; ++mt){
      int r = wm * 32 + mt * 16 + l15;
      af[mt] = *(const s16x8*)&sA[(r * 128 + (ch ^ (r & 7))) * 8];
    }
    s16x8 bf = *(const s16x8*)&saWb[ncol * 1024 + kt * 32 + l4 * 8];
    acc[0] = mfma16(af[0], bf, acc[0]);
    acc[1] = mfma16(af[1], bf, acc[1]);
  }
  float b0 = sab[ncol];
  float p0 = 0.f;
  #pragma unroll
  for (int mt = 0; mt < 2; ++mt){
    #pragma unroll
    for (int i = 0; i < 4; ++i)
      p0 += tanh_(acc[mt][i] + b0);
  }
  p0 += __shfl_xor(p0, 16); p0 += __shfl_xor(p0, 32);
  if (l4 == 0) atomicAdd(&red[wn * 16 + l15], p0);
  __syncthreads();
  if (t < 64) docv[nbase + t] = red[t];
}

// ---------------- logits + log_softmax (bf16 doW) ------------------------------------
__global__ __launch_bounds__(256) void k_final(const float* __restrict__ docv, const u16* __restrict__ doWb,
                                               const float* __restrict__ dob, float* __restrict__ out){
  __shared__ float lg[16];
  int w = threadIdx.x >> 6, l = threadIdx.x & 63;
  for (int c = w; c < 13; c += 4){
    float p = 0.f;
    for (int j = 0; j < 16; ++j){
      int k = j * 64 + l;
      p += docv[k] * b2f(doWb[c * 1024 + k]);
    }
    for (int o = 32; o >= 1; o >>= 1) p += __shfl_xor(p, o);
    if (l == 0) lg[c] = p + dob[c];
  }
  __syncthreads();
  if (threadIdx.x == 0){
    float m = lg[0];
    for (int c = 1; c < 13; ++c) m = fmaxf(m, lg[c]);
    float s = 0.f;
    for (int c = 0; c < 13; ++c) s += __expf(lg[c] - m);
    float ls = logf(s);
    for (int c = 0; c < 13; ++c) out[8256 + c] = lg[c] - m - ls;
  }
}

extern "C" void kernel_launch(void* const* d_in, const int* in_sizes, int n_in,
                              void* d_out, int out_size, void* d_ws, size_t ws_size,
                              hipStream_t stream) {
  (void)in_sizes; (void)n_in; (void)out_size; (void)ws_size;
  const int*   doc = (const int*)d_in[0];
  const float* emb = (const float*)d_in[1];
  const float* wWi = (const float*)d_in[2];
  const float* wWh = (const float*)d_in[3];
  const float* wbi = (const float*)d_in[4];
  const float* wbh = (const float*)d_in[5];
  const float* sWi = (const float*)d_in[6];
  // d_in[7] = s_Wh unused (sentence GRU sees zero state)
  const float* sbi = (const float*)d_in[8];
  const float* sbh = (const float*)d_in[9];
  const float* waW = (const float*)d_in[10];
  const float* wab = (const float*)d_in[11];
  // d_in[12] = uw_W unused (softmax over size-1 axis)
  const float* saW = (const float*)d_in[13];
  const float* sab = (const float*)d_in[14];
  // d_in[15] = us_W unused
  const float* doW = (const float*)d_in[16];
  const float* dob = (const float*)d_in[17];
  float* out = (float*)d_out;
  char* ws = (char*)d_ws;
  u16* gi    = (u16*)(ws);                    // 2*128*64*768 bf16 = 25,165,824 B
  u16* wenc  = (u16*)(ws + 25165824);         // 64*128*512 bf16  =  8,388,608 B
  u16* ssumv = (u16*)(ws + 33554432);         // 64*512 bf16      =     65,536 B
  u16* sencv = (u16*)(ws + 33619968);         // 64*1024 bf16     =    131,072 B
  float* docv = (float*)(ws + 33751040);      // 1024 f32         =      4,096 B
  // bf16 weights overlay the DEAD gi region after k_rec completes:
  u16* waWb = (u16*)(ws);                     // 262144 elems
  u16* sWib = waWb + 262144;                  // 1572864 elems
  u16* saWb = waWb + 1835008;                 // 1048576 elems
  u16* doWb = waWb + 2883584;                 // 13312 elems

  k_gi    <<<256, 512, 0, stream>>>(doc, emb, wWi, wbi, wbh, gi);
  k_rec   <<<8, 512, 0, stream>>>(wWh, wbh, gi, wenc);
  k_cvt   <<<1024, 256, 0, stream>>>(waW, sWi, saW, doW, waWb);
  k_uword <<<256, 512, 0, stream>>>(wenc, waWb, wab, ssumv, out);
  k_sent  <<<32, 512, 0, stream>>>(ssumv, sWib, sbi, sbh, sencv);
  k_usent <<<16, 512, 0, stream>>>(sencv, saWb, sab, docv, out);
  k_final <<<1, 256, 0, stream>>>(docv, doWb, dob, out);
}